// Round 1
// baseline (1348.741 us; speedup 1.0000x reference)
//
#include <hip/hip_runtime.h>
#include <cstddef>

constexpr int kB = 4, kL = 256, kR = 64, kH = 768, kTE = 100;

// Output offsets (floats) in return order
constexpr size_t OFF_FSS = 0;                       // f_sub_s  (B,L)
constexpr size_t OFF_FSE = OFF_FSS + kB * kL;       // f_sub_e  (B,L)
constexpr size_t OFF_FOS = OFF_FSE + kB * kL;       // f_obj_s  (B,L,R)
constexpr size_t OFF_FOE = OFF_FOS + (size_t)kB * kL * kR;
constexpr size_t OFF_BOS = OFF_FOE + (size_t)kB * kL * kR;
constexpr size_t OFF_BOE = OFF_BOS + kB * kL;
constexpr size_t OFF_BSS = OFF_BOE + kB * kL;
constexpr size_t OFF_BSE = OFF_BSS + (size_t)kB * kL * kR;

// Workspace layout (float offsets)
constexpr size_t WS_BREL  = 0;
constexpr size_t WS_RELPF = WS_BREL  + (size_t)kR * kH;
constexpr size_t WS_RELPB = WS_RELPF + (size_t)kR * kH;
constexpr size_t WS_HGPF  = WS_RELPB + (size_t)kR * kH;
constexpr size_t WS_HGPB  = WS_HGPF  + (size_t)kB * kH;
constexpr size_t WS_TOKPF = WS_HGPB  + (size_t)kB * kH;
constexpr size_t WS_TOKPB = WS_TOKPF + (size_t)kB * kL * kH;
constexpr size_t WS_FPAD  = WS_TOKPB + (size_t)kB * kL * kH;
constexpr size_t WS_BPAD  = WS_FPAD  + (size_t)kB * kL * kH;
constexpr size_t WS_FSW   = WS_BPAD  + (size_t)kB * kL * kH;
constexpr size_t WS_BOW   = WS_FSW   + (size_t)kB * kL * kH;
constexpr size_t WS_EMB8  = WS_BOW   + (size_t)kB * kL * kH;
constexpr size_t WS_EMB9  = WS_EMB8  + (size_t)kB * kL * kH;
constexpr size_t WS_CF    = WS_EMB9  + (size_t)kB * kL * kH;
constexpr size_t WS_CB    = WS_CF    + (size_t)kB * kR * kH;
constexpr size_t WS_FMASK = WS_CB    + (size_t)kB * kR * kH;
constexpr size_t WS_BMASK = WS_FMASK + kB * kL;
constexpr size_t WS_T4    = WS_BMASK + kB * kL;
constexpr size_t WS_T5    = WS_T4 + kB * kL;
constexpr size_t WS_T6    = WS_T5 + kB * kL;
constexpr size_t WS_T7    = WS_T6 + kB * kL;
constexpr size_t WS_C4    = WS_T7 + kB * kL;
constexpr size_t WS_C5    = WS_C4 + kB * kR;
constexpr size_t WS_C6    = WS_C5 + kB * kR;
constexpr size_t WS_C7    = WS_C6 + kB * kR;
constexpr size_t WS_AUX   = WS_C7 + kB * kR;   // int region from here

__device__ inline float fast_rcp(float x) {
#if __has_builtin(__builtin_amdgcn_rcpf)
    return __builtin_amdgcn_rcpf(x);
#else
    return 1.f / x;
#endif
}

__device__ inline float fast_tanh(float x) {
    // tanh(x) = 1 - 2/(e^{2x}+1); exp->inf gives 1, exp->0 gives -1 (correct limits)
    return 1.f - 2.f * fast_rcp(__expf(2.f * x) + 1.f);
}

// ---- 1. per-token fc logits (fp32 exact; also the threshold source) ----
__global__ __launch_bounds__(256) void k_logits(const float* __restrict__ embs,
        const float* __restrict__ fc_w, const float* __restrict__ fc_b,
        float* __restrict__ out)
{
    int t = blockIdx.x;  // b*L + l
    const float* e = embs + (size_t)t * kH;
    float s0 = 0, s1 = 0, s2 = 0, s3 = 0;
    for (int h = threadIdx.x; h < kH; h += 256) {
        float x = e[h];
        s0 += x * fc_w[0 * kH + h];
        s1 += x * fc_w[1 * kH + h];
        s2 += x * fc_w[2 * kH + h];
        s3 += x * fc_w[3 * kH + h];
    }
#pragma unroll
    for (int off = 32; off; off >>= 1) {
        s0 += __shfl_down(s0, off, 64);
        s1 += __shfl_down(s1, off, 64);
        s2 += __shfl_down(s2, off, 64);
        s3 += __shfl_down(s3, off, 64);
    }
    __shared__ float red[4][4];
    int wid = threadIdx.x >> 6;
    if ((threadIdx.x & 63) == 0) {
        red[0][wid] = s0; red[1][wid] = s1; red[2][wid] = s2; red[3][wid] = s3;
    }
    __syncthreads();
    if (threadIdx.x == 0) {
        out[OFF_FSS + t] = red[0][0] + red[0][1] + red[0][2] + red[0][3] + fc_b[0];
        out[OFF_FSE + t] = red[1][0] + red[1][1] + red[1][2] + red[1][3] + fc_b[1];
        out[OFF_BOS + t] = red[2][0] + red[2][1] + red[2][2] + red[2][3] + fc_b[2];
        out[OFF_BOE + t] = red[3][0] + red[3][1] + red[3][2] + red[3][3] + fc_b[3];
    }
}

// ---- 2. span extraction metadata: suffix-min of ends, prefix-sum of valid ----
__global__ __launch_bounds__(256) void k_extract_meta(const float* __restrict__ out,
        int* __restrict__ jbuf, int* __restrict__ rankbuf, int* __restrict__ validbuf,
        float* __restrict__ fmask, float* __restrict__ bmask)
{
    int which = blockIdx.x >> 2;   // 0=f, 1=b
    int b = blockIdx.x & 3;
    int i = threadIdx.x;           // blockDim == L == 256
    const float* slog = out + (which ? OFF_BOS : OFF_FSS) + (size_t)b * kL;
    const float* elog = out + (which ? OFF_BOE : OFF_FSE) + (size_t)b * kL;
    float sv = slog[i], ev = elog[i];
    bool st = (1.f / (1.f + __expf(-sv)) > 0.5f);
    bool en = (1.f / (1.f + __expf(-ev)) > 0.5f);

    __shared__ int sm[kL];
    __shared__ int ps[kL];
    sm[i] = en ? i : kL;
    __syncthreads();
    for (int step = 1; step < kL; step <<= 1) {  // suffix min
        int v = (i + step < kL) ? sm[i + step] : kL;
        __syncthreads();
        sm[i] = min(sm[i], v);
        __syncthreads();
    }
    int next_end = sm[i];
    int validi = (st && next_end < kL) ? 1 : 0;
    ps[i] = validi;
    __syncthreads();
    for (int step = 1; step < kL; step <<= 1) {  // inclusive prefix sum
        int v = (i >= step) ? ps[i - step] : 0;
        __syncthreads();
        ps[i] += v;
        __syncthreads();
    }
    int rank = ps[i] - 1;
    int num = ps[kL - 1];
    int gbase = (which * kB + b) * kL + i;
    jbuf[gbase] = min(next_end, kL - 1);
    rankbuf[gbase] = rank;
    validbuf[gbase] = validi;
    (which ? bmask : fmask)[b * kL + i] = (i < num) ? 1.f : 0.f;
}

// ---- 3. span means packed by rank ----
__global__ __launch_bounds__(256) void k_span_mean(const float* __restrict__ embs,
        const int* __restrict__ jbuf, const int* __restrict__ rankbuf,
        const int* __restrict__ validbuf,
        float* __restrict__ fpad, float* __restrict__ bpad)
{
    int idx = blockIdx.x;          // 2*B*L blocks
    int which = idx >> 10;
    int b = (idx >> 8) & 3;
    int i = idx & 255;
    int gbase = (which * kB + b) * kL + i;
    if (!validbuf[gbase]) return;
    int j = jbuf[gbase];
    int rk = rankbuf[gbase];
    int len = j - i + 1;
    float inv = 1.f / (float)len;
    float* pad = (which ? bpad : fpad) + ((size_t)(b * kL + rk)) * kH;
    const float* e = embs + ((size_t)(b * kL + i)) * kH;
    for (int h = threadIdx.x; h < kH; h += 256) {
        float s = 0.f;
        for (int row = 0; row < len; row++) s += e[(size_t)row * kH + h];
        pad[h] = s * inv;
    }
}

// ---- 4. generic fp32 GEMM: C[M,768] = A[M,K] @ W[K,768] + bias, optional row mask ----
__global__ __launch_bounds__(256) void k_gemm(const float* __restrict__ A,
        const float* __restrict__ W, const float* __restrict__ bias,
        float* __restrict__ C, int M, int K, const float* __restrict__ rowmask)
{
    const int N = kH;
    __shared__ float As[16][128];
    __shared__ float Ws[16][128];
    int tid = threadIdx.x;
    int tx = tid & 15, ty = tid >> 4;
    int n0 = blockIdx.x * 128;
    int m0 = blockIdx.y * 128;
    float acc[8][8] = {};
    int arow = tid >> 2;
    int akq = (tid & 3) << 2;
    int wrow = tid >> 5;
    int wcol = (tid & 31) << 2;

    for (int k0 = 0; k0 < K; k0 += 16) {
#pragma unroll
        for (int half = 0; half < 2; half++) {
            int m = m0 + arow + half * 64;
            float4 v = make_float4(0.f, 0.f, 0.f, 0.f);
            if (m < M) {
                int kbase = k0 + akq;
                if (kbase + 3 < K) {
                    v = *(const float4*)(A + (size_t)m * K + kbase);
                } else {
                    float tmp[4];
#pragma unroll
                    for (int q = 0; q < 4; q++)
                        tmp[q] = (kbase + q < K) ? A[(size_t)m * K + kbase + q] : 0.f;
                    v = make_float4(tmp[0], tmp[1], tmp[2], tmp[3]);
                }
            }
            As[akq + 0][arow + half * 64] = v.x;
            As[akq + 1][arow + half * 64] = v.y;
            As[akq + 2][arow + half * 64] = v.z;
            As[akq + 3][arow + half * 64] = v.w;
        }
#pragma unroll
        for (int half = 0; half < 2; half++) {
            int k = k0 + wrow + half * 8;
            float4 v = make_float4(0.f, 0.f, 0.f, 0.f);
            if (k < K) v = *(const float4*)(W + (size_t)k * N + n0 + wcol);
            *(float4*)&Ws[wrow + half * 8][wcol] = v;
        }
        __syncthreads();
#pragma unroll
        for (int kk = 0; kk < 16; kk++) {
            float a[8], w[8];
            *(float4*)&a[0] = *(const float4*)&As[kk][ty * 8];
            *(float4*)&a[4] = *(const float4*)&As[kk][ty * 8 + 4];
            *(float4*)&w[0] = *(const float4*)&Ws[kk][tx * 8];
            *(float4*)&w[4] = *(const float4*)&Ws[kk][tx * 8 + 4];
#pragma unroll
            for (int ii = 0; ii < 8; ii++)
#pragma unroll
                for (int jj = 0; jj < 8; jj++)
                    acc[ii][jj] += a[ii] * w[jj];
        }
        __syncthreads();
    }
#pragma unroll
    for (int ii = 0; ii < 8; ii++) {
        int m = m0 + ty * 8 + ii;
        if (m >= M) break;
        float mask = rowmask ? rowmask[m] : 1.f;
#pragma unroll
        for (int jj = 0; jj < 8; jj += 4) {
            int n = n0 + tx * 8 + jj;
            float4 o;
            o.x = (acc[ii][jj + 0] + bias[n + 0]) * mask;
            o.y = (acc[ii][jj + 1] + bias[n + 1]) * mask;
            o.z = (acc[ii][jj + 2] + bias[n + 2]) * mask;
            o.w = (acc[ii][jj + 3] + bias[n + 3]) * mask;
            *(float4*)(C + (size_t)m * N + n) = o;
        }
    }
}

// ---- 5. fused additive attention: tanh-score, softmax over L, C = A^T @ embs ----
__global__ __launch_bounds__(256) void k_attn(const float* __restrict__ embs,
        const float* __restrict__ tokpf, const float* __restrict__ tokpb,
        const float* __restrict__ relpf, const float* __restrict__ relpb,
        const float* __restrict__ hgpf, const float* __restrict__ hgpb,
        const float* __restrict__ V_w, const float* __restrict__ V_b,
        float* __restrict__ Cf, float* __restrict__ Cb)
{
    int idx = blockIdx.x;          // 2*B*R blocks
    int which = idx >> 8;
    int b = (idx >> 6) & 3;
    int r = idx & 63;
    const float* tokp = which ? tokpb : tokpf;
    const float* relp = (which ? relpb : relpf) + (size_t)r * kH;
    const float* hgp  = (which ? hgpb : hgpf) + (size_t)b * kH;
    float* Cout = (which ? Cb : Cf) + ((size_t)(b * kR + r)) * kH;

    __shared__ float addv[kH];
    __shared__ float vw[kH];
    __shared__ float A_lds[kL];
    __shared__ float red[4];

    for (int h = threadIdx.x; h < kH; h += 256) {
        addv[h] = relp[h] + hgp[h];
        vw[h] = V_w[h];
    }
    __syncthreads();

    int l = threadIdx.x;
    const float4* tp = (const float4*)(tokp + ((size_t)(b * kL + l)) * kH);
    float v = 0.f;
    for (int h4 = 0; h4 < kH / 4; h4++) {
        float4 tv = tp[h4];
        int h = h4 * 4;
        v += fast_tanh(tv.x + addv[h + 0]) * vw[h + 0];
        v += fast_tanh(tv.y + addv[h + 1]) * vw[h + 1];
        v += fast_tanh(tv.z + addv[h + 2]) * vw[h + 2];
        v += fast_tanh(tv.w + addv[h + 3]) * vw[h + 3];
    }
    v += V_b[0];

    // softmax over the 256 threads (= L)
    float m = v;
#pragma unroll
    for (int off = 32; off; off >>= 1) m = fmaxf(m, __shfl_xor(m, off, 64));
    int wid = threadIdx.x >> 6, lane = threadIdx.x & 63;
    if (!lane) red[wid] = m;
    __syncthreads();
    m = fmaxf(fmaxf(red[0], red[1]), fmaxf(red[2], red[3]));
    float p = __expf(v - m);
    float s = p;
#pragma unroll
    for (int off = 32; off; off >>= 1) s += __shfl_xor(s, off, 64);
    __syncthreads();
    if (!lane) red[wid] = s;
    __syncthreads();
    s = red[0] + red[1] + red[2] + red[3];
    A_lds[l] = p / s;
    __syncthreads();

    // C[b,r,h] = sum_l A[l] * embs[b,l,h]
    float acc0 = 0.f, acc1 = 0.f, acc2 = 0.f;
    for (int ll = 0; ll < kL; ll++) {
        float a = A_lds[ll];
        const float* er = embs + ((size_t)(b * kL + ll)) * kH + threadIdx.x;
        acc0 += a * er[0];
        acc1 += a * er[256];
        acc2 += a * er[512];
    }
    Cout[threadIdx.x] = acc0;
    Cout[threadIdx.x + 256] = acc1;
    Cout[threadIdx.x + 512] = acc2;
}

// ---- 6. t vectors: (Hik + embs) @ fc_w[i] for both fc rows of each side ----
__global__ __launch_bounds__(256) void k_t(const float* __restrict__ embs,
        const float* __restrict__ fsw, const float* __restrict__ emb8,
        const float* __restrict__ bow, const float* __restrict__ emb9,
        const float* __restrict__ fc_w,
        float* __restrict__ t4, float* __restrict__ t5,
        float* __restrict__ t6, float* __restrict__ t7)
{
    int idx = blockIdx.x;          // 2*B*L blocks
    int which = idx >> 10;
    int t = idx & 1023;
    const float* sw = which ? bow : fsw;
    const float* e8 = which ? emb9 : emb8;
    const float* w0 = fc_w + (size_t)(which ? 6 : 4) * kH;
    const float* w1 = w0 + kH;
    size_t base = (size_t)t * kH;
    float s0 = 0, s1 = 0;
    for (int h = threadIdx.x; h < kH; h += 256) {
        float x = sw[base + h] + e8[base + h] + embs[base + h];
        s0 += x * w0[h];
        s1 += x * w1[h];
    }
#pragma unroll
    for (int off = 32; off; off >>= 1) {
        s0 += __shfl_down(s0, off, 64);
        s1 += __shfl_down(s1, off, 64);
    }
    __shared__ float red[2][4];
    int wid = threadIdx.x >> 6;
    if ((threadIdx.x & 63) == 0) { red[0][wid] = s0; red[1][wid] = s1; }
    __syncthreads();
    if (threadIdx.x == 0) {
        float a = red[0][0] + red[0][1] + red[0][2] + red[0][3];
        float c = red[1][0] + red[1][1] + red[1][2] + red[1][3];
        if (which) { t6[t] = a; t7[t] = c; }
        else       { t4[t] = a; t5[t] = c; }
    }
}

// ---- 7. c vectors: C @ fc_w[i] ----
__global__ __launch_bounds__(256) void k_c(const float* __restrict__ Cf,
        const float* __restrict__ Cb, const float* __restrict__ fc_w,
        float* __restrict__ c4, float* __restrict__ c5,
        float* __restrict__ c6, float* __restrict__ c7)
{
    int idx = blockIdx.x;          // 2*B*R blocks
    int which = idx >> 8;
    int p = idx & 255;
    const float* Cm = (which ? Cb : Cf) + (size_t)p * kH;
    const float* w0 = fc_w + (size_t)(which ? 6 : 4) * kH;
    const float* w1 = w0 + kH;
    float s0 = 0, s1 = 0;
    for (int h = threadIdx.x; h < kH; h += 256) {
        float x = Cm[h];
        s0 += x * w0[h];
        s1 += x * w1[h];
    }
#pragma unroll
    for (int off = 32; off; off >>= 1) {
        s0 += __shfl_down(s0, off, 64);
        s1 += __shfl_down(s1, off, 64);
    }
    __shared__ float red[2][4];
    int wid = threadIdx.x >> 6;
    if ((threadIdx.x & 63) == 0) { red[0][wid] = s0; red[1][wid] = s1; }
    __syncthreads();
    if (threadIdx.x == 0) {
        float a = red[0][0] + red[0][1] + red[0][2] + red[0][3];
        float c = red[1][0] + red[1][1] + red[1][2] + red[1][3];
        if (which) { c6[p] = a; c7[p] = c; }
        else       { c4[p] = a; c5[p] = c; }
    }
}

// ---- 8. broadcast-add final pair logits ----
__global__ __launch_bounds__(64) void k_final(const float* __restrict__ t4,
        const float* __restrict__ t5, const float* __restrict__ t6,
        const float* __restrict__ t7, const float* __restrict__ c4,
        const float* __restrict__ c5, const float* __restrict__ c6,
        const float* __restrict__ c7, const float* __restrict__ fc_b,
        float* __restrict__ out)
{
    int which = blockIdx.x >> 10;
    int t = blockIdx.x & 1023;     // b*L + l
    int b = t >> 8;
    int r = threadIdx.x;
    if (!which) {
        out[OFF_FOS + (size_t)t * kR + r] = t4[t] + c4[b * kR + r] + fc_b[4];
        out[OFF_FOE + (size_t)t * kR + r] = t5[t] + c5[b * kR + r] + fc_b[5];
    } else {
        out[OFF_BSS + (size_t)t * kR + r] = t6[t] + c6[b * kR + r] + fc_b[6];
        out[OFF_BSE + (size_t)t * kR + r] = t7[t] + c7[b * kR + r] + fc_b[7];
    }
}

extern "C" void kernel_launch(void* const* d_in, const int* in_sizes, int n_in,
                              void* d_out, int out_size, void* d_ws, size_t ws_size,
                              hipStream_t stream)
{
    const float* embs       = (const float*)d_in[0];
    const float* h_gs       = (const float*)d_in[1];
    const float* rel_embs   = (const float*)d_in[2];
    const float* rel_transe = (const float*)d_in[3];
    const float* fc_w       = (const float*)d_in[4];
    const float* fc_b       = (const float*)d_in[5];
    const float* Wm         = (const float*)d_in[6];
    const float* Wb         = (const float*)d_in[7];
    const float* V_w        = (const float*)d_in[8];
    const float* V_b        = (const float*)d_in[9];
    const float* rproj_w    = (const float*)d_in[10];
    const float* rproj_b    = (const float*)d_in[11];
    float* out = (float*)d_out;
    float* ws  = (float*)d_ws;

    float* brel  = ws + WS_BREL;
    float* relpf = ws + WS_RELPF;
    float* relpb = ws + WS_RELPB;
    float* hgpf  = ws + WS_HGPF;
    float* hgpb  = ws + WS_HGPB;
    float* tokpf = ws + WS_TOKPF;
    float* tokpb = ws + WS_TOKPB;
    float* fpad  = ws + WS_FPAD;
    float* bpad  = ws + WS_BPAD;
    float* fsw   = ws + WS_FSW;
    float* bow   = ws + WS_BOW;
    float* emb8  = ws + WS_EMB8;
    float* emb9  = ws + WS_EMB9;
    float* Cf    = ws + WS_CF;
    float* Cb    = ws + WS_CB;
    float* fmask = ws + WS_FMASK;
    float* bmask = ws + WS_BMASK;
    float* t4 = ws + WS_T4;
    float* t5 = ws + WS_T5;
    float* t6 = ws + WS_T6;
    float* t7 = ws + WS_T7;
    float* c4 = ws + WS_C4;
    float* c5 = ws + WS_C5;
    float* c6 = ws + WS_C6;
    float* c7 = ws + WS_C7;
    int* jbuf     = (int*)(ws + WS_AUX);
    int* rankbuf  = jbuf + 2 * kB * kL;
    int* validbuf = rankbuf + 2 * kB * kL;

    const size_t HH = (size_t)kH * kH;

    k_logits<<<kB * kL, 256, 0, stream>>>(embs, fc_w, fc_b, out);
    k_extract_meta<<<2 * kB, 256, 0, stream>>>(out, jbuf, rankbuf, validbuf, fmask, bmask);
    k_span_mean<<<2 * kB * kL, 256, 0, stream>>>(embs, jbuf, rankbuf, validbuf, fpad, bpad);

    // small GEMMs
    k_gemm<<<dim3(6, 1), 256, 0, stream>>>(rel_transe, rproj_w, rproj_b, brel, kR, kTE, nullptr);
    k_gemm<<<dim3(6, 1), 256, 0, stream>>>(rel_embs, Wm + 2 * HH, Wb + 2 * kH, relpf, kR, kH, nullptr);
    k_gemm<<<dim3(6, 1), 256, 0, stream>>>(brel,     Wm + 5 * HH, Wb + 5 * kH, relpb, kR, kH, nullptr);
    k_gemm<<<dim3(6, 1), 256, 0, stream>>>(h_gs,     Wm + 3 * HH, Wb + 3 * kH, hgpf, kB, kH, nullptr);
    k_gemm<<<dim3(6, 1), 256, 0, stream>>>(h_gs,     Wm + 6 * HH, Wb + 6 * kH, hgpb, kB, kH, nullptr);
    // big GEMMs (M = B*L = 1024)
    k_gemm<<<dim3(6, 8), 256, 0, stream>>>(embs, Wm + 4 * HH, Wb + 4 * kH, tokpf, kB * kL, kH, nullptr);
    k_gemm<<<dim3(6, 8), 256, 0, stream>>>(embs, Wm + 7 * HH, Wb + 7 * kH, tokpb, kB * kL, kH, nullptr);
    k_gemm<<<dim3(6, 8), 256, 0, stream>>>(fpad, Wm + 0 * HH, Wb + 0 * kH, fsw, kB * kL, kH, fmask);
    k_gemm<<<dim3(6, 8), 256, 0, stream>>>(bpad, Wm + 1 * HH, Wb + 1 * kH, bow, kB * kL, kH, bmask);
    k_gemm<<<dim3(6, 8), 256, 0, stream>>>(embs, Wm + 8 * HH, Wb + 8 * kH, emb8, kB * kL, kH, nullptr);
    k_gemm<<<dim3(6, 8), 256, 0, stream>>>(embs, Wm + 9 * HH, Wb + 9 * kH, emb9, kB * kL, kH, nullptr);

    k_attn<<<2 * kB * kR, 256, 0, stream>>>(embs, tokpf, tokpb, relpf, relpb, hgpf, hgpb, V_w, V_b, Cf, Cb);
    k_t<<<2 * kB * kL, 256, 0, stream>>>(embs, fsw, emb8, bow, emb9, fc_w, t4, t5, t6, t7);
    k_c<<<2 * kB * kR, 256, 0, stream>>>(Cf, Cb, fc_w, c4, c5, c6, c7);
    k_final<<<2 * kB * kL, 64, 0, stream>>>(t4, t5, t6, t7, c4, c5, c6, c7, fc_b, out);
}

// Round 2
// 228.250 us; speedup vs baseline: 5.9091x; 5.9091x over previous
//
#include <hip/hip_runtime.h>
#include <cstddef>

using u16 = unsigned short;
typedef __attribute__((ext_vector_type(8))) short bf16x8;
typedef __attribute__((ext_vector_type(4))) float f32x4;

constexpr int kB = 4, kL = 256, kR = 64, kH = 768, kTE = 100;
constexpr size_t HH = (size_t)kH * kH;

// ---- output offsets (floats) in return order ----
constexpr size_t OFF_FSS = 0;
constexpr size_t OFF_FSE = OFF_FSS + kB * kL;
constexpr size_t OFF_FOS = OFF_FSE + kB * kL;
constexpr size_t OFF_FOE = OFF_FOS + (size_t)kB * kL * kR;
constexpr size_t OFF_BOS = OFF_FOE + (size_t)kB * kL * kR;
constexpr size_t OFF_BOE = OFF_BOS + kB * kL;
constexpr size_t OFF_BSS = OFF_BOE + kB * kL;
constexpr size_t OFF_BSE = OFF_BSS + (size_t)kB * kL * kR;

// ---- workspace layout (float units; all offsets multiple of 4 -> 16B aligned) ----
constexpr size_t WS_WTALL   = 0;                                  // 10 x [768][768] bf16 (transposed: Wt[n][k])
constexpr size_t WS_RPROJT  = WS_WTALL   + 10 * HH / 2;           // [768][128] bf16 (zero-padded K)
constexpr size_t WS_EMBSB   = WS_RPROJT  + (768 * 128) / 2;       // [1024][768] bf16
constexpr size_t WS_RELEMBB = WS_EMBSB   + (1024 * 768) / 2;      // [64][768] bf16
constexpr size_t WS_HGSB    = WS_RELEMBB + (64 * 768) / 2;        // [4][768] bf16
constexpr size_t WS_RTRANSB = WS_HGSB    + (4 * 768) / 2;         // [64][128] bf16 (zero-padded K)
constexpr size_t WS_FPADB   = WS_RTRANSB + (64 * 128) / 2;        // [1024][768] bf16
constexpr size_t WS_BPADB   = WS_FPADB   + (1024 * 768) / 2;
constexpr size_t WS_BRELB   = WS_BPADB   + (1024 * 768) / 2;      // [64][768] bf16
constexpr size_t WS_BREL    = WS_BRELB   + (64 * 768) / 2;        // [64][768] f32
constexpr size_t WS_RELPF   = WS_BREL    + 64 * 768;
constexpr size_t WS_RELPB   = WS_RELPF   + 64 * 768;
constexpr size_t WS_HGPF    = WS_RELPB   + 64 * 768;
constexpr size_t WS_HGPB    = WS_HGPF    + 4 * 768;
constexpr size_t WS_BIG4    = WS_HGPB    + 4 * 768;               // [1024][3072] f32: tokpf|tokpb|emb8|emb9
constexpr size_t WS_FSW     = WS_BIG4    + (size_t)1024 * 3072;
constexpr size_t WS_BOW     = WS_FSW     + 1024 * 768;
constexpr size_t WS_FMASK   = WS_BOW     + 1024 * 768;
constexpr size_t WS_BMASK   = WS_FMASK   + 1024;
constexpr size_t WS_T4      = WS_BMASK   + 1024;
constexpr size_t WS_T5      = WS_T4 + 1024;
constexpr size_t WS_T6      = WS_T5 + 1024;
constexpr size_t WS_T7      = WS_T6 + 1024;
constexpr size_t WS_C4      = WS_T7 + 1024;
constexpr size_t WS_C5      = WS_C4 + 256;
constexpr size_t WS_C6      = WS_C5 + 256;
constexpr size_t WS_C7      = WS_C6 + 256;
constexpr size_t WS_AUX     = WS_C7 + 256;   // int region

__device__ inline float fast_rcp(float x) {
#if __has_builtin(__builtin_amdgcn_rcpf)
    return __builtin_amdgcn_rcpf(x);
#else
    return 1.f / x;
#endif
}
__device__ inline float fast_tanh(float x) {
    return 1.f - 2.f * fast_rcp(__expf(2.f * x) + 1.f);
}
__device__ inline u16 f2bf(float x) {   // RNE
    union { float f; unsigned u; } v; v.f = x;
    unsigned r = v.u + 0x7FFFu + ((v.u >> 16) & 1u);
    return (u16)(r >> 16);
}

// ---- 1. per-token fc logits (fp32 exact: threshold source) + embs bf16 cast ----
__global__ __launch_bounds__(256) void k_logits(const float* __restrict__ embs,
        const float* __restrict__ fc_w, const float* __restrict__ fc_b,
        float* __restrict__ out, u16* __restrict__ embsB)
{
    int t = blockIdx.x;
    const float* e = embs + (size_t)t * kH;
    float s0 = 0, s1 = 0, s2 = 0, s3 = 0;
    for (int h = threadIdx.x; h < kH; h += 256) {
        float x = e[h];
        embsB[(size_t)t * kH + h] = f2bf(x);
        s0 += x * fc_w[0 * kH + h];
        s1 += x * fc_w[1 * kH + h];
        s2 += x * fc_w[2 * kH + h];
        s3 += x * fc_w[3 * kH + h];
    }
#pragma unroll
    for (int off = 32; off; off >>= 1) {
        s0 += __shfl_down(s0, off, 64);
        s1 += __shfl_down(s1, off, 64);
        s2 += __shfl_down(s2, off, 64);
        s3 += __shfl_down(s3, off, 64);
    }
    __shared__ float red[4][4];
    int wid = threadIdx.x >> 6;
    if ((threadIdx.x & 63) == 0) {
        red[0][wid] = s0; red[1][wid] = s1; red[2][wid] = s2; red[3][wid] = s3;
    }
    __syncthreads();
    if (threadIdx.x == 0) {
        out[OFF_FSS + t] = red[0][0] + red[0][1] + red[0][2] + red[0][3] + fc_b[0];
        out[OFF_FSE + t] = red[1][0] + red[1][1] + red[1][2] + red[1][3] + fc_b[1];
        out[OFF_BOS + t] = red[2][0] + red[2][1] + red[2][2] + red[2][3] + fc_b[2];
        out[OFF_BOE + t] = red[3][0] + red[3][1] + red[3][2] + red[3][3] + fc_b[3];
    }
}

// ---- 2. misc bf16 casts: rel_embs, h_gs, rel_transe (K-pad 100->128) ----
__global__ __launch_bounds__(256) void k_prep_cast(const float* __restrict__ rel_embs,
        const float* __restrict__ h_gs, const float* __restrict__ rel_transe,
        u16* __restrict__ relembB, u16* __restrict__ hgsB, u16* __restrict__ rtransB)
{
    int bx = blockIdx.x, t = threadIdx.x;
    if (bx < 64) {
        for (int h = t; h < kH; h += 256) relembB[bx * kH + h] = f2bf(rel_embs[bx * kH + h]);
    } else if (bx < 68) {
        int r = bx - 64;
        for (int h = t; h < kH; h += 256) hgsB[r * kH + h] = f2bf(h_gs[r * kH + h]);
    } else {
        int r = bx - 68;
        if (t < 128) rtransB[r * 128 + t] = (t < kTE) ? f2bf(rel_transe[r * kTE + t]) : (u16)0;
    }
}

// ---- 3. weight transposes: Wt[n][k] = W[k][n], bf16 out ----
// blocks 0..1439: Wm (10 matrices x 144 64x64 tiles); 1440..1463: rproj (12 n-tiles x 2 k-tiles)
__global__ __launch_bounds__(256) void k_prep_w(const float* __restrict__ Wm,
        const float* __restrict__ rproj_w, u16* __restrict__ WtAll, u16* __restrict__ rprojT)
{
    __shared__ float tl[64][65];
    int bx = blockIdx.x, t = threadIdx.x;
    const float* src; u16* dst; int kt, nt, dstStride, srcRows;
    if (bx < 1440) {
        int mi = bx / 144, tile = bx % 144;
        kt = (tile / 12) * 64; nt = (tile % 12) * 64;
        src = Wm + (size_t)mi * HH; dst = WtAll + (size_t)mi * HH;
        dstStride = kH; srcRows = kH;
    } else {
        int tt = bx - 1440;
        kt = (tt / 12) * 64; nt = (tt % 12) * 64;
        src = rproj_w; dst = rprojT; dstStride = 128; srcRows = kTE;
    }
    int r = t >> 2, cq = (t & 3) * 16;
    int row = kt + r;
#pragma unroll
    for (int q = 0; q < 4; q++) {
        float4 v = make_float4(0.f, 0.f, 0.f, 0.f);
        if (row < srcRows) v = *(const float4*)(src + (size_t)row * kH + nt + cq + q * 4);
        tl[r][cq + q * 4 + 0] = v.x;
        tl[r][cq + q * 4 + 1] = v.y;
        tl[r][cq + q * 4 + 2] = v.z;
        tl[r][cq + q * 4 + 3] = v.w;
    }
    __syncthreads();
    // write: dst[(nt + n_local)*stride + kt + k_local], n_local = r, k_local = cq..cq+15
    u16* drow = dst + (size_t)(nt + r) * dstStride + kt + cq;
#pragma unroll
    for (int j = 0; j < 16; j++) drow[j] = f2bf(tl[cq + j][r]);
}

// ---- 4. span extraction metadata ----
__global__ __launch_bounds__(256) void k_extract_meta(const float* __restrict__ out,
        int* __restrict__ jbuf, int* __restrict__ rankbuf, int* __restrict__ validbuf,
        float* __restrict__ fmask, float* __restrict__ bmask)
{
    int which = blockIdx.x >> 2;
    int b = blockIdx.x & 3;
    int i = threadIdx.x;
    const float* slog = out + (which ? OFF_BOS : OFF_FSS) + (size_t)b * kL;
    const float* elog = out + (which ? OFF_BOE : OFF_FSE) + (size_t)b * kL;
    float sv = slog[i], ev = elog[i];
    bool st = (1.f / (1.f + __expf(-sv)) > 0.5f);
    bool en = (1.f / (1.f + __expf(-ev)) > 0.5f);

    __shared__ int sm[kL];
    __shared__ int ps[kL];
    sm[i] = en ? i : kL;
    __syncthreads();
    for (int step = 1; step < kL; step <<= 1) {
        int v = (i + step < kL) ? sm[i + step] : kL;
        __syncthreads();
        sm[i] = min(sm[i], v);
        __syncthreads();
    }
    int next_end = sm[i];
    int validi = (st && next_end < kL) ? 1 : 0;
    ps[i] = validi;
    __syncthreads();
    for (int step = 1; step < kL; step <<= 1) {
        int v = (i >= step) ? ps[i - step] : 0;
        __syncthreads();
        ps[i] += v;
        __syncthreads();
    }
    int rank = ps[i] - 1;
    int num = ps[kL - 1];
    int gbase = (which * kB + b) * kL + i;
    jbuf[gbase] = min(next_end, kL - 1);
    rankbuf[gbase] = rank;
    validbuf[gbase] = validi;
    (which ? bmask : fmask)[b * kL + i] = (i < num) ? 1.f : 0.f;
}

// ---- 5. span means packed by rank (bf16 out) ----
__global__ __launch_bounds__(256) void k_span_mean(const float* __restrict__ embs,
        const int* __restrict__ jbuf, const int* __restrict__ rankbuf,
        const int* __restrict__ validbuf, u16* __restrict__ fpadB, u16* __restrict__ bpadB)
{
    int idx = blockIdx.x;
    int which = idx >> 10;
    int b = (idx >> 8) & 3;
    int i = idx & 255;
    int gbase = (which * kB + b) * kL + i;
    if (!validbuf[gbase]) return;
    int j = jbuf[gbase];
    int rk = rankbuf[gbase];
    int len = j - i + 1;
    float inv = 1.f / (float)len;
    u16* pad = (which ? bpadB : fpadB) + ((size_t)(b * kL + rk)) * kH;
    const float* e = embs + ((size_t)(b * kL + i)) * kH;
    for (int h = threadIdx.x; h < kH; h += 256) {
        float s = 0.f;
        for (int row = 0; row < len; row++) s += e[(size_t)row * kH + h];
        pad[h] = f2bf(s * inv);
    }
}

// ---- 6. batched MFMA GEMM: C = A[M][K]bf16 @ Wt[N][K]^T + bias ----
struct GemmJob {
    const u16* A; const u16* Wt; const float* bias;
    float* C; u16* Cbf; const float* rowmask;
    int M; int K; int ldc; int coff;
};
struct GemmBatch { GemmJob j[4]; };

__global__ __launch_bounds__(256) void k_gemm_mfma(GemmBatch batch)
{
    GemmJob jb = batch.j[blockIdx.z];
    __shared__ short Als[128][40];   // padded: row stride 80B (2-way max conflict)
    __shared__ short Bls[128][40];
    int tid = threadIdx.x;
    int m0 = blockIdx.x * 128;
    int n0 = blockIdx.y * 128;
    int w = tid >> 6, lane = tid & 63;
    int wm = (w >> 1) * 64, wn = (w & 1) * 64;
    int lrow = lane & 15, lhi = lane >> 4;

    f32x4 zero4 = {0.f, 0.f, 0.f, 0.f};
    f32x4 acc[4][4];
#pragma unroll
    for (int i = 0; i < 4; i++)
#pragma unroll
        for (int j = 0; j < 4; j++) acc[i][j] = zero4;

    int srow = tid >> 2;
    int schunk = (tid & 3) * 8;
    int K = jb.K;

    for (int k0 = 0; k0 < K; k0 += 32) {
#pragma unroll
        for (int rph = 0; rph < 2; rph++) {
            int r = srow + rph * 64;
            bf16x8 va;
#pragma unroll
            for (int q = 0; q < 8; q++) va[q] = 0;
            if (m0 + r < jb.M)
                va = *reinterpret_cast<const bf16x8*>(jb.A + (size_t)(m0 + r) * K + k0 + schunk);
            *reinterpret_cast<bf16x8*>(&Als[r][schunk]) = va;
            bf16x8 vb = *reinterpret_cast<const bf16x8*>(jb.Wt + (size_t)(n0 + r) * K + k0 + schunk);
            *reinterpret_cast<bf16x8*>(&Bls[r][schunk]) = vb;
        }
        __syncthreads();
        bf16x8 af[4], bg[4];
#pragma unroll
        for (int i = 0; i < 4; i++) {
            af[i] = *reinterpret_cast<const bf16x8*>(&Als[wm + i * 16 + lrow][lhi * 8]);
            bg[i] = *reinterpret_cast<const bf16x8*>(&Bls[wn + i * 16 + lrow][lhi * 8]);
        }
#pragma unroll
        for (int i = 0; i < 4; i++)
#pragma unroll
            for (int j = 0; j < 4; j++)
                acc[i][j] = __builtin_amdgcn_mfma_f32_16x16x32_bf16(af[i], bg[j], acc[i][j], 0, 0, 0);
        __syncthreads();
    }
    // epilogue: D col = lane&15 (n), row = (lane>>4)*4 + q (m)
#pragma unroll
    for (int i = 0; i < 4; i++) {
#pragma unroll
        for (int j = 0; j < 4; j++) {
            int n = n0 + wn + j * 16 + lrow;
            float bi = jb.bias[n];
#pragma unroll
            for (int q = 0; q < 4; q++) {
                int m = m0 + wm + i * 16 + lhi * 4 + q;
                if (m < jb.M) {
                    float val = acc[i][j][q] + bi;
                    if (jb.rowmask) val *= jb.rowmask[m];
                    jb.C[(size_t)m * jb.ldc + jb.coff + n] = val;
                    if (jb.Cbf) jb.Cbf[(size_t)m * jb.ldc + jb.coff + n] = f2bf(val);
                }
            }
        }
    }
}

// ---- 7. fused additive attention + C@fc_w dots (replaces k_c) ----
__global__ __launch_bounds__(256) void k_attn(const float* __restrict__ embs,
        const float* __restrict__ big4,
        const float* __restrict__ relpf, const float* __restrict__ relpb,
        const float* __restrict__ hgpf, const float* __restrict__ hgpb,
        const float* __restrict__ V_w, const float* __restrict__ V_b,
        const float* __restrict__ fc_w,
        float* __restrict__ c4, float* __restrict__ c5,
        float* __restrict__ c6, float* __restrict__ c7)
{
    int idx = blockIdx.x;          // 2*B*R
    int which = idx >> 8;
    int b = (idx >> 6) & 3;
    int r = idx & 63;
    const float* relp = (which ? relpb : relpf) + (size_t)r * kH;
    const float* hgp  = (which ? hgpb : hgpf) + (size_t)b * kH;

    __shared__ float addv[kH];
    __shared__ float vw[kH];
    __shared__ float A_lds[kL];
    __shared__ float red[4];
    __shared__ float redc[2][4];

    for (int h = threadIdx.x; h < kH; h += 256) {
        addv[h] = relp[h] + hgp[h];
        vw[h] = V_w[h];
    }
    __syncthreads();

    int l = threadIdx.x;
    const float4* tp = (const float4*)(big4 + ((size_t)(b * kL + l)) * 3072 + which * kH);
    float v = 0.f;
    for (int h4 = 0; h4 < kH / 4; h4++) {
        float4 tv = tp[h4];
        int h = h4 * 4;
        v += fast_tanh(tv.x + addv[h + 0]) * vw[h + 0];
        v += fast_tanh(tv.y + addv[h + 1]) * vw[h + 1];
        v += fast_tanh(tv.z + addv[h + 2]) * vw[h + 2];
        v += fast_tanh(tv.w + addv[h + 3]) * vw[h + 3];
    }
    v += V_b[0];

    float m = v;
#pragma unroll
    for (int off = 32; off; off >>= 1) m = fmaxf(m, __shfl_xor(m, off, 64));
    int wid = threadIdx.x >> 6, lane = threadIdx.x & 63;
    if (!lane) red[wid] = m;
    __syncthreads();
    m = fmaxf(fmaxf(red[0], red[1]), fmaxf(red[2], red[3]));
    float p = __expf(v - m);
    float s = p;
#pragma unroll
    for (int off = 32; off; off >>= 1) s += __shfl_xor(s, off, 64);
    __syncthreads();
    if (!lane) red[wid] = s;
    __syncthreads();
    s = red[0] + red[1] + red[2] + red[3];
    A_lds[l] = p / s;
    __syncthreads();

    // C[h] = sum_l A[l] * embs[b,l,h]; thread owns h = tid, tid+256, tid+512
    float acc0 = 0.f, acc1 = 0.f, acc2 = 0.f;
    for (int ll = 0; ll < kL; ll++) {
        float a = A_lds[ll];
        const float* er = embs + ((size_t)(b * kL + ll)) * kH + threadIdx.x;
        acc0 += a * er[0];
        acc1 += a * er[256];
        acc2 += a * er[512];
    }
    // fused: c = C @ fc_w[row]
    const float* w0 = fc_w + (size_t)(which ? 6 : 4) * kH;
    const float* w1 = w0 + kH;
    float d0 = acc0 * w0[l] + acc1 * w0[l + 256] + acc2 * w0[l + 512];
    float d1 = acc0 * w1[l] + acc1 * w1[l + 256] + acc2 * w1[l + 512];
#pragma unroll
    for (int off = 32; off; off >>= 1) {
        d0 += __shfl_down(d0, off, 64);
        d1 += __shfl_down(d1, off, 64);
    }
    if (!lane) { redc[0][wid] = d0; redc[1][wid] = d1; }
    __syncthreads();
    if (threadIdx.x == 0) {
        float a = redc[0][0] + redc[0][1] + redc[0][2] + redc[0][3];
        float c = redc[1][0] + redc[1][1] + redc[1][2] + redc[1][3];
        if (which) { c6[b * kR + r] = a; c7[b * kR + r] = c; }
        else       { c4[b * kR + r] = a; c5[b * kR + r] = c; }
    }
}

// ---- 8. t vectors ----
__global__ __launch_bounds__(256) void k_t(const float* __restrict__ embs,
        const float* __restrict__ fsw, const float* __restrict__ bow,
        const float* __restrict__ big4, const float* __restrict__ fc_w,
        float* __restrict__ t4, float* __restrict__ t5,
        float* __restrict__ t6, float* __restrict__ t7)
{
    int idx = blockIdx.x;
    int which = idx >> 10;
    int t = idx & 1023;
    const float* sw = which ? bow : fsw;
    const float* e8 = big4 + (size_t)t * 3072 + (which ? 2304 : 1536);
    const float* w0 = fc_w + (size_t)(which ? 6 : 4) * kH;
    const float* w1 = w0 + kH;
    size_t base = (size_t)t * kH;
    float s0 = 0, s1 = 0;
    for (int h = threadIdx.x; h < kH; h += 256) {
        float x = sw[base + h] + e8[h] + embs[base + h];
        s0 += x * w0[h];
        s1 += x * w1[h];
    }
#pragma unroll
    for (int off = 32; off; off >>= 1) {
        s0 += __shfl_down(s0, off, 64);
        s1 += __shfl_down(s1, off, 64);
    }
    __shared__ float red[2][4];
    int wid = threadIdx.x >> 6;
    if ((threadIdx.x & 63) == 0) { red[0][wid] = s0; red[1][wid] = s1; }
    __syncthreads();
    if (threadIdx.x == 0) {
        float a = red[0][0] + red[0][1] + red[0][2] + red[0][3];
        float c = red[1][0] + red[1][1] + red[1][2] + red[1][3];
        if (which) { t6[t] = a; t7[t] = c; }
        else       { t4[t] = a; t5[t] = c; }
    }
}

// ---- 9. broadcast-add final pair logits ----
__global__ __launch_bounds__(64) void k_final(const float* __restrict__ t4,
        const float* __restrict__ t5, const float* __restrict__ t6,
        const float* __restrict__ t7, const float* __restrict__ c4,
        const float* __restrict__ c5, const float* __restrict__ c6,
        const float* __restrict__ c7, const float* __restrict__ fc_b,
        float* __restrict__ out)
{
    int which = blockIdx.x >> 10;
    int t = blockIdx.x & 1023;
    int b = t >> 8;
    int r = threadIdx.x;
    if (!which) {
        out[OFF_FOS + (size_t)t * kR + r] = t4[t] + c4[b * kR + r] + fc_b[4];
        out[OFF_FOE + (size_t)t * kR + r] = t5[t] + c5[b * kR + r] + fc_b[5];
    } else {
        out[OFF_BSS + (size_t)t * kR + r] = t6[t] + c6[b * kR + r] + fc_b[6];
        out[OFF_BSE + (size_t)t * kR + r] = t7[t] + c7[b * kR + r] + fc_b[7];
    }
}

extern "C" void kernel_launch(void* const* d_in, const int* in_sizes, int n_in,
                              void* d_out, int out_size, void* d_ws, size_t ws_size,
                              hipStream_t stream)
{
    const float* embs       = (const float*)d_in[0];
    const float* h_gs       = (const float*)d_in[1];
    const float* rel_embs   = (const float*)d_in[2];
    const float* rel_transe = (const float*)d_in[3];
    const float* fc_w       = (const float*)d_in[4];
    const float* fc_b       = (const float*)d_in[5];
    const float* Wm         = (const float*)d_in[6];
    const float* Wb         = (const float*)d_in[7];
    const float* V_w        = (const float*)d_in[8];
    const float* V_b        = (const float*)d_in[9];
    const float* rproj_w    = (const float*)d_in[10];
    const float* rproj_b    = (const float*)d_in[11];
    float* out = (float*)d_out;
    float* ws  = (float*)d_ws;

    u16* WtAll   = (u16*)(ws + WS_WTALL);
    u16* rprojT  = (u16*)(ws + WS_RPROJT);
    u16* embsB   = (u16*)(ws + WS_EMBSB);
    u16* relembB = (u16*)(ws + WS_RELEMBB);
    u16* hgsB    = (u16*)(ws + WS_HGSB);
    u16* rtransB = (u16*)(ws + WS_RTRANSB);
    u16* fpadB   = (u16*)(ws + WS_FPADB);
    u16* bpadB   = (u16*)(ws + WS_BPADB);
    u16* brelB   = (u16*)(ws + WS_BRELB);
    float* brel  = ws + WS_BREL;
    float* relpf = ws + WS_RELPF;
    float* relpb = ws + WS_RELPB;
    float* hgpf  = ws + WS_HGPF;
    float* hgpb  = ws + WS_HGPB;
    float* big4  = ws + WS_BIG4;
    float* fsw   = ws + WS_FSW;
    float* bow   = ws + WS_BOW;
    float* fmask = ws + WS_FMASK;
    float* bmask = ws + WS_BMASK;
    float* t4 = ws + WS_T4; float* t5 = ws + WS_T5;
    float* t6 = ws + WS_T6; float* t7 = ws + WS_T7;
    float* c4 = ws + WS_C4; float* c5 = ws + WS_C5;
    float* c6 = ws + WS_C6; float* c7 = ws + WS_C7;
    int* jbuf     = (int*)(ws + WS_AUX);
    int* rankbuf  = jbuf + 2 * kB * kL;
    int* validbuf = rankbuf + 2 * kB * kL;

    // prep
    k_logits<<<kB * kL, 256, 0, stream>>>(embs, fc_w, fc_b, out, embsB);
    k_prep_cast<<<132, 256, 0, stream>>>(rel_embs, h_gs, rel_transe, relembB, hgsB, rtransB);
    k_prep_w<<<1464, 256, 0, stream>>>(Wm, rproj_w, WtAll, rprojT);
    k_extract_meta<<<2 * kB, 256, 0, stream>>>(out, jbuf, rankbuf, validbuf, fmask, bmask);
    k_span_mean<<<2 * kB * kL, 256, 0, stream>>>(embs, jbuf, rankbuf, validbuf, fpadB, bpadB);

    // L1: small projections (+ brel with bf16 copy)
    {
        GemmBatch bt;
        bt.j[0] = { relembB, WtAll + 2 * HH, Wb + 2 * kH, relpf, nullptr, nullptr, kR, kH, kH, 0 };
        bt.j[1] = { hgsB,    WtAll + 3 * HH, Wb + 3 * kH, hgpf,  nullptr, nullptr, kB, kH, kH, 0 };
        bt.j[2] = { hgsB,    WtAll + 6 * HH, Wb + 6 * kH, hgpb,  nullptr, nullptr, kB, kH, kH, 0 };
        bt.j[3] = { rtransB, rprojT,         rproj_b,     brel,  brelB,   nullptr, kR, 128, kH, 0 };
        k_gemm_mfma<<<dim3(1, 6, 4), 256, 0, stream>>>(bt);
    }
    // L2: relpb = brel @ Wm5
    {
        GemmBatch bt;
        bt.j[0] = { brelB, WtAll + 5 * HH, Wb + 5 * kH, relpb, nullptr, nullptr, kR, kH, kH, 0 };
        bt.j[1] = bt.j[0]; bt.j[2] = bt.j[0]; bt.j[3] = bt.j[0];
        k_gemm_mfma<<<dim3(1, 6, 1), 256, 0, stream>>>(bt);
    }
    // L3: big4 = embs @ {Wm4, Wm7, Wm8, Wm9}
    {
        GemmBatch bt;
        const int midx[4] = { 4, 7, 8, 9 };
        for (int z = 0; z < 4; z++)
            bt.j[z] = { embsB, WtAll + (size_t)midx[z] * HH, Wb + (size_t)midx[z] * kH,
                        big4, nullptr, nullptr, kB * kL, kH, 4 * kH, z * kH };
        k_gemm_mfma<<<dim3(8, 6, 4), 256, 0, stream>>>(bt);
    }
    // L4: masked pad GEMMs
    {
        GemmBatch bt;
        bt.j[0] = { fpadB, WtAll + 0 * HH, Wb + 0 * kH, fsw, nullptr, fmask, kB * kL, kH, kH, 0 };
        bt.j[1] = { bpadB, WtAll + 1 * HH, Wb + 1 * kH, bow, nullptr, bmask, kB * kL, kH, kH, 0 };
        bt.j[2] = bt.j[0]; bt.j[3] = bt.j[0];
        k_gemm_mfma<<<dim3(8, 6, 2), 256, 0, stream>>>(bt);
    }

    k_attn<<<2 * kB * kR, 256, 0, stream>>>(embs, big4, relpf, relpb, hgpf, hgpb,
                                            V_w, V_b, fc_w, c4, c5, c6, c7);
    k_t<<<2 * kB * kL, 256, 0, stream>>>(embs, fsw, bow, big4, fc_w, t4, t5, t6, t7);
    k_final<<<2 * kB * kL, 64, 0, stream>>>(t4, t5, t6, t7, c4, c5, c6, c7, fc_b, out);
}

// Round 4
// 183.583 us; speedup vs baseline: 7.3468x; 1.2433x over previous
//
#include <hip/hip_runtime.h>
#include <cstddef>

using u16 = unsigned short;
typedef __attribute__((ext_vector_type(8))) short bf16x8;
typedef __attribute__((ext_vector_type(4))) float f32x4;

constexpr int kB = 4, kL = 256, kR = 64, kH = 768, kTE = 100;
constexpr size_t HH = (size_t)kH * kH;

// ---- output offsets (floats) in return order ----
constexpr size_t OFF_FSS = 0;
constexpr size_t OFF_FSE = OFF_FSS + kB * kL;
constexpr size_t OFF_FOS = OFF_FSE + kB * kL;
constexpr size_t OFF_FOE = OFF_FOS + (size_t)kB * kL * kR;
constexpr size_t OFF_BOS = OFF_FOE + (size_t)kB * kL * kR;
constexpr size_t OFF_BOE = OFF_BOS + kB * kL;
constexpr size_t OFF_BSS = OFF_BOE + kB * kL;
constexpr size_t OFF_BSE = OFF_BSS + (size_t)kB * kL * kR;

// ---- workspace layout (float units) ----
constexpr size_t WS_WTALL   = 0;                                   // 10xHH u16
constexpr size_t WS_RPROJT  = WS_WTALL   + 10 * HH / 2;            // 768x128 u16
constexpr size_t WS_EMBSB   = WS_RPROJT  + (768 * 128) / 2;        // 1024x768 u16
constexpr size_t WS_RELEMBB = WS_EMBSB   + (1024 * 768) / 2;       // 64x768 u16
constexpr size_t WS_HGSB    = WS_RELEMBB + (64 * 768) / 2;         // 4x768 u16
constexpr size_t WS_RTRANSB = WS_HGSB    + (4 * 768) / 2;          // 64x128 u16
constexpr size_t WS_FPADB   = WS_RTRANSB + (64 * 128) / 2;         // 1024x768 u16 (dead after gemmA)
constexpr size_t WS_BPADB   = WS_FPADB   + (1024 * 768) / 2;       // 1024x768 u16 (dead after gemmA)
constexpr size_t WS_BRELB   = WS_BPADB   + (1024 * 768) / 2;       // 64x768 u16
constexpr size_t WS_EMBST   = WS_BRELB   + (64 * 768) / 2;         // 4x768x256 u16
constexpr size_t WS_TOKPB   = WS_EMBST   + (4 * 768 * 256) / 2;    // 2x1024x768 u16
constexpr size_t WS_RELPF   = WS_TOKPB   + (2 * 1024 * 768) / 2;   // 64x768 f32
constexpr size_t WS_RELPB   = WS_RELPF   + 64 * 768;
constexpr size_t WS_HGPF    = WS_RELPB   + 64 * 768;               // 4x768 f32
constexpr size_t WS_HGPB    = WS_HGPF    + 4 * 768;
constexpr size_t WS_EMB8    = WS_HGPB    + 4 * 768;                // 1024x768 f32
constexpr size_t WS_EMB9    = WS_EMB8    + 1024 * 768;
constexpr size_t WS_FSW     = WS_EMB9    + 1024 * 768;
constexpr size_t WS_BOW     = WS_FSW     + 1024 * 768;
constexpr size_t WS_ZB      = WS_BOW     + 1024 * 768;             // 768 zeros
constexpr size_t WS_FMASK   = WS_ZB      + 768;
constexpr size_t WS_BMASK   = WS_FMASK   + 1024;
constexpr size_t WS_T4      = WS_BMASK   + 1024;
constexpr size_t WS_T5      = WS_T4 + 1024;
constexpr size_t WS_T6      = WS_T5 + 1024;
constexpr size_t WS_T7      = WS_T6 + 1024;
constexpr size_t WS_C4      = WS_T7 + 1024;
constexpr size_t WS_C5      = WS_C4 + 256;
constexpr size_t WS_C6      = WS_C5 + 256;
constexpr size_t WS_C7      = WS_C6 + 256;
constexpr size_t WS_AUX     = WS_C7 + 256;    // int region
// aliases over dead pad regions (gemmA has consumed fpadB/bpadB before these are written).
// NOTE: pad rows >= num are stale garbage on timed replays (may decode as bf16 Inf/NaN);
// the GEMM epilogue must SELECT on rowmask, never multiply (0*Inf=NaN).
constexpr size_t WS_CFB     = WS_FPADB;       // 512x768 f32
constexpr size_t WS_VRAW    = WS_BPADB;       // 512x256 f32
constexpr size_t WS_ABUF    = WS_BPADB + 512 * 256;   // 512x256 u16

__device__ inline float fast_rcp(float x) {
#if __has_builtin(__builtin_amdgcn_rcpf)
    return __builtin_amdgcn_rcpf(x);
#else
    return 1.f / x;
#endif
}
__device__ inline float fast_tanh(float x) {
    return 1.f - 2.f * fast_rcp(__expf(2.f * x) + 1.f);
}
__device__ inline u16 f2bf(float x) {   // RNE
    union { float f; unsigned u; } v; v.f = x;
    unsigned r = v.u + 0x7FFFu + ((v.u >> 16) & 1u);
    return (u16)(r >> 16);
}
__device__ inline float bf2f(u16 x) {
    union { unsigned u; float f; } v; v.u = ((unsigned)x) << 16;
    return v.f;
}

// ---- 1. per-token fc logits (fp32 exact: threshold source) + embs bf16 cast ----
__global__ __launch_bounds__(256) void k_logits(const float* __restrict__ embs,
        const float* __restrict__ fc_w, const float* __restrict__ fc_b,
        float* __restrict__ out, u16* __restrict__ embsB)
{
    int t = blockIdx.x;
    const float* e = embs + (size_t)t * kH;
    float s0 = 0, s1 = 0, s2 = 0, s3 = 0;
    for (int h = threadIdx.x; h < kH; h += 256) {
        float x = e[h];
        embsB[(size_t)t * kH + h] = f2bf(x);
        s0 += x * fc_w[0 * kH + h];
        s1 += x * fc_w[1 * kH + h];
        s2 += x * fc_w[2 * kH + h];
        s3 += x * fc_w[3 * kH + h];
    }
#pragma unroll
    for (int off = 32; off; off >>= 1) {
        s0 += __shfl_down(s0, off, 64);
        s1 += __shfl_down(s1, off, 64);
        s2 += __shfl_down(s2, off, 64);
        s3 += __shfl_down(s3, off, 64);
    }
    __shared__ float red[4][4];
    int wid = threadIdx.x >> 6;
    if ((threadIdx.x & 63) == 0) {
        red[0][wid] = s0; red[1][wid] = s1; red[2][wid] = s2; red[3][wid] = s3;
    }
    __syncthreads();
    if (threadIdx.x == 0) {
        out[OFF_FSS + t] = red[0][0] + red[0][1] + red[0][2] + red[0][3] + fc_b[0];
        out[OFF_FSE + t] = red[1][0] + red[1][1] + red[1][2] + red[1][3] + fc_b[1];
        out[OFF_BOS + t] = red[2][0] + red[2][1] + red[2][2] + red[2][3] + fc_b[2];
        out[OFF_BOE + t] = red[3][0] + red[3][1] + red[3][2] + red[3][3] + fc_b[3];
    }
}

// ---- 2. misc bf16 casts + zero-bias init ----
__global__ __launch_bounds__(256) void k_prep_cast(const float* __restrict__ rel_embs,
        const float* __restrict__ h_gs, const float* __restrict__ rel_transe,
        u16* __restrict__ relembB, u16* __restrict__ hgsB, u16* __restrict__ rtransB,
        float* __restrict__ zb)
{
    int bx = blockIdx.x, t = threadIdx.x;
    if (bx < 64) {
        for (int h = t; h < kH; h += 256) relembB[bx * kH + h] = f2bf(rel_embs[bx * kH + h]);
    } else if (bx < 68) {
        int r = bx - 64;
        for (int h = t; h < kH; h += 256) hgsB[r * kH + h] = f2bf(h_gs[r * kH + h]);
    } else if (bx < 132) {
        int r = bx - 68;
        if (t < 128) rtransB[r * 128 + t] = (t < kTE) ? f2bf(rel_transe[r * kTE + t]) : (u16)0;
    } else {
        for (int h = t; h < kH; h += 256) zb[h] = 0.f;
    }
}

// ---- 3. weight transposes: Wt[n][k] = W[k][n], bf16 out ----
__global__ __launch_bounds__(256) void k_prep_w(const float* __restrict__ Wm,
        const float* __restrict__ rproj_w, u16* __restrict__ WtAll, u16* __restrict__ rprojT)
{
    __shared__ float tl[64][65];
    int bx = blockIdx.x, t = threadIdx.x;
    const float* src; u16* dst; int kt, nt, dstStride, srcRows;
    if (bx < 1440) {
        int mi = bx / 144, tile = bx % 144;
        kt = (tile / 12) * 64; nt = (tile % 12) * 64;
        src = Wm + (size_t)mi * HH; dst = WtAll + (size_t)mi * HH;
        dstStride = kH; srcRows = kH;
    } else {
        int tt = bx - 1440;
        kt = (tt / 12) * 64; nt = (tt % 12) * 64;
        src = rproj_w; dst = rprojT; dstStride = 128; srcRows = kTE;
    }
    int r = t >> 2, cq = (t & 3) * 16;
    int row = kt + r;
#pragma unroll
    for (int q = 0; q < 4; q++) {
        float4 v = make_float4(0.f, 0.f, 0.f, 0.f);
        if (row < srcRows) v = *(const float4*)(src + (size_t)row * kH + nt + cq + q * 4);
        tl[r][cq + q * 4 + 0] = v.x;
        tl[r][cq + q * 4 + 1] = v.y;
        tl[r][cq + q * 4 + 2] = v.z;
        tl[r][cq + q * 4 + 3] = v.w;
    }
    __syncthreads();
    u16* drow = dst + (size_t)(nt + r) * dstStride + kt + cq;
#pragma unroll
    for (int j = 0; j < 16; j++) drow[j] = f2bf(tl[cq + j][r]);
}

// ---- 3b. embs transpose to embsT[b][h][l] bf16 ----
__global__ __launch_bounds__(256) void k_embsT(const u16* __restrict__ embsB,
        u16* __restrict__ embsT)
{
    __shared__ u16 tl[64][66];
    int b = blockIdx.x / 48, rem = blockIdx.x % 48;
    int h0 = (rem / 4) * 64, l0 = (rem % 4) * 64;
    int r = threadIdx.x >> 2, cq = (threadIdx.x & 3) * 16;
    const u16* src = embsB + (size_t)(b * kL + l0 + r) * kH + h0 + cq;
#pragma unroll
    for (int j = 0; j < 16; j++) tl[r][cq + j] = src[j];
    __syncthreads();
    u16* dst = embsT + (size_t)b * kH * kL + (size_t)(h0 + r) * kL + l0 + cq;
#pragma unroll
    for (int j = 0; j < 16; j++) dst[j] = tl[cq + j][r];
}

// ---- 4. span extraction metadata ----
__global__ __launch_bounds__(256) void k_extract_meta(const float* __restrict__ out,
        int* __restrict__ jbuf, int* __restrict__ rankbuf, int* __restrict__ validbuf,
        float* __restrict__ fmask, float* __restrict__ bmask)
{
    int which = blockIdx.x >> 2;
    int b = blockIdx.x & 3;
    int i = threadIdx.x;
    const float* slog = out + (which ? OFF_BOS : OFF_FSS) + (size_t)b * kL;
    const float* elog = out + (which ? OFF_BOE : OFF_FSE) + (size_t)b * kL;
    float sv = slog[i], ev = elog[i];
    bool st = (1.f / (1.f + __expf(-sv)) > 0.5f);
    bool en = (1.f / (1.f + __expf(-ev)) > 0.5f);

    __shared__ int sm[kL];
    __shared__ int ps[kL];
    sm[i] = en ? i : kL;
    __syncthreads();
    for (int step = 1; step < kL; step <<= 1) {
        int v = (i + step < kL) ? sm[i + step] : kL;
        __syncthreads();
        sm[i] = min(sm[i], v);
        __syncthreads();
    }
    int next_end = sm[i];
    int validi = (st && next_end < kL) ? 1 : 0;
    ps[i] = validi;
    __syncthreads();
    for (int step = 1; step < kL; step <<= 1) {
        int v = (i >= step) ? ps[i - step] : 0;
        __syncthreads();
        ps[i] += v;
        __syncthreads();
    }
    int rank = ps[i] - 1;
    int num = ps[kL - 1];
    int gbase = (which * kB + b) * kL + i;
    jbuf[gbase] = min(next_end, kL - 1);
    rankbuf[gbase] = rank;
    validbuf[gbase] = validi;
    (which ? bmask : fmask)[b * kL + i] = (i < num) ? 1.f : 0.f;
}

// ---- 5. span means packed by rank (bf16 out) ----
__global__ __launch_bounds__(256) void k_span_mean(const float* __restrict__ embs,
        const int* __restrict__ jbuf, const int* __restrict__ rankbuf,
        const int* __restrict__ validbuf, u16* __restrict__ fpadB, u16* __restrict__ bpadB)
{
    int idx = blockIdx.x;
    int which = idx >> 10;
    int b = (idx >> 8) & 3;
    int i = idx & 255;
    int gbase = (which * kB + b) * kL + i;
    if (!validbuf[gbase]) return;
    int j = jbuf[gbase];
    int rk = rankbuf[gbase];
    int len = j - i + 1;
    float inv = 1.f / (float)len;
    u16* pad = (which ? bpadB : fpadB) + ((size_t)(b * kL + rk)) * kH;
    const float* e = embs + ((size_t)(b * kL + i)) * kH;
    for (int h = threadIdx.x; h < kH; h += 256) {
        float s = 0.f;
        for (int row = 0; row < len; row++) s += e[(size_t)row * kH + h];
        pad[h] = f2bf(s * inv);
    }
}

// ---- 6. batched MFMA GEMM ----
struct GemmJob {
    const u16* A; const u16* Wt; const float* bias;
    float* C; u16* Cbf; const float* rowmask;
    int M; int K; int ldc; int coff;
};
struct GemmBatch { GemmJob j[10]; };

__global__ __launch_bounds__(256) void k_gemm_mfma(GemmBatch batch)
{
    GemmJob jb = batch.j[blockIdx.z];
    if (blockIdx.x * 128 >= jb.M) return;
    __shared__ short Als[128][40];
    __shared__ short Bls[128][40];
    int tid = threadIdx.x;
    int m0 = blockIdx.x * 128;
    int n0 = blockIdx.y * 128;
    int w = tid >> 6, lane = tid & 63;
    int wm = (w >> 1) * 64, wn = (w & 1) * 64;
    int lrow = lane & 15, lhi = lane >> 4;

    f32x4 zero4 = {0.f, 0.f, 0.f, 0.f};
    f32x4 acc[4][4];
#pragma unroll
    for (int i = 0; i < 4; i++)
#pragma unroll
        for (int j = 0; j < 4; j++) acc[i][j] = zero4;

    int srow = tid >> 2;
    int schunk = (tid & 3) * 8;
    int K = jb.K;

    for (int k0 = 0; k0 < K; k0 += 32) {
#pragma unroll
        for (int rph = 0; rph < 2; rph++) {
            int r = srow + rph * 64;
            bf16x8 va;
#pragma unroll
            for (int q = 0; q < 8; q++) va[q] = 0;
            if (m0 + r < jb.M)
                va = *reinterpret_cast<const bf16x8*>(jb.A + (size_t)(m0 + r) * K + k0 + schunk);
            *reinterpret_cast<bf16x8*>(&Als[r][schunk]) = va;
            bf16x8 vb = *reinterpret_cast<const bf16x8*>(jb.Wt + (size_t)(n0 + r) * K + k0 + schunk);
            *reinterpret_cast<bf16x8*>(&Bls[r][schunk]) = vb;
        }
        __syncthreads();
        bf16x8 af[4], bg[4];
#pragma unroll
        for (int i = 0; i < 4; i++) {
            af[i] = *reinterpret_cast<const bf16x8*>(&Als[wm + i * 16 + lrow][lhi * 8]);
            bg[i] = *reinterpret_cast<const bf16x8*>(&Bls[wn + i * 16 + lrow][lhi * 8]);
        }
#pragma unroll
        for (int i = 0; i < 4; i++)
#pragma unroll
            for (int j = 0; j < 4; j++)
                acc[i][j] = __builtin_amdgcn_mfma_f32_16x16x32_bf16(af[i], bg[j], acc[i][j], 0, 0, 0);
        __syncthreads();
    }
#pragma unroll
    for (int i = 0; i < 4; i++) {
#pragma unroll
        for (int j = 0; j < 4; j++) {
            int n = n0 + wn + j * 16 + lrow;
            float bi = jb.bias[n];
#pragma unroll
            for (int q = 0; q < 4; q++) {
                int m = m0 + wm + i * 16 + lhi * 4 + q;
                if (m < jb.M) {
                    float val = acc[i][j][q] + bi;
                    // SELECT, not multiply: masked-out rows may have accumulated
                    // Inf/NaN from stale pad-buffer garbage (0 * Inf = NaN).
                    if (jb.rowmask) val = (jb.rowmask[m] != 0.f) ? val : 0.f;
                    if (jb.C)   jb.C[(size_t)m * jb.ldc + jb.coff + n] = val;
                    if (jb.Cbf) jb.Cbf[(size_t)m * jb.ldc + jb.coff + n] = f2bf(val);
                }
            }
        }
    }
}

// ---- 7. attention scores (split 4-way over l and 4-way over h) ----
__global__ __launch_bounds__(256) void k_score(const u16* __restrict__ tokpB,
        const float* __restrict__ relpf, const float* __restrict__ relpb,
        const float* __restrict__ hgpf, const float* __restrict__ hgpb,
        const float* __restrict__ V_w, const float* __restrict__ V_b,
        float* __restrict__ vraw)
{
    int idx = blockIdx.x;          // 2048
    int which = idx >> 10, b = (idx >> 8) & 3, r = (idx >> 2) & 63, lt = idx & 3;
    const float* relp = (which ? relpb : relpf) + (size_t)r * kH;
    const float* hgp  = (which ? hgpb : hgpf) + (size_t)b * kH;
    __shared__ float addv[4 * 200];   // chunk stride 200 words: banks 0/8/16/24, conflict-free
    __shared__ float vwl[4 * 200];
    for (int h = threadIdx.x; h < kH; h += 256) {
        int c = h / 192, o = h - c * 192;
        addv[c * 200 + o] = relp[h] + hgp[h];
        vwl[c * 200 + o] = V_w[h];
    }
    __syncthreads();
    int ll = threadIdx.x >> 2, hc = threadIdx.x & 3;
    int l = lt * 64 + ll;
    const u16* row = tokpB + ((size_t)which * (kB * kL) + b * kL + l) * kH + hc * 192;
    const float* av = addv + hc * 200;
    const float* vv = vwl + hc * 200;
    float acc = 0.f;
    for (int i = 0; i < 192; i += 8) {
        bf16x8 v8 = *reinterpret_cast<const bf16x8*>(row + i);
#pragma unroll
        for (int j = 0; j < 8; j++)
            acc += fast_tanh(bf2f((u16)v8[j]) + av[i + j]) * vv[i + j];
    }
    acc += __shfl_xor(acc, 1, 64);
    acc += __shfl_xor(acc, 2, 64);
    if (hc == 0)
        vraw[((size_t)(which * kB + b) * kR + r) * kL + l] = acc + V_b[0];
}

// ---- 8. softmax over l, bf16 A out ----
__global__ __launch_bounds__(256) void k_softmax(const float* __restrict__ vraw,
        u16* __restrict__ Abuf)
{
    int wid = threadIdx.x >> 6, lane = threadIdx.x & 63;
    int g = blockIdx.x * 4 + wid;      // 512 rows
    const float* row = vraw + (size_t)g * kL;
    float x[4];
#pragma unroll
    for (int q = 0; q < 4; q++) x[q] = row[lane + 64 * q];
    float m = fmaxf(fmaxf(x[0], x[1]), fmaxf(x[2], x[3]));
#pragma unroll
    for (int off = 32; off; off >>= 1) m = fmaxf(m, __shfl_xor(m, off, 64));
    float p[4], s = 0.f;
#pragma unroll
    for (int q = 0; q < 4; q++) { p[q] = __expf(x[q] - m); s += p[q]; }
#pragma unroll
    for (int off = 32; off; off >>= 1) s += __shfl_xor(s, off, 64);
    float inv = 1.f / s;
#pragma unroll
    for (int q = 0; q < 4; q++) Abuf[(size_t)g * kL + lane + 64 * q] = f2bf(p[q] * inv);
}

// ---- 9. c vectors from Cfb ----
__global__ __launch_bounds__(256) void k_c(const float* __restrict__ Cfb,
        const float* __restrict__ fc_w, float* __restrict__ c4, float* __restrict__ c5,
        float* __restrict__ c6, float* __restrict__ c7)
{
    int p = blockIdx.x;               // 512 = which*256 + b*64 + r
    int which = p >> 8, local = p & 255;
    const float* Cm = Cfb + (size_t)p * kH;
    const float* w0 = fc_w + (size_t)(which ? 6 : 4) * kH;
    const float* w1 = w0 + kH;
    float s0 = 0, s1 = 0;
    for (int h = threadIdx.x; h < kH; h += 256) {
        float x = Cm[h];
        s0 += x * w0[h];
        s1 += x * w1[h];
    }
#pragma unroll
    for (int off = 32; off; off >>= 1) {
        s0 += __shfl_down(s0, off, 64);
        s1 += __shfl_down(s1, off, 64);
    }
    __shared__ float red[2][4];
    int wid = threadIdx.x >> 6;
    if ((threadIdx.x & 63) == 0) { red[0][wid] = s0; red[1][wid] = s1; }
    __syncthreads();
    if (threadIdx.x == 0) {
        float a = red[0][0] + red[0][1] + red[0][2] + red[0][3];
        float c = red[1][0] + red[1][1] + red[1][2] + red[1][3];
        if (which) { c6[local] = a; c7[local] = c; }
        else       { c4[local] = a; c5[local] = c; }
    }
}

// ---- 10. t vectors ----
__global__ __launch_bounds__(256) void k_t(const float* __restrict__ embs,
        const float* __restrict__ fsw, const float* __restrict__ bow,
        const float* __restrict__ emb8, const float* __restrict__ emb9,
        const float* __restrict__ fc_w,
        float* __restrict__ t4, float* __restrict__ t5,
        float* __restrict__ t6, float* __restrict__ t7)
{
    int idx = blockIdx.x;
    int which = idx >> 10;
    int t = idx & 1023;
    const float* sw = which ? bow : fsw;
    const float* e8 = (which ? emb9 : emb8) + (size_t)t * kH;
    const float* w0 = fc_w + (size_t)(which ? 6 : 4) * kH;
    const float* w1 = w0 + kH;
    size_t base = (size_t)t * kH;
    float s0 = 0, s1 = 0;
    for (int h = threadIdx.x; h < kH; h += 256) {
        float x = sw[base + h] + e8[h] + embs[base + h];
        s0 += x * w0[h];
        s1 += x * w1[h];
    }
#pragma unroll
    for (int off = 32; off; off >>= 1) {
        s0 += __shfl_down(s0, off, 64);
        s1 += __shfl_down(s1, off, 64);
    }
    __shared__ float red[2][4];
    int wid = threadIdx.x >> 6;
    if ((threadIdx.x & 63) == 0) { red[0][wid] = s0; red[1][wid] = s1; }
    __syncthreads();
    if (threadIdx.x == 0) {
        float a = red[0][0] + red[0][1] + red[0][2] + red[0][3];
        float c = red[1][0] + red[1][1] + red[1][2] + red[1][3];
        if (which) { t6[t] = a; t7[t] = c; }
        else       { t4[t] = a; t5[t] = c; }
    }
}

// ---- 11. broadcast-add final pair logits ----
__global__ __launch_bounds__(64) void k_final(const float* __restrict__ t4,
        const float* __restrict__ t5, const float* __restrict__ t6,
        const float* __restrict__ t7, const float* __restrict__ c4,
        const float* __restrict__ c5, const float* __restrict__ c6,
        const float* __restrict__ c7, const float* __restrict__ fc_b,
        float* __restrict__ out)
{
    int which = blockIdx.x >> 10;
    int t = blockIdx.x & 1023;
    int b = t >> 8;
    int r = threadIdx.x;
    if (!which) {
        out[OFF_FOS + (size_t)t * kR + r] = t4[t] + c4[b * kR + r] + fc_b[4];
        out[OFF_FOE + (size_t)t * kR + r] = t5[t] + c5[b * kR + r] + fc_b[5];
    } else {
        out[OFF_BSS + (size_t)t * kR + r] = t6[t] + c6[b * kR + r] + fc_b[6];
        out[OFF_BSE + (size_t)t * kR + r] = t7[t] + c7[b * kR + r] + fc_b[7];
    }
}

extern "C" void kernel_launch(void* const* d_in, const int* in_sizes, int n_in,
                              void* d_out, int out_size, void* d_ws, size_t ws_size,
                              hipStream_t stream)
{
    const float* embs       = (const float*)d_in[0];
    const float* h_gs       = (const float*)d_in[1];
    const float* rel_embs   = (const float*)d_in[2];
    const float* rel_transe = (const float*)d_in[3];
    const float* fc_w       = (const float*)d_in[4];
    const float* fc_b       = (const float*)d_in[5];
    const float* Wm         = (const float*)d_in[6];
    const float* Wb         = (const float*)d_in[7];
    const float* V_w        = (const float*)d_in[8];
    const float* V_b        = (const float*)d_in[9];
    const float* rproj_w    = (const float*)d_in[10];
    const float* rproj_b    = (const float*)d_in[11];
    float* out = (float*)d_out;
    float* ws  = (float*)d_ws;

    u16* WtAll   = (u16*)(ws + WS_WTALL);
    u16* rprojT  = (u16*)(ws + WS_RPROJT);
    u16* embsB   = (u16*)(ws + WS_EMBSB);
    u16* relembB = (u16*)(ws + WS_RELEMBB);
    u16* hgsB    = (u16*)(ws + WS_HGSB);
    u16* rtransB = (u16*)(ws + WS_RTRANSB);
    u16* fpadB   = (u16*)(ws + WS_FPADB);
    u16* bpadB   = (u16*)(ws + WS_BPADB);
    u16* brelB   = (u16*)(ws + WS_BRELB);
    u16* embsT   = (u16*)(ws + WS_EMBST);
    u16* tokpB   = (u16*)(ws + WS_TOKPB);
    float* relpf = ws + WS_RELPF;
    float* relpb = ws + WS_RELPB;
    float* hgpf  = ws + WS_HGPF;
    float* hgpb  = ws + WS_HGPB;
    float* emb8  = ws + WS_EMB8;
    float* emb9  = ws + WS_EMB9;
    float* fsw   = ws + WS_FSW;
    float* bow   = ws + WS_BOW;
    float* zb    = ws + WS_ZB;
    float* fmask = ws + WS_FMASK;
    float* bmask = ws + WS_BMASK;
    float* vraw  = ws + WS_VRAW;
    u16*   Abuf  = (u16*)(ws + WS_ABUF);
    float* Cfb   = ws + WS_CFB;
    float* t4 = ws + WS_T4; float* t5 = ws + WS_T5;
    float* t6 = ws + WS_T6; float* t7 = ws + WS_T7;
    float* c4 = ws + WS_C4; float* c5 = ws + WS_C5;
    float* c6 = ws + WS_C6; float* c7 = ws + WS_C7;
    int* jbuf     = (int*)(ws + WS_AUX);
    int* rankbuf  = jbuf + 2 * kB * kL;
    int* validbuf = rankbuf + 2 * kB * kL;

    // prep
    k_logits<<<kB * kL, 256, 0, stream>>>(embs, fc_w, fc_b, out, embsB);
    k_prep_cast<<<133, 256, 0, stream>>>(rel_embs, h_gs, rel_transe, relembB, hgsB, rtransB, zb);
    k_prep_w<<<1464, 256, 0, stream>>>(Wm, rproj_w, WtAll, rprojT);
    k_embsT<<<192, 256, 0, stream>>>(embsB, embsT);
    k_extract_meta<<<2 * kB, 256, 0, stream>>>(out, jbuf, rankbuf, validbuf, fmask, bmask);
    k_span_mean<<<2 * kB * kL, 256, 0, stream>>>(embs, jbuf, rankbuf, validbuf, fpadB, bpadB);

    // gemmA: all independent GEMMs in one launch (10 jobs)
    {
        GemmBatch bt;
        bt.j[0] = { relembB, WtAll + 2 * HH, Wb + 2 * kH, relpf, nullptr, nullptr, kR, kH, kH, 0 };
        bt.j[1] = { hgsB,    WtAll + 3 * HH, Wb + 3 * kH, hgpf,  nullptr, nullptr, kB, kH, kH, 0 };
        bt.j[2] = { hgsB,    WtAll + 6 * HH, Wb + 6 * kH, hgpb,  nullptr, nullptr, kB, kH, kH, 0 };
        bt.j[3] = { rtransB, rprojT,         rproj_b,     nullptr, brelB, nullptr, kR, 128, kH, 0 };
        bt.j[4] = { embsB,   WtAll + 4 * HH, Wb + 4 * kH, nullptr, tokpB,            nullptr, kB * kL, kH, kH, 0 };
        bt.j[5] = { embsB,   WtAll + 7 * HH, Wb + 7 * kH, nullptr, tokpB + (size_t)kB * kL * kH, nullptr, kB * kL, kH, kH, 0 };
        bt.j[6] = { embsB,   WtAll + 8 * HH, Wb + 8 * kH, emb8, nullptr, nullptr, kB * kL, kH, kH, 0 };
        bt.j[7] = { embsB,   WtAll + 9 * HH, Wb + 9 * kH, emb9, nullptr, nullptr, kB * kL, kH, kH, 0 };
        bt.j[8] = { fpadB,   WtAll + 0 * HH, Wb + 0 * kH, fsw, nullptr, fmask, kB * kL, kH, kH, 0 };
        bt.j[9] = { bpadB,   WtAll + 1 * HH, Wb + 1 * kH, bow, nullptr, bmask, kB * kL, kH, kH, 0 };
        k_gemm_mfma<<<dim3(8, 6, 10), 256, 0, stream>>>(bt);
    }
    // gemmB: relpb = brel @ Wm5 (depends on brelB)
    {
        GemmBatch bt;
        bt.j[0] = { brelB, WtAll + 5 * HH, Wb + 5 * kH, relpb, nullptr, nullptr, kR, kH, kH, 0 };
        k_gemm_mfma<<<dim3(1, 6, 1), 256, 0, stream>>>(bt);
    }

    k_score<<<2048, 256, 0, stream>>>(tokpB, relpf, relpb, hgpf, hgpb, V_w, V_b, vraw);
    k_softmax<<<128, 256, 0, stream>>>(vraw, Abuf);

    // gemmC: C[which,b] = A[which,b] @ embsT[b]^T  (8 jobs, M=64, K=256)
    {
        GemmBatch bt;
        for (int z = 0; z < 8; z++) {
            int which = z >> 2, b = z & 3;
            bt.j[z] = { Abuf + (size_t)z * kR * kL,
                        embsT + (size_t)b * kH * kL,
                        zb,
                        Cfb + (size_t)z * kR * kH, nullptr, nullptr,
                        kR, kL, kH, 0 };
        }
        k_gemm_mfma<<<dim3(1, 6, 8), 256, 0, stream>>>(bt);
    }

    k_c<<<512, 256, 0, stream>>>(Cfb, fc_w, c4, c5, c6, c7);
    k_t<<<2 * kB * kL, 256, 0, stream>>>(embs, fsw, bow, emb8, emb9, fc_w, t4, t5, t6, t7);
    k_final<<<2 * kB * kL, 64, 0, stream>>>(t4, t5, t6, t7, c4, c5, c6, c7, fc_b, out);
}

// Round 5
// 162.612 us; speedup vs baseline: 8.2942x; 1.1290x over previous
//
#include <hip/hip_runtime.h>
#include <cstddef>

using u16 = unsigned short;
typedef __attribute__((ext_vector_type(8))) short bf16x8;
typedef __attribute__((ext_vector_type(4))) short bf16x4;
typedef __attribute__((ext_vector_type(4))) float f32x4;

constexpr int kB = 4, kL = 256, kR = 64, kH = 768, kTE = 100;
constexpr size_t HH = (size_t)kH * kH;

// ---- output offsets (floats) in return order ----
constexpr size_t OFF_FSS = 0;
constexpr size_t OFF_FSE = OFF_FSS + kB * kL;
constexpr size_t OFF_FOS = OFF_FSE + kB * kL;
constexpr size_t OFF_FOE = OFF_FOS + (size_t)kB * kL * kR;
constexpr size_t OFF_BOS = OFF_FOE + (size_t)kB * kL * kR;
constexpr size_t OFF_BOE = OFF_BOS + kB * kL;
constexpr size_t OFF_BSS = OFF_BOE + kB * kL;
constexpr size_t OFF_BSE = OFF_BSS + (size_t)kB * kL * kR;

// ---- workspace layout (float units) ----
constexpr size_t WS_WTALL   = 0;                                   // 10xHH u16
constexpr size_t WS_RPROJT  = WS_WTALL   + 10 * HH / 2;            // 768x128 u16
constexpr size_t WS_EMBSB   = WS_RPROJT  + (768 * 128) / 2;        // 1024x768 u16
constexpr size_t WS_RELEMBB = WS_EMBSB   + (1024 * 768) / 2;       // 64x768 u16
constexpr size_t WS_HGSB    = WS_RELEMBB + (64 * 768) / 2;         // 4x768 u16
constexpr size_t WS_RTRANSB = WS_HGSB    + (4 * 768) / 2;          // 64x128 u16
constexpr size_t WS_FPADB   = WS_RTRANSB + (64 * 128) / 2;         // 1024x768 u16 (dead after gemmA)
constexpr size_t WS_BPADB   = WS_FPADB   + (1024 * 768) / 2;       // 1024x768 u16 (dead after gemmA)
constexpr size_t WS_BRELB   = WS_BPADB   + (1024 * 768) / 2;       // 64x768 u16
constexpr size_t WS_EMBST   = WS_BRELB   + (64 * 768) / 2;         // 4x768x256 u16
constexpr size_t WS_TOKPB   = WS_EMBST   + (4 * 768 * 256) / 2;    // 2x1024x768 u16
constexpr size_t WS_RELPF   = WS_TOKPB   + (2 * 1024 * 768) / 2;   // 64x768 f32
constexpr size_t WS_RELPB   = WS_RELPF   + 64 * 768;
constexpr size_t WS_HGPF    = WS_RELPB   + 64 * 768;               // 4x768 f32
constexpr size_t WS_HGPB    = WS_HGPF    + 4 * 768;
constexpr size_t WS_EMB8    = WS_HGPB    + 4 * 768;                // 1024x768 f32
constexpr size_t WS_EMB9    = WS_EMB8    + 1024 * 768;
constexpr size_t WS_FSW     = WS_EMB9    + 1024 * 768;
constexpr size_t WS_BOW     = WS_FSW     + 1024 * 768;
constexpr size_t WS_ZB      = WS_BOW     + 1024 * 768;             // 768 zeros
constexpr size_t WS_FMASK   = WS_ZB      + 768;
constexpr size_t WS_BMASK   = WS_FMASK   + 1024;
constexpr size_t WS_T4      = WS_BMASK   + 1024;
constexpr size_t WS_T5      = WS_T4 + 1024;
constexpr size_t WS_T6      = WS_T5 + 1024;
constexpr size_t WS_T7      = WS_T6 + 1024;
constexpr size_t WS_C4      = WS_T7 + 1024;
constexpr size_t WS_C5      = WS_C4 + 256;
constexpr size_t WS_C6      = WS_C5 + 256;
constexpr size_t WS_C7      = WS_C6 + 256;
constexpr size_t WS_AUX     = WS_C7 + 256;    // int region
// aliases over dead pad regions (gemmA has consumed fpadB/bpadB before these are written).
// NOTE: pad rows >= num are stale garbage on timed replays (may decode as bf16 Inf/NaN);
// the GEMM epilogue must SELECT on rowmask, never multiply (0*Inf=NaN).
constexpr size_t WS_CFB     = WS_FPADB;       // 512x768 f32
constexpr size_t WS_VRAW    = WS_BPADB;       // 512x256 f32
constexpr size_t WS_ABUF    = WS_BPADB + 512 * 256;   // 512x256 u16

__device__ inline float fast_rcp(float x) {
#if __has_builtin(__builtin_amdgcn_rcpf)
    return __builtin_amdgcn_rcpf(x);
#else
    return 1.f / x;
#endif
}
__device__ inline float fast_exp2(float x) {
#if __has_builtin(__builtin_amdgcn_exp2f)
    return __builtin_amdgcn_exp2f(x);
#else
    return __exp2f(x);
#endif
}
__device__ inline float fast_tanh(float x) {
    return 1.f - 2.f * fast_rcp(__expf(2.f * x) + 1.f);
}
__device__ inline u16 f2bf(float x) {   // RNE
    union { float f; unsigned u; } v; v.f = x;
    unsigned r = v.u + 0x7FFFu + ((v.u >> 16) & 1u);
    return (u16)(r >> 16);
}
__device__ inline float bf2f(u16 x) {
    union { unsigned u; float f; } v; v.u = ((unsigned)x) << 16;
    return v.f;
}

// ---- 1. per-token fc logits (fp32 exact: threshold source) + embs bf16 cast ----
__global__ __launch_bounds__(256) void k_logits(const float* __restrict__ embs,
        const float* __restrict__ fc_w, const float* __restrict__ fc_b,
        float* __restrict__ out, u16* __restrict__ embsB)
{
    int t = blockIdx.x;
    const float* e = embs + (size_t)t * kH;
    float s0 = 0, s1 = 0, s2 = 0, s3 = 0;
    for (int h = threadIdx.x; h < kH; h += 256) {
        float x = e[h];
        embsB[(size_t)t * kH + h] = f2bf(x);
        s0 += x * fc_w[0 * kH + h];
        s1 += x * fc_w[1 * kH + h];
        s2 += x * fc_w[2 * kH + h];
        s3 += x * fc_w[3 * kH + h];
    }
#pragma unroll
    for (int off = 32; off; off >>= 1) {
        s0 += __shfl_down(s0, off, 64);
        s1 += __shfl_down(s1, off, 64);
        s2 += __shfl_down(s2, off, 64);
        s3 += __shfl_down(s3, off, 64);
    }
    __shared__ float red[4][4];
    int wid = threadIdx.x >> 6;
    if ((threadIdx.x & 63) == 0) {
        red[0][wid] = s0; red[1][wid] = s1; red[2][wid] = s2; red[3][wid] = s3;
    }
    __syncthreads();
    if (threadIdx.x == 0) {
        out[OFF_FSS + t] = red[0][0] + red[0][1] + red[0][2] + red[0][3] + fc_b[0];
        out[OFF_FSE + t] = red[1][0] + red[1][1] + red[1][2] + red[1][3] + fc_b[1];
        out[OFF_BOS + t] = red[2][0] + red[2][1] + red[2][2] + red[2][3] + fc_b[2];
        out[OFF_BOE + t] = red[3][0] + red[3][1] + red[3][2] + red[3][3] + fc_b[3];
    }
}

// ---- 2. misc bf16 casts + zero-bias init ----
__global__ __launch_bounds__(256) void k_prep_cast(const float* __restrict__ rel_embs,
        const float* __restrict__ h_gs, const float* __restrict__ rel_transe,
        u16* __restrict__ relembB, u16* __restrict__ hgsB, u16* __restrict__ rtransB,
        float* __restrict__ zb)
{
    int bx = blockIdx.x, t = threadIdx.x;
    if (bx < 64) {
        for (int h = t; h < kH; h += 256) relembB[bx * kH + h] = f2bf(rel_embs[bx * kH + h]);
    } else if (bx < 68) {
        int r = bx - 64;
        for (int h = t; h < kH; h += 256) hgsB[r * kH + h] = f2bf(h_gs[r * kH + h]);
    } else if (bx < 132) {
        int r = bx - 68;
        if (t < 128) rtransB[r * 128 + t] = (t < kTE) ? f2bf(rel_transe[r * kTE + t]) : (u16)0;
    } else {
        for (int h = t; h < kH; h += 256) zb[h] = 0.f;
    }
}

// ---- 3. weight transposes: Wt[n][k] = W[k][n], bf16 out ----
__global__ __launch_bounds__(256) void k_prep_w(const float* __restrict__ Wm,
        const float* __restrict__ rproj_w, u16* __restrict__ WtAll, u16* __restrict__ rprojT)
{
    __shared__ float tl[64][65];
    int bx = blockIdx.x, t = threadIdx.x;
    const float* src; u16* dst; int kt, nt, dstStride, srcRows;
    if (bx < 1440) {
        int mi = bx / 144, tile = bx % 144;
        kt = (tile / 12) * 64; nt = (tile % 12) * 64;
        src = Wm + (size_t)mi * HH; dst = WtAll + (size_t)mi * HH;
        dstStride = kH; srcRows = kH;
    } else {
        int tt = bx - 1440;
        kt = (tt / 12) * 64; nt = (tt % 12) * 64;
        src = rproj_w; dst = rprojT; dstStride = 128; srcRows = kTE;
    }
    int r = t >> 2, cq = (t & 3) * 16;
    int row = kt + r;
#pragma unroll
    for (int q = 0; q < 4; q++) {
        float4 v = make_float4(0.f, 0.f, 0.f, 0.f);
        if (row < srcRows) v = *(const float4*)(src + (size_t)row * kH + nt + cq + q * 4);
        tl[r][cq + q * 4 + 0] = v.x;
        tl[r][cq + q * 4 + 1] = v.y;
        tl[r][cq + q * 4 + 2] = v.z;
        tl[r][cq + q * 4 + 3] = v.w;
    }
    __syncthreads();
    u16* drow = dst + (size_t)(nt + r) * dstStride + kt + cq;
#pragma unroll
    for (int j = 0; j < 16; j++) drow[j] = f2bf(tl[cq + j][r]);
}

// ---- 3b. embs transpose to embsT[b][h][l] bf16 ----
__global__ __launch_bounds__(256) void k_embsT(const u16* __restrict__ embsB,
        u16* __restrict__ embsT)
{
    __shared__ u16 tl[64][66];
    int b = blockIdx.x / 48, rem = blockIdx.x % 48;
    int h0 = (rem / 4) * 64, l0 = (rem % 4) * 64;
    int r = threadIdx.x >> 2, cq = (threadIdx.x & 3) * 16;
    const u16* src = embsB + (size_t)(b * kL + l0 + r) * kH + h0 + cq;
#pragma unroll
    for (int j = 0; j < 16; j++) tl[r][cq + j] = src[j];
    __syncthreads();
    u16* dst = embsT + (size_t)b * kH * kL + (size_t)(h0 + r) * kL + l0 + cq;
#pragma unroll
    for (int j = 0; j < 16; j++) dst[j] = tl[cq + j][r];
}

// ---- 4. span extraction metadata ----
__global__ __launch_bounds__(256) void k_extract_meta(const float* __restrict__ out,
        int* __restrict__ jbuf, int* __restrict__ rankbuf, int* __restrict__ validbuf,
        float* __restrict__ fmask, float* __restrict__ bmask)
{
    int which = blockIdx.x >> 2;
    int b = blockIdx.x & 3;
    int i = threadIdx.x;
    const float* slog = out + (which ? OFF_BOS : OFF_FSS) + (size_t)b * kL;
    const float* elog = out + (which ? OFF_BOE : OFF_FSE) + (size_t)b * kL;
    float sv = slog[i], ev = elog[i];
    bool st = (1.f / (1.f + __expf(-sv)) > 0.5f);
    bool en = (1.f / (1.f + __expf(-ev)) > 0.5f);

    __shared__ int sm[kL];
    __shared__ int ps[kL];
    sm[i] = en ? i : kL;
    __syncthreads();
    for (int step = 1; step < kL; step <<= 1) {
        int v = (i + step < kL) ? sm[i + step] : kL;
        __syncthreads();
        sm[i] = min(sm[i], v);
        __syncthreads();
    }
    int next_end = sm[i];
    int validi = (st && next_end < kL) ? 1 : 0;
    ps[i] = validi;
    __syncthreads();
    for (int step = 1; step < kL; step <<= 1) {
        int v = (i >= step) ? ps[i - step] : 0;
        __syncthreads();
        ps[i] += v;
        __syncthreads();
    }
    int rank = ps[i] - 1;
    int num = ps[kL - 1];
    int gbase = (which * kB + b) * kL + i;
    jbuf[gbase] = min(next_end, kL - 1);
    rankbuf[gbase] = rank;
    validbuf[gbase] = validi;
    (which ? bmask : fmask)[b * kL + i] = (i < num) ? 1.f : 0.f;
}

// ---- 5. span means packed by rank (bf16 out) ----
__global__ __launch_bounds__(256) void k_span_mean(const float* __restrict__ embs,
        const int* __restrict__ jbuf, const int* __restrict__ rankbuf,
        const int* __restrict__ validbuf, u16* __restrict__ fpadB, u16* __restrict__ bpadB)
{
    int idx = blockIdx.x;
    int which = idx >> 10;
    int b = (idx >> 8) & 3;
    int i = idx & 255;
    int gbase = (which * kB + b) * kL + i;
    if (!validbuf[gbase]) return;
    int j = jbuf[gbase];
    int rk = rankbuf[gbase];
    int len = j - i + 1;
    float inv = 1.f / (float)len;
    u16* pad = (which ? bpadB : fpadB) + ((size_t)(b * kL + rk)) * kH;
    const float* e = embs + ((size_t)(b * kL + i)) * kH;
    for (int h = threadIdx.x; h < kH; h += 256) {
        float s = 0.f;
        for (int row = 0; row < len; row++) s += e[(size_t)row * kH + h];
        pad[h] = f2bf(s * inv);
    }
}

// ---- 6. batched MFMA GEMM ----
struct GemmJob {
    const u16* A; const u16* Wt; const float* bias;
    float* C; u16* Cbf; const float* rowmask;
    int M; int K; int ldc; int coff;
};
struct GemmBatch { GemmJob j[10]; };

__global__ __launch_bounds__(256) void k_gemm_mfma(GemmBatch batch)
{
    GemmJob jb = batch.j[blockIdx.z];
    if (blockIdx.x * 128 >= jb.M) return;
    __shared__ short Als[128][40];
    __shared__ short Bls[128][40];
    int tid = threadIdx.x;
    int m0 = blockIdx.x * 128;
    int n0 = blockIdx.y * 128;
    int w = tid >> 6, lane = tid & 63;
    int wm = (w >> 1) * 64, wn = (w & 1) * 64;
    int lrow = lane & 15, lhi = lane >> 4;

    f32x4 zero4 = {0.f, 0.f, 0.f, 0.f};
    f32x4 acc[4][4];
#pragma unroll
    for (int i = 0; i < 4; i++)
#pragma unroll
        for (int j = 0; j < 4; j++) acc[i][j] = zero4;

    int srow = tid >> 2;
    int schunk = (tid & 3) * 8;
    int K = jb.K;

    for (int k0 = 0; k0 < K; k0 += 32) {
#pragma unroll
        for (int rph = 0; rph < 2; rph++) {
            int r = srow + rph * 64;
            bf16x8 va;
#pragma unroll
            for (int q = 0; q < 8; q++) va[q] = 0;
            if (m0 + r < jb.M)
                va = *reinterpret_cast<const bf16x8*>(jb.A + (size_t)(m0 + r) * K + k0 + schunk);
            *reinterpret_cast<bf16x8*>(&Als[r][schunk]) = va;
            bf16x8 vb = *reinterpret_cast<const bf16x8*>(jb.Wt + (size_t)(n0 + r) * K + k0 + schunk);
            *reinterpret_cast<bf16x8*>(&Bls[r][schunk]) = vb;
        }
        __syncthreads();
        bf16x8 af[4], bg[4];
#pragma unroll
        for (int i = 0; i < 4; i++) {
            af[i] = *reinterpret_cast<const bf16x8*>(&Als[wm + i * 16 + lrow][lhi * 8]);
            bg[i] = *reinterpret_cast<const bf16x8*>(&Bls[wn + i * 16 + lrow][lhi * 8]);
        }
#pragma unroll
        for (int i = 0; i < 4; i++)
#pragma unroll
            for (int j = 0; j < 4; j++)
                acc[i][j] = __builtin_amdgcn_mfma_f32_16x16x32_bf16(af[i], bg[j], acc[i][j], 0, 0, 0);
        __syncthreads();
    }
#pragma unroll
    for (int i = 0; i < 4; i++) {
#pragma unroll
        for (int j = 0; j < 4; j++) {
            int n = n0 + wn + j * 16 + lrow;
            float bi = jb.bias[n];
#pragma unroll
            for (int q = 0; q < 4; q++) {
                int m = m0 + wm + i * 16 + lhi * 4 + q;
                if (m < jb.M) {
                    float val = acc[i][j][q] + bi;
                    // SELECT, not multiply: masked-out rows may have accumulated
                    // Inf/NaN from stale pad-buffer garbage (0 * Inf = NaN).
                    if (jb.rowmask) val = (jb.rowmask[m] != 0.f) ? val : 0.f;
                    if (jb.C)   jb.C[(size_t)m * jb.ldc + jb.coff + n] = val;
                    if (jb.Cbf) jb.Cbf[(size_t)m * jb.ldc + jb.coff + n] = f2bf(val);
                }
            }
        }
    }
}

// ---- 7. attention scores: block=(which,b,r), lane owns 12-elem h-slice in regs ----
// score(l) = sum_h tanh(tok+rel+hg)*vw = sum_h vw - 2*sum_h vw * r,
// r = 1/(exp2(C*x)+1), C = 2*log2(e). av2/w2/wsum live in VGPRs -> zero LDS traffic.
__global__ __launch_bounds__(512) void k_score(const u16* __restrict__ tokpB,
        const float* __restrict__ relpf, const float* __restrict__ relpb,
        const float* __restrict__ hgpf, const float* __restrict__ hgpb,
        const float* __restrict__ V_w, const float* __restrict__ V_b,
        float* __restrict__ vraw)
{
    constexpr float C = 2.8853900817779268f;   // 2*log2(e)
    int idx = blockIdx.x;            // 512
    int which = idx >> 8, b = (idx >> 6) & 3, r = idx & 63;
    int wid = threadIdx.x >> 6, lane = threadIdx.x & 63;
    int h0 = lane * 12;
    const float* relp = (which ? relpb : relpf) + (size_t)r * kH + h0;
    const float* hgp  = (which ? hgpb : hgpf) + (size_t)b * kH + h0;
    const float* vw   = V_w + h0;

    float av2[12], w2[12], wsum = 0.f;
#pragma unroll
    for (int j = 0; j < 12; j++) {
        av2[j] = C * (relp[j] + hgp[j]);
        float wv = vw[j];
        w2[j] = -2.f * wv;
        wsum += wv;
    }
    float vb = V_b[0];
    const u16* base = tokpB + ((size_t)which * (kB * kL) + b * kL) * kH + h0;
    float* vout = vraw + ((size_t)(which * kB + b) * kR + r) * kL;

    int l0 = wid * 32;
    bf16x4 t0 = *reinterpret_cast<const bf16x4*>(base + (size_t)l0 * kH);
    bf16x4 t1 = *reinterpret_cast<const bf16x4*>(base + (size_t)l0 * kH + 4);
    bf16x4 t2 = *reinterpret_cast<const bf16x4*>(base + (size_t)l0 * kH + 8);
    for (int l = l0; l < l0 + 32; l++) {
        bf16x4 n0, n1, n2;
        if (l + 1 < l0 + 32) {
            const u16* nrow = base + (size_t)(l + 1) * kH;
            n0 = *reinterpret_cast<const bf16x4*>(nrow);
            n1 = *reinterpret_cast<const bf16x4*>(nrow + 4);
            n2 = *reinterpret_cast<const bf16x4*>(nrow + 8);
        }
        float acc = wsum;
#pragma unroll
        for (int j = 0; j < 4; j++) {
            float e0 = fast_exp2(fmaf(bf2f((u16)t0[j]), C, av2[j]));
            acc = fmaf(w2[j], fast_rcp(e0 + 1.f), acc);
            float e1 = fast_exp2(fmaf(bf2f((u16)t1[j]), C, av2[4 + j]));
            acc = fmaf(w2[4 + j], fast_rcp(e1 + 1.f), acc);
            float e2 = fast_exp2(fmaf(bf2f((u16)t2[j]), C, av2[8 + j]));
            acc = fmaf(w2[8 + j], fast_rcp(e2 + 1.f), acc);
        }
#pragma unroll
        for (int off = 32; off; off >>= 1) acc += __shfl_xor(acc, off, 64);
        if (lane == 0) vout[l] = acc + vb;
        t0 = n0; t1 = n1; t2 = n2;
    }
}

// ---- 8. softmax over l, bf16 A out ----
__global__ __launch_bounds__(256) void k_softmax(const float* __restrict__ vraw,
        u16* __restrict__ Abuf)
{
    int wid = threadIdx.x >> 6, lane = threadIdx.x & 63;
    int g = blockIdx.x * 4 + wid;      // 512 rows
    const float* row = vraw + (size_t)g * kL;
    float x[4];
#pragma unroll
    for (int q = 0; q < 4; q++) x[q] = row[lane + 64 * q];
    float m = fmaxf(fmaxf(x[0], x[1]), fmaxf(x[2], x[3]));
#pragma unroll
    for (int off = 32; off; off >>= 1) m = fmaxf(m, __shfl_xor(m, off, 64));
    float p[4], s = 0.f;
#pragma unroll
    for (int q = 0; q < 4; q++) { p[q] = __expf(x[q] - m); s += p[q]; }
#pragma unroll
    for (int off = 32; off; off >>= 1) s += __shfl_xor(s, off, 64);
    float inv = 1.f / s;
#pragma unroll
    for (int q = 0; q < 4; q++) Abuf[(size_t)g * kL + lane + 64 * q] = f2bf(p[q] * inv);
}

// ---- 9. c vectors from Cfb ----
__global__ __launch_bounds__(256) void k_c(const float* __restrict__ Cfb,
        const float* __restrict__ fc_w, float* __restrict__ c4, float* __restrict__ c5,
        float* __restrict__ c6, float* __restrict__ c7)
{
    int p = blockIdx.x;               // 512 = which*256 + b*64 + r
    int which = p >> 8, local = p & 255;
    const float* Cm = Cfb + (size_t)p * kH;
    const float* w0 = fc_w + (size_t)(which ? 6 : 4) * kH;
    const float* w1 = w0 + kH;
    float s0 = 0, s1 = 0;
    for (int h = threadIdx.x; h < kH; h += 256) {
        float x = Cm[h];
        s0 += x * w0[h];
        s1 += x * w1[h];
    }
#pragma unroll
    for (int off = 32; off; off >>= 1) {
        s0 += __shfl_down(s0, off, 64);
        s1 += __shfl_down(s1, off, 64);
    }
    __shared__ float red[2][4];
    int wid = threadIdx.x >> 6;
    if ((threadIdx.x & 63) == 0) { red[0][wid] = s0; red[1][wid] = s1; }
    __syncthreads();
    if (threadIdx.x == 0) {
        float a = red[0][0] + red[0][1] + red[0][2] + red[0][3];
        float c = red[1][0] + red[1][1] + red[1][2] + red[1][3];
        if (which) { c6[local] = a; c7[local] = c; }
        else       { c4[local] = a; c5[local] = c; }
    }
}

// ---- 10. t vectors ----
__global__ __launch_bounds__(256) void k_t(const float* __restrict__ embs,
        const float* __restrict__ fsw, const float* __restrict__ bow,
        const float* __restrict__ emb8, const float* __restrict__ emb9,
        const float* __restrict__ fc_w,
        float* __restrict__ t4, float* __restrict__ t5,
        float* __restrict__ t6, float* __restrict__ t7)
{
    int idx = blockIdx.x;
    int which = idx >> 10;
    int t = idx & 1023;
    const float* sw = which ? bow : fsw;
    const float* e8 = (which ? emb9 : emb8) + (size_t)t * kH;
    const float* w0 = fc_w + (size_t)(which ? 6 : 4) * kH;
    const float* w1 = w0 + kH;
    size_t base = (size_t)t * kH;
    float s0 = 0, s1 = 0;
    for (int h = threadIdx.x; h < kH; h += 256) {
        float x = sw[base + h] + e8[h] + embs[base + h];
        s0 += x * w0[h];
        s1 += x * w1[h];
    }
#pragma unroll
    for (int off = 32; off; off >>= 1) {
        s0 += __shfl_down(s0, off, 64);
        s1 += __shfl_down(s1, off, 64);
    }
    __shared__ float red[2][4];
    int wid = threadIdx.x >> 6;
    if ((threadIdx.x & 63) == 0) { red[0][wid] = s0; red[1][wid] = s1; }
    __syncthreads();
    if (threadIdx.x == 0) {
        float a = red[0][0] + red[0][1] + red[0][2] + red[0][3];
        float c = red[1][0] + red[1][1] + red[1][2] + red[1][3];
        if (which) { t6[t] = a; t7[t] = c; }
        else       { t4[t] = a; t5[t] = c; }
    }
}

// ---- 11. broadcast-add final pair logits ----
__global__ __launch_bounds__(64) void k_final(const float* __restrict__ t4,
        const float* __restrict__ t5, const float* __restrict__ t6,
        const float* __restrict__ t7, const float* __restrict__ c4,
        const float* __restrict__ c5, const float* __restrict__ c6,
        const float* __restrict__ c7, const float* __restrict__ fc_b,
        float* __restrict__ out)
{
    int which = blockIdx.x >> 10;
    int t = blockIdx.x & 1023;
    int b = t >> 8;
    int r = threadIdx.x;
    if (!which) {
        out[OFF_FOS + (size_t)t * kR + r] = t4[t] + c4[b * kR + r] + fc_b[4];
        out[OFF_FOE + (size_t)t * kR + r] = t5[t] + c5[b * kR + r] + fc_b[5];
    } else {
        out[OFF_BSS + (size_t)t * kR + r] = t6[t] + c6[b * kR + r] + fc_b[6];
        out[OFF_BSE + (size_t)t * kR + r] = t7[t] + c7[b * kR + r] + fc_b[7];
    }
}

extern "C" void kernel_launch(void* const* d_in, const int* in_sizes, int n_in,
                              void* d_out, int out_size, void* d_ws, size_t ws_size,
                              hipStream_t stream)
{
    const float* embs       = (const float*)d_in[0];
    const float* h_gs       = (const float*)d_in[1];
    const float* rel_embs   = (const float*)d_in[2];
    const float* rel_transe = (const float*)d_in[3];
    const float* fc_w       = (const float*)d_in[4];
    const float* fc_b       = (const float*)d_in[5];
    const float* Wm         = (const float*)d_in[6];
    const float* Wb         = (const float*)d_in[7];
    const float* V_w        = (const float*)d_in[8];
    const float* V_b        = (const float*)d_in[9];
    const float* rproj_w    = (const float*)d_in[10];
    const float* rproj_b    = (const float*)d_in[11];
    float* out = (float*)d_out;
    float* ws  = (float*)d_ws;

    u16* WtAll   = (u16*)(ws + WS_WTALL);
    u16* rprojT  = (u16*)(ws + WS_RPROJT);
    u16* embsB   = (u16*)(ws + WS_EMBSB);
    u16* relembB = (u16*)(ws + WS_RELEMBB);
    u16* hgsB    = (u16*)(ws + WS_HGSB);
    u16* rtransB = (u16*)(ws + WS_RTRANSB);
    u16* fpadB   = (u16*)(ws + WS_FPADB);
    u16* bpadB   = (u16*)(ws + WS_BPADB);
    u16* brelB   = (u16*)(ws + WS_BRELB);
    u16* embsT   = (u16*)(ws + WS_EMBST);
    u16* tokpB   = (u16*)(ws + WS_TOKPB);
    float* relpf = ws + WS_RELPF;
    float* relpb = ws + WS_RELPB;
    float* hgpf  = ws + WS_HGPF;
    float* hgpb  = ws + WS_HGPB;
    float* emb8  = ws + WS_EMB8;
    float* emb9  = ws + WS_EMB9;
    float* fsw   = ws + WS_FSW;
    float* bow   = ws + WS_BOW;
    float* zb    = ws + WS_ZB;
    float* fmask = ws + WS_FMASK;
    float* bmask = ws + WS_BMASK;
    float* vraw  = ws + WS_VRAW;
    u16*   Abuf  = (u16*)(ws + WS_ABUF);
    float* Cfb   = ws + WS_CFB;
    float* t4 = ws + WS_T4; float* t5 = ws + WS_T5;
    float* t6 = ws + WS_T6; float* t7 = ws + WS_T7;
    float* c4 = ws + WS_C4; float* c5 = ws + WS_C5;
    float* c6 = ws + WS_C6; float* c7 = ws + WS_C7;
    int* jbuf     = (int*)(ws + WS_AUX);
    int* rankbuf  = jbuf + 2 * kB * kL;
    int* validbuf = rankbuf + 2 * kB * kL;

    // prep
    k_logits<<<kB * kL, 256, 0, stream>>>(embs, fc_w, fc_b, out, embsB);
    k_prep_cast<<<133, 256, 0, stream>>>(rel_embs, h_gs, rel_transe, relembB, hgsB, rtransB, zb);
    k_prep_w<<<1464, 256, 0, stream>>>(Wm, rproj_w, WtAll, rprojT);
    k_embsT<<<192, 256, 0, stream>>>(embsB, embsT);
    k_extract_meta<<<2 * kB, 256, 0, stream>>>(out, jbuf, rankbuf, validbuf, fmask, bmask);
    k_span_mean<<<2 * kB * kL, 256, 0, stream>>>(embs, jbuf, rankbuf, validbuf, fpadB, bpadB);

    // gemmA: all independent GEMMs in one launch (10 jobs)
    {
        GemmBatch bt;
        bt.j[0] = { relembB, WtAll + 2 * HH, Wb + 2 * kH, relpf, nullptr, nullptr, kR, kH, kH, 0 };
        bt.j[1] = { hgsB,    WtAll + 3 * HH, Wb + 3 * kH, hgpf,  nullptr, nullptr, kB, kH, kH, 0 };
        bt.j[2] = { hgsB,    WtAll + 6 * HH, Wb + 6 * kH, hgpb,  nullptr, nullptr, kB, kH, kH, 0 };
        bt.j[3] = { rtransB, rprojT,         rproj_b,     nullptr, brelB, nullptr, kR, 128, kH, 0 };
        bt.j[4] = { embsB,   WtAll + 4 * HH, Wb + 4 * kH, nullptr, tokpB,            nullptr, kB * kL, kH, kH, 0 };
        bt.j[5] = { embsB,   WtAll + 7 * HH, Wb + 7 * kH, nullptr, tokpB + (size_t)kB * kL * kH, nullptr, kB * kL, kH, kH, 0 };
        bt.j[6] = { embsB,   WtAll + 8 * HH, Wb + 8 * kH, emb8, nullptr, nullptr, kB * kL, kH, kH, 0 };
        bt.j[7] = { embsB,   WtAll + 9 * HH, Wb + 9 * kH, emb9, nullptr, nullptr, kB * kL, kH, kH, 0 };
        bt.j[8] = { fpadB,   WtAll + 0 * HH, Wb + 0 * kH, fsw, nullptr, fmask, kB * kL, kH, kH, 0 };
        bt.j[9] = { bpadB,   WtAll + 1 * HH, Wb + 1 * kH, bow, nullptr, bmask, kB * kL, kH, kH, 0 };
        k_gemm_mfma<<<dim3(8, 6, 10), 256, 0, stream>>>(bt);
    }
    // gemmB: relpb = brel @ Wm5 (depends on brelB)
    {
        GemmBatch bt;
        bt.j[0] = { brelB, WtAll + 5 * HH, Wb + 5 * kH, relpb, nullptr, nullptr, kR, kH, kH, 0 };
        k_gemm_mfma<<<dim3(1, 6, 1), 256, 0, stream>>>(bt);
    }

    k_score<<<512, 512, 0, stream>>>(tokpB, relpf, relpb, hgpf, hgpb, V_w, V_b, vraw);
    k_softmax<<<128, 256, 0, stream>>>(vraw, Abuf);

    // gemmC: C[which,b] = A[which,b] @ embsT[b]^T  (8 jobs, M=64, K=256)
    {
        GemmBatch bt;
        for (int z = 0; z < 8; z++) {
            int which = z >> 2, b = z & 3;
            bt.j[z] = { Abuf + (size_t)z * kR * kL,
                        embsT + (size_t)b * kH * kL,
                        zb,
                        Cfb + (size_t)z * kR * kH, nullptr, nullptr,
                        kR, kL, kH, 0 };
        }
        k_gemm_mfma<<<dim3(1, 6, 8), 256, 0, stream>>>(bt);
    }

    k_c<<<512, 256, 0, stream>>>(Cfb, fc_w, c4, c5, c6, c7);
    k_t<<<2 * kB * kL, 256, 0, stream>>>(embs, fsw, bow, emb8, emb9, fc_w, t4, t5, t6, t7);
    k_final<<<2 * kB * kL, 64, 0, stream>>>(t4, t5, t6, t7, c4, c5, c6, c7, fc_b, out);
}

// Round 6
// 149.419 us; speedup vs baseline: 9.0266x; 1.0883x over previous
//
#include <hip/hip_runtime.h>
#include <cstddef>

using u16 = unsigned short;
typedef __attribute__((ext_vector_type(8))) short bf16x8;
typedef __attribute__((ext_vector_type(4))) short bf16x4;
typedef __attribute__((ext_vector_type(4))) float f32x4;

constexpr int kB = 4, kL = 256, kR = 64, kH = 768, kTE = 100;
constexpr size_t HH = (size_t)kH * kH;

// ---- output offsets (floats) in return order ----
constexpr size_t OFF_FSS = 0;
constexpr size_t OFF_FSE = OFF_FSS + kB * kL;
constexpr size_t OFF_FOS = OFF_FSE + kB * kL;
constexpr size_t OFF_FOE = OFF_FOS + (size_t)kB * kL * kR;
constexpr size_t OFF_BOS = OFF_FOE + (size_t)kB * kL * kR;
constexpr size_t OFF_BOE = OFF_BOS + kB * kL;
constexpr size_t OFF_BSS = OFF_BOE + kB * kL;
constexpr size_t OFF_BSE = OFF_BSS + (size_t)kB * kL * kR;

// ---- workspace layout (float units) ----
constexpr size_t WS_WTALL   = 0;                                   // 10xHH u16
constexpr size_t WS_RPROJT  = WS_WTALL   + 10 * HH / 2;            // 768x128 u16
constexpr size_t WS_EMBSB   = WS_RPROJT  + (768 * 128) / 2;        // 1024x768 u16
constexpr size_t WS_RELEMBB = WS_EMBSB   + (1024 * 768) / 2;       // 64x768 u16
constexpr size_t WS_HGSB    = WS_RELEMBB + (64 * 768) / 2;         // 4x768 u16
constexpr size_t WS_RTRANSB = WS_HGSB    + (4 * 768) / 2;          // 64x128 u16
constexpr size_t WS_FPADB   = WS_RTRANSB + (64 * 128) / 2;         // 1024x768 u16 (dead after gemmA)
constexpr size_t WS_BPADB   = WS_FPADB   + (1024 * 768) / 2;       // 1024x768 u16 (dead after gemmA)
constexpr size_t WS_BRELB   = WS_BPADB   + (1024 * 768) / 2;       // 64x768 u16
constexpr size_t WS_EMBST   = WS_BRELB   + (64 * 768) / 2;         // 4x768x256 u16
constexpr size_t WS_TOKPB   = WS_EMBST   + (4 * 768 * 256) / 2;    // 2x1024x768 u16
constexpr size_t WS_RELPF   = WS_TOKPB   + (2 * 1024 * 768) / 2;   // 64x768 f32
constexpr size_t WS_RELPB   = WS_RELPF   + 64 * 768;
constexpr size_t WS_HGPF    = WS_RELPB   + 64 * 768;               // 4x768 f32
constexpr size_t WS_HGPB    = WS_HGPF    + 4 * 768;
constexpr size_t WS_EMB8    = WS_HGPB    + 4 * 768;                // 1024x768 f32
constexpr size_t WS_EMB9    = WS_EMB8    + 1024 * 768;
constexpr size_t WS_FSW     = WS_EMB9    + 1024 * 768;
constexpr size_t WS_BOW     = WS_FSW     + 1024 * 768;
constexpr size_t WS_ZB      = WS_BOW     + 1024 * 768;             // 768 zeros
constexpr size_t WS_FMASK   = WS_ZB      + 768;
constexpr size_t WS_BMASK   = WS_FMASK   + 1024;
constexpr size_t WS_T4      = WS_BMASK   + 1024;
constexpr size_t WS_T5      = WS_T4 + 1024;
constexpr size_t WS_T6      = WS_T5 + 1024;
constexpr size_t WS_T7      = WS_T6 + 1024;
constexpr size_t WS_C4      = WS_T7 + 1024;
constexpr size_t WS_C5      = WS_C4 + 256;
constexpr size_t WS_C6      = WS_C5 + 256;
constexpr size_t WS_C7      = WS_C6 + 256;
constexpr size_t WS_AUX     = WS_C7 + 256;    // int region
// aliases over dead pad regions (gemmA has consumed fpadB/bpadB before these are written).
// NOTE: pad rows >= num are stale garbage on timed replays (may decode as bf16 Inf/NaN);
// the GEMM epilogue must SELECT on rowmask, never multiply (0*Inf=NaN).
constexpr size_t WS_CFB     = WS_FPADB;       // 512x768 f32
constexpr size_t WS_VRAW    = WS_BPADB;       // 512x256 f32
constexpr size_t WS_ABUF    = WS_BPADB + 512 * 256;   // 512x256 u16

__device__ inline float fast_rcp(float x) {
#if __has_builtin(__builtin_amdgcn_rcpf)
    return __builtin_amdgcn_rcpf(x);
#else
    return 1.f / x;
#endif
}
__device__ inline float fast_exp2(float x) {
#if __has_builtin(__builtin_amdgcn_exp2f)
    return __builtin_amdgcn_exp2f(x);
#else
    return __exp2f(x);
#endif
}
__device__ inline u16 f2bf(float x) {   // RNE
    union { float f; unsigned u; } v; v.f = x;
    unsigned r = v.u + 0x7FFFu + ((v.u >> 16) & 1u);
    return (u16)(r >> 16);
}
__device__ inline float bf2f(u16 x) {
    union { unsigned u; float f; } v; v.u = ((unsigned)x) << 16;
    return v.f;
}

// ---- 1. per-token fc logits (fp32 exact: threshold source) + embs bf16 cast ----
__global__ __launch_bounds__(256) void k_logits(const float* __restrict__ embs,
        const float* __restrict__ fc_w, const float* __restrict__ fc_b,
        float* __restrict__ out, u16* __restrict__ embsB)
{
    int t = blockIdx.x;
    const float* e = embs + (size_t)t * kH;
    float s0 = 0, s1 = 0, s2 = 0, s3 = 0;
    for (int h = threadIdx.x; h < kH; h += 256) {
        float x = e[h];
        embsB[(size_t)t * kH + h] = f2bf(x);
        s0 += x * fc_w[0 * kH + h];
        s1 += x * fc_w[1 * kH + h];
        s2 += x * fc_w[2 * kH + h];
        s3 += x * fc_w[3 * kH + h];
    }
#pragma unroll
    for (int off = 32; off; off >>= 1) {
        s0 += __shfl_down(s0, off, 64);
        s1 += __shfl_down(s1, off, 64);
        s2 += __shfl_down(s2, off, 64);
        s3 += __shfl_down(s3, off, 64);
    }
    __shared__ float red[4][4];
    int wid = threadIdx.x >> 6;
    if ((threadIdx.x & 63) == 0) {
        red[0][wid] = s0; red[1][wid] = s1; red[2][wid] = s2; red[3][wid] = s3;
    }
    __syncthreads();
    if (threadIdx.x == 0) {
        out[OFF_FSS + t] = red[0][0] + red[0][1] + red[0][2] + red[0][3] + fc_b[0];
        out[OFF_FSE + t] = red[1][0] + red[1][1] + red[1][2] + red[1][3] + fc_b[1];
        out[OFF_BOS + t] = red[2][0] + red[2][1] + red[2][2] + red[2][3] + fc_b[2];
        out[OFF_BOE + t] = red[3][0] + red[3][1] + red[3][2] + red[3][3] + fc_b[3];
    }
}

// ---- 2. misc bf16 casts + zero-bias init ----
__global__ __launch_bounds__(256) void k_prep_cast(const float* __restrict__ rel_embs,
        const float* __restrict__ h_gs, const float* __restrict__ rel_transe,
        u16* __restrict__ relembB, u16* __restrict__ hgsB, u16* __restrict__ rtransB,
        float* __restrict__ zb)
{
    int bx = blockIdx.x, t = threadIdx.x;
    if (bx < 64) {
        for (int h = t; h < kH; h += 256) relembB[bx * kH + h] = f2bf(rel_embs[bx * kH + h]);
    } else if (bx < 68) {
        int r = bx - 64;
        for (int h = t; h < kH; h += 256) hgsB[r * kH + h] = f2bf(h_gs[r * kH + h]);
    } else if (bx < 132) {
        int r = bx - 68;
        if (t < 128) rtransB[r * 128 + t] = (t < kTE) ? f2bf(rel_transe[r * kTE + t]) : (u16)0;
    } else {
        for (int h = t; h < kH; h += 256) zb[h] = 0.f;
    }
}

// ---- 3. weight transposes: Wt[n][k] = W[k][n], bf16 out ----
__global__ __launch_bounds__(256) void k_prep_w(const float* __restrict__ Wm,
        const float* __restrict__ rproj_w, u16* __restrict__ WtAll, u16* __restrict__ rprojT)
{
    __shared__ float tl[64][65];
    int bx = blockIdx.x, t = threadIdx.x;
    const float* src; u16* dst; int kt, nt, dstStride, srcRows;
    if (bx < 1440) {
        int mi = bx / 144, tile = bx % 144;
        kt = (tile / 12) * 64; nt = (tile % 12) * 64;
        src = Wm + (size_t)mi * HH; dst = WtAll + (size_t)mi * HH;
        dstStride = kH; srcRows = kH;
    } else {
        int tt = bx - 1440;
        kt = (tt / 12) * 64; nt = (tt % 12) * 64;
        src = rproj_w; dst = rprojT; dstStride = 128; srcRows = kTE;
    }
    int r = t >> 2, cq = (t & 3) * 16;
    int row = kt + r;
#pragma unroll
    for (int q = 0; q < 4; q++) {
        float4 v = make_float4(0.f, 0.f, 0.f, 0.f);
        if (row < srcRows) v = *(const float4*)(src + (size_t)row * kH + nt + cq + q * 4);
        tl[r][cq + q * 4 + 0] = v.x;
        tl[r][cq + q * 4 + 1] = v.y;
        tl[r][cq + q * 4 + 2] = v.z;
        tl[r][cq + q * 4 + 3] = v.w;
    }
    __syncthreads();
    u16* drow = dst + (size_t)(nt + r) * dstStride + kt + cq;
#pragma unroll
    for (int j = 0; j < 16; j++) drow[j] = f2bf(tl[cq + j][r]);
}

// ---- 3b. embs transpose to embsT[b][h][l] bf16 ----
__global__ __launch_bounds__(256) void k_embsT(const u16* __restrict__ embsB,
        u16* __restrict__ embsT)
{
    __shared__ u16 tl[64][66];
    int b = blockIdx.x / 48, rem = blockIdx.x % 48;
    int h0 = (rem / 4) * 64, l0 = (rem % 4) * 64;
    int r = threadIdx.x >> 2, cq = (threadIdx.x & 3) * 16;
    const u16* src = embsB + (size_t)(b * kL + l0 + r) * kH + h0 + cq;
#pragma unroll
    for (int j = 0; j < 16; j++) tl[r][cq + j] = src[j];
    __syncthreads();
    u16* dst = embsT + (size_t)b * kH * kL + (size_t)(h0 + r) * kL + l0 + cq;
#pragma unroll
    for (int j = 0; j < 16; j++) dst[j] = tl[cq + j][r];
}

// ---- 4. span extraction metadata ----
__global__ __launch_bounds__(256) void k_extract_meta(const float* __restrict__ out,
        int* __restrict__ jbuf, int* __restrict__ rankbuf, int* __restrict__ validbuf,
        float* __restrict__ fmask, float* __restrict__ bmask)
{
    int which = blockIdx.x >> 2;
    int b = blockIdx.x & 3;
    int i = threadIdx.x;
    const float* slog = out + (which ? OFF_BOS : OFF_FSS) + (size_t)b * kL;
    const float* elog = out + (which ? OFF_BOE : OFF_FSE) + (size_t)b * kL;
    float sv = slog[i], ev = elog[i];
    bool st = (1.f / (1.f + __expf(-sv)) > 0.5f);
    bool en = (1.f / (1.f + __expf(-ev)) > 0.5f);

    __shared__ int sm[kL];
    __shared__ int ps[kL];
    sm[i] = en ? i : kL;
    __syncthreads();
    for (int step = 1; step < kL; step <<= 1) {
        int v = (i + step < kL) ? sm[i + step] : kL;
        __syncthreads();
        sm[i] = min(sm[i], v);
        __syncthreads();
    }
    int next_end = sm[i];
    int validi = (st && next_end < kL) ? 1 : 0;
    ps[i] = validi;
    __syncthreads();
    for (int step = 1; step < kL; step <<= 1) {
        int v = (i >= step) ? ps[i - step] : 0;
        __syncthreads();
        ps[i] += v;
        __syncthreads();
    }
    int rank = ps[i] - 1;
    int num = ps[kL - 1];
    int gbase = (which * kB + b) * kL + i;
    jbuf[gbase] = min(next_end, kL - 1);
    rankbuf[gbase] = rank;
    validbuf[gbase] = validi;
    (which ? bmask : fmask)[b * kL + i] = (i < num) ? 1.f : 0.f;
}

// ---- 5. span means packed by rank (bf16 out) ----
__global__ __launch_bounds__(256) void k_span_mean(const float* __restrict__ embs,
        const int* __restrict__ jbuf, const int* __restrict__ rankbuf,
        const int* __restrict__ validbuf, u16* __restrict__ fpadB, u16* __restrict__ bpadB)
{
    int idx = blockIdx.x;
    int which = idx >> 10;
    int b = (idx >> 8) & 3;
    int i = idx & 255;
    int gbase = (which * kB + b) * kL + i;
    if (!validbuf[gbase]) return;
    int j = jbuf[gbase];
    int rk = rankbuf[gbase];
    int len = j - i + 1;
    float inv = 1.f / (float)len;
    u16* pad = (which ? bpadB : fpadB) + ((size_t)(b * kL + rk)) * kH;
    const float* e = embs + ((size_t)(b * kL + i)) * kH;
    for (int h = threadIdx.x; h < kH; h += 256) {
        float s = 0.f;
        for (int row = 0; row < len; row++) s += e[(size_t)row * kH + h];
        pad[h] = f2bf(s * inv);
    }
}

// ---- 6. batched MFMA GEMM, double-buffered + reg-prefetch pipeline, BK=64 ----
// LDS: [2][128][64] shorts per operand = 64KB total. XOR swizzle (slot ^= row&7,
// slot = 16B unit within the 128B row) on BOTH ds_write and ds_read sides:
// read rows 0-15 at fixed slot spread over 8 bank-quads (2-way = free).
struct GemmJob {
    const u16* A; const u16* Wt; const float* bias;
    float* C; u16* Cbf; const float* rowmask;
    int M; int K; int ldc; int coff;
};
struct GemmBatch { GemmJob j[10]; };

__device__ inline int swz(int row, int slot) {   // short-index into [128][64] row-major
    return row * 64 + ((slot ^ (row & 7)) << 3);
}

__global__ __launch_bounds__(256) void k_gemm_mfma(GemmBatch batch)
{
    GemmJob jb = batch.j[blockIdx.z];
    if (blockIdx.x * 128 >= jb.M) return;
    __shared__ short Als[2][128 * 64];
    __shared__ short Bls[2][128 * 64];
    int tid = threadIdx.x;
    int m0 = blockIdx.x * 128;
    int n0 = blockIdx.y * 128;
    int w = tid >> 6, lane = tid & 63;
    int wm = (w >> 1) * 64, wn = (w & 1) * 64;
    int lrow = lane & 15, lhi = lane >> 4;
    int srow = tid >> 2, sc = tid & 3;
    int K = jb.K;
    int T = K >> 6;                 // all K are multiples of 64

    f32x4 zero4 = {0.f, 0.f, 0.f, 0.f};
    f32x4 acc[4][4];
#pragma unroll
    for (int i = 0; i < 4; i++)
#pragma unroll
        for (int j = 0; j < 4; j++) acc[i][j] = zero4;

    bf16x8 pa[4], pb[4];

#define LOADT(k0)                                                                 \
    {                                                                             \
        _Pragma("unroll")                                                         \
        for (int q = 0; q < 4; q++) {                                             \
            int row = srow + 64 * (q >> 1);                                       \
            int kofs = (sc + 4 * (q & 1)) * 8;                                    \
            bf16x8 va;                                                            \
            _Pragma("unroll") for (int z = 0; z < 8; z++) va[z] = 0;              \
            if (m0 + row < jb.M)                                                  \
                va = *reinterpret_cast<const bf16x8*>(                            \
                    jb.A + (size_t)(m0 + row) * K + (k0) + kofs);                 \
            pa[q] = va;                                                           \
            pb[q] = *reinterpret_cast<const bf16x8*>(                             \
                jb.Wt + (size_t)(n0 + row) * K + (k0) + kofs);                    \
        }                                                                         \
    }
#define STORET(buf)                                                               \
    {                                                                             \
        _Pragma("unroll")                                                         \
        for (int q = 0; q < 4; q++) {                                             \
            int row = srow + 64 * (q >> 1);                                       \
            int slot = sc + 4 * (q & 1);                                          \
            *reinterpret_cast<bf16x8*>(&Als[buf][swz(row, slot)]) = pa[q];        \
            *reinterpret_cast<bf16x8*>(&Bls[buf][swz(row, slot)]) = pb[q];        \
        }                                                                         \
    }

    LOADT(0);
    STORET(0);
    __syncthreads();
    int cur = 0;
    for (int t = 0; t < T; t++) {
        if (t + 1 < T) LOADT((t + 1) << 6);     // issue next-tile loads early
#pragma unroll
        for (int sub = 0; sub < 2; sub++) {
            bf16x8 af[4], bg[4];
#pragma unroll
            for (int i = 0; i < 4; i++) {
                af[i] = *reinterpret_cast<const bf16x8*>(
                    &Als[cur][swz(wm + i * 16 + lrow, sub * 4 + lhi)]);
                bg[i] = *reinterpret_cast<const bf16x8*>(
                    &Bls[cur][swz(wn + i * 16 + lrow, sub * 4 + lhi)]);
            }
#pragma unroll
            for (int i = 0; i < 4; i++)
#pragma unroll
                for (int j = 0; j < 4; j++)
                    acc[i][j] = __builtin_amdgcn_mfma_f32_16x16x32_bf16(af[i], bg[j], acc[i][j], 0, 0, 0);
        }
        if (t + 1 < T) STORET(cur ^ 1);         // write to alternate buffer
        __syncthreads();                        // one barrier per iter (dbuf-safe)
        cur ^= 1;
    }
#undef LOADT
#undef STORET

#pragma unroll
    for (int i = 0; i < 4; i++) {
#pragma unroll
        for (int j = 0; j < 4; j++) {
            int n = n0 + wn + j * 16 + lrow;
            float bi = jb.bias[n];
#pragma unroll
            for (int q = 0; q < 4; q++) {
                int m = m0 + wm + i * 16 + lhi * 4 + q;
                if (m < jb.M) {
                    float val = acc[i][j][q] + bi;
                    // SELECT, not multiply: masked-out rows may have accumulated
                    // Inf/NaN from stale pad-buffer garbage (0 * Inf = NaN).
                    if (jb.rowmask) val = (jb.rowmask[m] != 0.f) ? val : 0.f;
                    if (jb.C)   jb.C[(size_t)m * jb.ldc + jb.coff + n] = val;
                    if (jb.Cbf) jb.Cbf[(size_t)m * jb.ldc + jb.coff + n] = f2bf(val);
                }
            }
        }
    }
}

// ---- 7. attention scores: block=(which,b,r), lane owns 12-elem h-slice in regs ----
__global__ __launch_bounds__(512) void k_score(const u16* __restrict__ tokpB,
        const float* __restrict__ relpf, const float* __restrict__ relpb,
        const float* __restrict__ hgpf, const float* __restrict__ hgpb,
        const float* __restrict__ V_w, const float* __restrict__ V_b,
        float* __restrict__ vraw)
{
    constexpr float C = 2.8853900817779268f;   // 2*log2(e)
    int idx = blockIdx.x;            // 512
    int which = idx >> 8, b = (idx >> 6) & 3, r = idx & 63;
    int wid = threadIdx.x >> 6, lane = threadIdx.x & 63;
    int h0 = lane * 12;
    const float* relp = (which ? relpb : relpf) + (size_t)r * kH + h0;
    const float* hgp  = (which ? hgpb : hgpf) + (size_t)b * kH + h0;
    const float* vw   = V_w + h0;

    float av2[12], w2[12], wsum = 0.f;
#pragma unroll
    for (int j = 0; j < 12; j++) {
        av2[j] = C * (relp[j] + hgp[j]);
        float wv = vw[j];
        w2[j] = -2.f * wv;
        wsum += wv;
    }
    float vb = V_b[0];
    const u16* base = tokpB + ((size_t)which * (kB * kL) + b * kL) * kH + h0;
    float* vout = vraw + ((size_t)(which * kB + b) * kR + r) * kL;

    int l0 = wid * 32;
    bf16x4 t0 = *reinterpret_cast<const bf16x4*>(base + (size_t)l0 * kH);
    bf16x4 t1 = *reinterpret_cast<const bf16x4*>(base + (size_t)l0 * kH + 4);
    bf16x4 t2 = *reinterpret_cast<const bf16x4*>(base + (size_t)l0 * kH + 8);
    for (int l = l0; l < l0 + 32; l++) {
        bf16x4 n0, n1, n2;
        if (l + 1 < l0 + 32) {
            const u16* nrow = base + (size_t)(l + 1) * kH;
            n0 = *reinterpret_cast<const bf16x4*>(nrow);
            n1 = *reinterpret_cast<const bf16x4*>(nrow + 4);
            n2 = *reinterpret_cast<const bf16x4*>(nrow + 8);
        }
        float acc = wsum;
#pragma unroll
        for (int j = 0; j < 4; j++) {
            float e0 = fast_exp2(fmaf(bf2f((u16)t0[j]), C, av2[j]));
            acc = fmaf(w2[j], fast_rcp(e0 + 1.f), acc);
            float e1 = fast_exp2(fmaf(bf2f((u16)t1[j]), C, av2[4 + j]));
            acc = fmaf(w2[4 + j], fast_rcp(e1 + 1.f), acc);
            float e2 = fast_exp2(fmaf(bf2f((u16)t2[j]), C, av2[8 + j]));
            acc = fmaf(w2[8 + j], fast_rcp(e2 + 1.f), acc);
        }
#pragma unroll
        for (int off = 32; off; off >>= 1) acc += __shfl_xor(acc, off, 64);
        if (lane == 0) vout[l] = acc + vb;
        t0 = n0; t1 = n1; t2 = n2;
    }
}

// ---- 8. softmax over l, bf16 A out ----
__global__ __launch_bounds__(256) void k_softmax(const float* __restrict__ vraw,
        u16* __restrict__ Abuf)
{
    int wid = threadIdx.x >> 6, lane = threadIdx.x & 63;
    int g = blockIdx.x * 4 + wid;      // 512 rows
    const float* row = vraw + (size_t)g * kL;
    float x[4];
#pragma unroll
    for (int q = 0; q < 4; q++) x[q] = row[lane + 64 * q];
    float m = fmaxf(fmaxf(x[0], x[1]), fmaxf(x[2], x[3]));
#pragma unroll
    for (int off = 32; off; off >>= 1) m = fmaxf(m, __shfl_xor(m, off, 64));
    float p[4], s = 0.f;
#pragma unroll
    for (int q = 0; q < 4; q++) { p[q] = __expf(x[q] - m); s += p[q]; }
#pragma unroll
    for (int off = 32; off; off >>= 1) s += __shfl_xor(s, off, 64);
    float inv = 1.f / s;
#pragma unroll
    for (int q = 0; q < 4; q++) Abuf[(size_t)g * kL + lane + 64 * q] = f2bf(p[q] * inv);
}

// ---- 9. c vectors from Cfb ----
__global__ __launch_bounds__(256) void k_c(const float* __restrict__ Cfb,
        const float* __restrict__ fc_w, float* __restrict__ c4, float* __restrict__ c5,
        float* __restrict__ c6, float* __restrict__ c7)
{
    int p = blockIdx.x;               // 512 = which*256 + b*64 + r
    int which = p >> 8, local = p & 255;
    const float* Cm = Cfb + (size_t)p * kH;
    const float* w0 = fc_w + (size_t)(which ? 6 : 4) * kH;
    const float* w1 = w0 + kH;
    float s0 = 0, s1 = 0;
    for (int h = threadIdx.x; h < kH; h += 256) {
        float x = Cm[h];
        s0 += x * w0[h];
        s1 += x * w1[h];
    }
#pragma unroll
    for (int off = 32; off; off >>= 1) {
        s0 += __shfl_down(s0, off, 64);
        s1 += __shfl_down(s1, off, 64);
    }
    __shared__ float red[2][4];
    int wid = threadIdx.x >> 6;
    if ((threadIdx.x & 63) == 0) { red[0][wid] = s0; red[1][wid] = s1; }
    __syncthreads();
    if (threadIdx.x == 0) {
        float a = red[0][0] + red[0][1] + red[0][2] + red[0][3];
        float c = red[1][0] + red[1][1] + red[1][2] + red[1][3];
        if (which) { c6[local] = a; c7[local] = c; }
        else       { c4[local] = a; c5[local] = c; }
    }
}

// ---- 10. t vectors ----
__global__ __launch_bounds__(256) void k_t(const float* __restrict__ embs,
        const float* __restrict__ fsw, const float* __restrict__ bow,
        const float* __restrict__ emb8, const float* __restrict__ emb9,
        const float* __restrict__ fc_w,
        float* __restrict__ t4, float* __restrict__ t5,
        float* __restrict__ t6, float* __restrict__ t7)
{
    int idx = blockIdx.x;
    int which = idx >> 10;
    int t = idx & 1023;
    const float* sw = which ? bow : fsw;
    const float* e8 = (which ? emb9 : emb8) + (size_t)t * kH;
    const float* w0 = fc_w + (size_t)(which ? 6 : 4) * kH;
    const float* w1 = w0 + kH;
    size_t base = (size_t)t * kH;
    float s0 = 0, s1 = 0;
    for (int h = threadIdx.x; h < kH; h += 256) {
        float x = sw[base + h] + e8[h] + embs[base + h];
        s0 += x * w0[h];
        s1 += x * w1[h];
    }
#pragma unroll
    for (int off = 32; off; off >>= 1) {
        s0 += __shfl_down(s0, off, 64);
        s1 += __shfl_down(s1, off, 64);
    }
    __shared__ float red[2][4];
    int wid = threadIdx.x >> 6;
    if ((threadIdx.x & 63) == 0) { red[0][wid] = s0; red[1][wid] = s1; }
    __syncthreads();
    if (threadIdx.x == 0) {
        float a = red[0][0] + red[0][1] + red[0][2] + red[0][3];
        float c = red[1][0] + red[1][1] + red[1][2] + red[1][3];
        if (which) { t6[t] = a; t7[t] = c; }
        else       { t4[t] = a; t5[t] = c; }
    }
}

// ---- 11. broadcast-add final pair logits ----
__global__ __launch_bounds__(64) void k_final(const float* __restrict__ t4,
        const float* __restrict__ t5, const float* __restrict__ t6,
        const float* __restrict__ t7, const float* __restrict__ c4,
        const float* __restrict__ c5, const float* __restrict__ c6,
        const float* __restrict__ c7, const float* __restrict__ fc_b,
        float* __restrict__ out)
{
    int which = blockIdx.x >> 10;
    int t = blockIdx.x & 1023;
    int b = t >> 8;
    int r = threadIdx.x;
    if (!which) {
        out[OFF_FOS + (size_t)t * kR + r] = t4[t] + c4[b * kR + r] + fc_b[4];
        out[OFF_FOE + (size_t)t * kR + r] = t5[t] + c5[b * kR + r] + fc_b[5];
    } else {
        out[OFF_BSS + (size_t)t * kR + r] = t6[t] + c6[b * kR + r] + fc_b[6];
        out[OFF_BSE + (size_t)t * kR + r] = t7[t] + c7[b * kR + r] + fc_b[7];
    }
}

extern "C" void kernel_launch(void* const* d_in, const int* in_sizes, int n_in,
                              void* d_out, int out_size, void* d_ws, size_t ws_size,
                              hipStream_t stream)
{
    const float* embs       = (const float*)d_in[0];
    const float* h_gs       = (const float*)d_in[1];
    const float* rel_embs   = (const float*)d_in[2];
    const float* rel_transe = (const float*)d_in[3];
    const float* fc_w       = (const float*)d_in[4];
    const float* fc_b       = (const float*)d_in[5];
    const float* Wm         = (const float*)d_in[6];
    const float* Wb         = (const float*)d_in[7];
    const float* V_w        = (const float*)d_in[8];
    const float* V_b        = (const float*)d_in[9];
    const float* rproj_w    = (const float*)d_in[10];
    const float* rproj_b    = (const float*)d_in[11];
    float* out = (float*)d_out;
    float* ws  = (float*)d_ws;

    u16* WtAll   = (u16*)(ws + WS_WTALL);
    u16* rprojT  = (u16*)(ws + WS_RPROJT);
    u16* embsB   = (u16*)(ws + WS_EMBSB);
    u16* relembB = (u16*)(ws + WS_RELEMBB);
    u16* hgsB    = (u16*)(ws + WS_HGSB);
    u16* rtransB = (u16*)(ws + WS_RTRANSB);
    u16* fpadB   = (u16*)(ws + WS_FPADB);
    u16* bpadB   = (u16*)(ws + WS_BPADB);
    u16* brelB   = (u16*)(ws + WS_BRELB);
    u16* embsT   = (u16*)(ws + WS_EMBST);
    u16* tokpB   = (u16*)(ws + WS_TOKPB);
    float* relpf = ws + WS_RELPF;
    float* relpb = ws + WS_RELPB;
    float* hgpf  = ws + WS_HGPF;
    float* hgpb  = ws + WS_HGPB;
    float* emb8  = ws + WS_EMB8;
    float* emb9  = ws + WS_EMB9;
    float* fsw   = ws + WS_FSW;
    float* bow   = ws + WS_BOW;
    float* zb    = ws + WS_ZB;
    float* fmask = ws + WS_FMASK;
    float* bmask = ws + WS_BMASK;
    float* vraw  = ws + WS_VRAW;
    u16*   Abuf  = (u16*)(ws + WS_ABUF);
    float* Cfb   = ws + WS_CFB;
    float* t4 = ws + WS_T4; float* t5 = ws + WS_T5;
    float* t6 = ws + WS_T6; float* t7 = ws + WS_T7;
    float* c4 = ws + WS_C4; float* c5 = ws + WS_C5;
    float* c6 = ws + WS_C6; float* c7 = ws + WS_C7;
    int* jbuf     = (int*)(ws + WS_AUX);
    int* rankbuf  = jbuf + 2 * kB * kL;
    int* validbuf = rankbuf + 2 * kB * kL;

    // prep
    k_logits<<<kB * kL, 256, 0, stream>>>(embs, fc_w, fc_b, out, embsB);
    k_prep_cast<<<133, 256, 0, stream>>>(rel_embs, h_gs, rel_transe, relembB, hgsB, rtransB, zb);
    k_prep_w<<<1464, 256, 0, stream>>>(Wm, rproj_w, WtAll, rprojT);
    k_embsT<<<192, 256, 0, stream>>>(embsB, embsT);
    k_extract_meta<<<2 * kB, 256, 0, stream>>>(out, jbuf, rankbuf, validbuf, fmask, bmask);
    k_span_mean<<<2 * kB * kL, 256, 0, stream>>>(embs, jbuf, rankbuf, validbuf, fpadB, bpadB);

    // gemmA: all independent GEMMs in one launch (10 jobs)
    {
        GemmBatch bt;
        bt.j[0] = { relembB, WtAll + 2 * HH, Wb + 2 * kH, relpf, nullptr, nullptr, kR, kH, kH, 0 };
        bt.j[1] = { hgsB,    WtAll + 3 * HH, Wb + 3 * kH, hgpf,  nullptr, nullptr, kB, kH, kH, 0 };
        bt.j[2] = { hgsB,    WtAll + 6 * HH, Wb + 6 * kH, hgpb,  nullptr, nullptr, kB, kH, kH, 0 };
        bt.j[3] = { rtransB, rprojT,         rproj_b,     nullptr, brelB, nullptr, kR, 128, kH, 0 };
        bt.j[4] = { embsB,   WtAll + 4 * HH, Wb + 4 * kH, nullptr, tokpB,            nullptr, kB * kL, kH, kH, 0 };
        bt.j[5] = { embsB,   WtAll + 7 * HH, Wb + 7 * kH, nullptr, tokpB + (size_t)kB * kL * kH, nullptr, kB * kL, kH, kH, 0 };
        bt.j[6] = { embsB,   WtAll + 8 * HH, Wb + 8 * kH, emb8, nullptr, nullptr, kB * kL, kH, kH, 0 };
        bt.j[7] = { embsB,   WtAll + 9 * HH, Wb + 9 * kH, emb9, nullptr, nullptr, kB * kL, kH, kH, 0 };
        bt.j[8] = { fpadB,   WtAll + 0 * HH, Wb + 0 * kH, fsw, nullptr, fmask, kB * kL, kH, kH, 0 };
        bt.j[9] = { bpadB,   WtAll + 1 * HH, Wb + 1 * kH, bow, nullptr, bmask, kB * kL, kH, kH, 0 };
        k_gemm_mfma<<<dim3(8, 6, 10), 256, 0, stream>>>(bt);
    }
    // gemmB: relpb = brel @ Wm5 (depends on brelB)
    {
        GemmBatch bt;
        bt.j[0] = { brelB, WtAll + 5 * HH, Wb + 5 * kH, relpb, nullptr, nullptr, kR, kH, kH, 0 };
        k_gemm_mfma<<<dim3(1, 6, 1), 256, 0, stream>>>(bt);
    }

    k_score<<<512, 512, 0, stream>>>(tokpB, relpf, relpb, hgpf, hgpb, V_w, V_b, vraw);
    k_softmax<<<128, 256, 0, stream>>>(vraw, Abuf);

    // gemmC: C[which,b] = A[which,b] @ embsT[b]^T  (8 jobs, M=64, K=256)
    {
        GemmBatch bt;
        for (int z = 0; z < 8; z++) {
            int which = z >> 2, b = z & 3;
            bt.j[z] = { Abuf + (size_t)z * kR * kL,
                        embsT + (size_t)b * kH * kL,
                        zb,
                        Cfb + (size_t)z * kR * kH, nullptr, nullptr,
                        kR, kL, kH, 0 };
        }
        k_gemm_mfma<<<dim3(1, 6, 8), 256, 0, stream>>>(bt);
    }

    k_c<<<512, 256, 0, stream>>>(Cfb, fc_w, c4, c5, c6, c7);
    k_t<<<2 * kB * kL, 256, 0, stream>>>(embs, fsw, bow, emb8, emb9, fc_w, t4, t5, t6, t7);
    k_final<<<2 * kB * kL, 64, 0, stream>>>(t4, t5, t6, t7, c4, c5, c6, c7, fc_b, out);
}

// Round 7
// 132.366 us; speedup vs baseline: 10.1895x; 1.1288x over previous
//
#include <hip/hip_runtime.h>
#include <cstddef>

using u16 = unsigned short;
typedef __attribute__((ext_vector_type(8))) short bf16x8;
typedef __attribute__((ext_vector_type(4))) short bf16x4;
typedef __attribute__((ext_vector_type(4))) float f32x4;

constexpr int kB = 4, kL = 256, kR = 64, kH = 768, kTE = 100;
constexpr size_t HH = (size_t)kH * kH;

// ---- output offsets (floats) in return order ----
constexpr size_t OFF_FSS = 0;
constexpr size_t OFF_FSE = OFF_FSS + kB * kL;
constexpr size_t OFF_FOS = OFF_FSE + kB * kL;
constexpr size_t OFF_FOE = OFF_FOS + (size_t)kB * kL * kR;
constexpr size_t OFF_BOS = OFF_FOE + (size_t)kB * kL * kR;
constexpr size_t OFF_BOE = OFF_BOS + kB * kL;
constexpr size_t OFF_BSS = OFF_BOE + kB * kL;
constexpr size_t OFF_BSE = OFF_BSS + (size_t)kB * kL * kR;

// ---- workspace layout (float units) ----
constexpr size_t WS_WTALL   = 0;                                   // 10xHH u16
constexpr size_t WS_RPROJT  = WS_WTALL   + 10 * HH / 2;            // 768x128 u16
constexpr size_t WS_EMBSB   = WS_RPROJT  + (768 * 128) / 2;        // 1024x768 u16
constexpr size_t WS_RELEMBB = WS_EMBSB   + (1024 * 768) / 2;       // 64x768 u16
constexpr size_t WS_HGSB    = WS_RELEMBB + (64 * 768) / 2;         // 4x768 u16
constexpr size_t WS_RTRANSB = WS_HGSB    + (4 * 768) / 2;          // 64x128 u16
constexpr size_t WS_FPADB   = WS_RTRANSB + (64 * 128) / 2;         // 1024x768 u16 (dead after gemmA)
constexpr size_t WS_BPADB   = WS_FPADB   + (1024 * 768) / 2;       // 1024x768 u16 (dead after gemmA)
constexpr size_t WS_BRELB   = WS_BPADB   + (1024 * 768) / 2;       // 64x768 u16
constexpr size_t WS_EMBST   = WS_BRELB   + (64 * 768) / 2;         // 4x768x256 u16
constexpr size_t WS_TOKPB   = WS_EMBST   + (4 * 768 * 256) / 2;    // 2x1024x768 u16
constexpr size_t WS_RELPF   = WS_TOKPB   + (2 * 1024 * 768) / 2;   // 64x768 f32
constexpr size_t WS_RELPB   = WS_RELPF   + 64 * 768;
constexpr size_t WS_HGPF    = WS_RELPB   + 64 * 768;               // 4x768 f32
constexpr size_t WS_HGPB    = WS_HGPF    + 4 * 768;
constexpr size_t WS_EMB8    = WS_HGPB    + 4 * 768;                // 1024x768 f32
constexpr size_t WS_EMB9    = WS_EMB8    + 1024 * 768;
constexpr size_t WS_FSW     = WS_EMB9    + 1024 * 768;
constexpr size_t WS_BOW     = WS_FSW     + 1024 * 768;
constexpr size_t WS_ZB      = WS_BOW     + 1024 * 768;             // 768 zeros
constexpr size_t WS_FMASK   = WS_ZB      + 768;
constexpr size_t WS_BMASK   = WS_FMASK   + 1024;
constexpr size_t WS_T4      = WS_BMASK   + 1024;
constexpr size_t WS_T5      = WS_T4 + 1024;
constexpr size_t WS_T6      = WS_T5 + 1024;
constexpr size_t WS_T7      = WS_T6 + 1024;
constexpr size_t WS_C4      = WS_T7 + 1024;
constexpr size_t WS_C5      = WS_C4 + 256;
constexpr size_t WS_C6      = WS_C5 + 256;
constexpr size_t WS_C7      = WS_C6 + 256;
constexpr size_t WS_AUX     = WS_C7 + 256;    // int region
// aliases over dead pad regions (gemmA has consumed fpadB/bpadB before these are written).
// NOTE: pad rows >= num are stale garbage on timed replays (may decode as bf16 Inf/NaN);
// the GEMM epilogue must SELECT on rowmask, never multiply (0*Inf=NaN).
constexpr size_t WS_CFB     = WS_FPADB;       // 512x768 f32
constexpr size_t WS_VRAW    = WS_BPADB;       // 512x256 f32
constexpr size_t WS_ABUF    = WS_BPADB + 512 * 256;   // 512x256 u16

__device__ inline float fast_rcp(float x) {
#if __has_builtin(__builtin_amdgcn_rcpf)
    return __builtin_amdgcn_rcpf(x);
#else
    return 1.f / x;
#endif
}
__device__ inline float fast_exp2(float x) {
#if __has_builtin(__builtin_amdgcn_exp2f)
    return __builtin_amdgcn_exp2f(x);
#else
    return __exp2f(x);
#endif
}
__device__ inline u16 f2bf(float x) {   // RNE
    union { float f; unsigned u; } v; v.f = x;
    unsigned r = v.u + 0x7FFFu + ((v.u >> 16) & 1u);
    return (u16)(r >> 16);
}
__device__ inline float bf2f(u16 x) {
    union { unsigned u; float f; } v; v.u = ((unsigned)x) << 16;
    return v.f;
}

// ---- 1. per-token fc logits (fp32 exact: threshold source) + embs bf16 cast ----
__global__ __launch_bounds__(256) void k_logits(const float* __restrict__ embs,
        const float* __restrict__ fc_w, const float* __restrict__ fc_b,
        float* __restrict__ out, u16* __restrict__ embsB)
{
    int t = blockIdx.x;
    const float* e = embs + (size_t)t * kH;
    float s0 = 0, s1 = 0, s2 = 0, s3 = 0;
    for (int h = threadIdx.x; h < kH; h += 256) {
        float x = e[h];
        embsB[(size_t)t * kH + h] = f2bf(x);
        s0 += x * fc_w[0 * kH + h];
        s1 += x * fc_w[1 * kH + h];
        s2 += x * fc_w[2 * kH + h];
        s3 += x * fc_w[3 * kH + h];
    }
#pragma unroll
    for (int off = 32; off; off >>= 1) {
        s0 += __shfl_down(s0, off, 64);
        s1 += __shfl_down(s1, off, 64);
        s2 += __shfl_down(s2, off, 64);
        s3 += __shfl_down(s3, off, 64);
    }
    __shared__ float red[4][4];
    int wid = threadIdx.x >> 6;
    if ((threadIdx.x & 63) == 0) {
        red[0][wid] = s0; red[1][wid] = s1; red[2][wid] = s2; red[3][wid] = s3;
    }
    __syncthreads();
    if (threadIdx.x == 0) {
        out[OFF_FSS + t] = red[0][0] + red[0][1] + red[0][2] + red[0][3] + fc_b[0];
        out[OFF_FSE + t] = red[1][0] + red[1][1] + red[1][2] + red[1][3] + fc_b[1];
        out[OFF_BOS + t] = red[2][0] + red[2][1] + red[2][2] + red[2][3] + fc_b[2];
        out[OFF_BOE + t] = red[3][0] + red[3][1] + red[3][2] + red[3][3] + fc_b[3];
    }
}

// ---- 2. misc bf16 casts + zero-bias init ----
__global__ __launch_bounds__(256) void k_prep_cast(const float* __restrict__ rel_embs,
        const float* __restrict__ h_gs, const float* __restrict__ rel_transe,
        u16* __restrict__ relembB, u16* __restrict__ hgsB, u16* __restrict__ rtransB,
        float* __restrict__ zb)
{
    int bx = blockIdx.x, t = threadIdx.x;
    if (bx < 64) {
        for (int h = t; h < kH; h += 256) relembB[bx * kH + h] = f2bf(rel_embs[bx * kH + h]);
    } else if (bx < 68) {
        int r = bx - 64;
        for (int h = t; h < kH; h += 256) hgsB[r * kH + h] = f2bf(h_gs[r * kH + h]);
    } else if (bx < 132) {
        int r = bx - 68;
        if (t < 128) rtransB[r * 128 + t] = (t < kTE) ? f2bf(rel_transe[r * kTE + t]) : (u16)0;
    } else {
        for (int h = t; h < kH; h += 256) zb[h] = 0.f;
    }
}

// ---- 3. weight transposes: Wt[n][k] = W[k][n], bf16 out ----
__global__ __launch_bounds__(256) void k_prep_w(const float* __restrict__ Wm,
        const float* __restrict__ rproj_w, u16* __restrict__ WtAll, u16* __restrict__ rprojT)
{
    __shared__ float tl[64][65];
    int bx = blockIdx.x, t = threadIdx.x;
    const float* src; u16* dst; int kt, nt, dstStride, srcRows;
    if (bx < 1440) {
        int mi = bx / 144, tile = bx % 144;
        kt = (tile / 12) * 64; nt = (tile % 12) * 64;
        src = Wm + (size_t)mi * HH; dst = WtAll + (size_t)mi * HH;
        dstStride = kH; srcRows = kH;
    } else {
        int tt = bx - 1440;
        kt = (tt / 12) * 64; nt = (tt % 12) * 64;
        src = rproj_w; dst = rprojT; dstStride = 128; srcRows = kTE;
    }
    int r = t >> 2, cq = (t & 3) * 16;
    int row = kt + r;
#pragma unroll
    for (int q = 0; q < 4; q++) {
        float4 v = make_float4(0.f, 0.f, 0.f, 0.f);
        if (row < srcRows) v = *(const float4*)(src + (size_t)row * kH + nt + cq + q * 4);
        tl[r][cq + q * 4 + 0] = v.x;
        tl[r][cq + q * 4 + 1] = v.y;
        tl[r][cq + q * 4 + 2] = v.z;
        tl[r][cq + q * 4 + 3] = v.w;
    }
    __syncthreads();
    u16* drow = dst + (size_t)(nt + r) * dstStride + kt + cq;
#pragma unroll
    for (int j = 0; j < 16; j++) drow[j] = f2bf(tl[cq + j][r]);
}

// ---- 3b. embs transpose to embsT[b][h][l] bf16 ----
__global__ __launch_bounds__(256) void k_embsT(const u16* __restrict__ embsB,
        u16* __restrict__ embsT)
{
    __shared__ u16 tl[64][66];
    int b = blockIdx.x / 48, rem = blockIdx.x % 48;
    int h0 = (rem / 4) * 64, l0 = (rem % 4) * 64;
    int r = threadIdx.x >> 2, cq = (threadIdx.x & 3) * 16;
    const u16* src = embsB + (size_t)(b * kL + l0 + r) * kH + h0 + cq;
#pragma unroll
    for (int j = 0; j < 16; j++) tl[r][cq + j] = src[j];
    __syncthreads();
    u16* dst = embsT + (size_t)b * kH * kL + (size_t)(h0 + r) * kL + l0 + cq;
#pragma unroll
    for (int j = 0; j < 16; j++) dst[j] = tl[cq + j][r];
}

// ---- 4. span extraction metadata ----
__global__ __launch_bounds__(256) void k_extract_meta(const float* __restrict__ out,
        int* __restrict__ jbuf, int* __restrict__ rankbuf, int* __restrict__ validbuf,
        float* __restrict__ fmask, float* __restrict__ bmask)
{
    int which = blockIdx.x >> 2;
    int b = blockIdx.x & 3;
    int i = threadIdx.x;
    const float* slog = out + (which ? OFF_BOS : OFF_FSS) + (size_t)b * kL;
    const float* elog = out + (which ? OFF_BOE : OFF_FSE) + (size_t)b * kL;
    float sv = slog[i], ev = elog[i];
    bool st = (1.f / (1.f + __expf(-sv)) > 0.5f);
    bool en = (1.f / (1.f + __expf(-ev)) > 0.5f);

    __shared__ int sm[kL];
    __shared__ int ps[kL];
    sm[i] = en ? i : kL;
    __syncthreads();
    for (int step = 1; step < kL; step <<= 1) {
        int v = (i + step < kL) ? sm[i + step] : kL;
        __syncthreads();
        sm[i] = min(sm[i], v);
        __syncthreads();
    }
    int next_end = sm[i];
    int validi = (st && next_end < kL) ? 1 : 0;
    ps[i] = validi;
    __syncthreads();
    for (int step = 1; step < kL; step <<= 1) {
        int v = (i >= step) ? ps[i - step] : 0;
        __syncthreads();
        ps[i] += v;
        __syncthreads();
    }
    int rank = ps[i] - 1;
    int num = ps[kL - 1];
    int gbase = (which * kB + b) * kL + i;
    jbuf[gbase] = min(next_end, kL - 1);
    rankbuf[gbase] = rank;
    validbuf[gbase] = validi;
    (which ? bmask : fmask)[b * kL + i] = (i < num) ? 1.f : 0.f;
}

// ---- 5. span means packed by rank (bf16 out) ----
__global__ __launch_bounds__(256) void k_span_mean(const float* __restrict__ embs,
        const int* __restrict__ jbuf, const int* __restrict__ rankbuf,
        const int* __restrict__ validbuf, u16* __restrict__ fpadB, u16* __restrict__ bpadB)
{
    int idx = blockIdx.x;
    int which = idx >> 10;
    int b = (idx >> 8) & 3;
    int i = idx & 255;
    int gbase = (which * kB + b) * kL + i;
    if (!validbuf[gbase]) return;
    int j = jbuf[gbase];
    int rk = rankbuf[gbase];
    int len = j - i + 1;
    float inv = 1.f / (float)len;
    u16* pad = (which ? bpadB : fpadB) + ((size_t)(b * kL + rk)) * kH;
    const float* e = embs + ((size_t)(b * kL + i)) * kH;
    for (int h = threadIdx.x; h < kH; h += 256) {
        float s = 0.f;
        for (int row = 0; row < len; row++) s += e[(size_t)row * kH + h];
        pad[h] = f2bf(s * inv);
    }
}

// ---- 6. batched MFMA GEMM, 64x128 tile, BK=64, dbuf + reg-prefetch ----
// LDS 48KB -> 3 blocks/CU residency (12 waves/CU): independent blocks hide
// each other's load latency. XOR swizzle on both ds_write and ds_read.
struct GemmJob {
    const u16* A; const u16* Wt; const float* bias;
    float* C; u16* Cbf; const float* rowmask;
    int M; int K; int ldc; int coff;
};
struct GemmBatch { GemmJob j[10]; };

__device__ inline int swz(int row, int slot) {   // short-index into [row][64] layout
    return row * 64 + ((slot ^ (row & 7)) << 3);
}

__global__ __launch_bounds__(256) void k_gemm_mfma(GemmBatch batch)
{
    GemmJob jb = batch.j[blockIdx.z];
    if (blockIdx.x * 64 >= jb.M) return;
    __shared__ short Als[2][64 * 64];      // 16 KB
    __shared__ short Bls[2][128 * 64];     // 32 KB
    int tid = threadIdx.x;
    int m0 = blockIdx.x * 64;
    int n0 = blockIdx.y * 128;
    int w = tid >> 6, lane = tid & 63;
    int wm = (w >> 1) * 32, wn = (w & 1) * 64;   // 2M x 2N waves, each 32x64
    int lrow = lane & 15, lhi = lane >> 4;
    int arow = tid >> 2, ac0 = (tid & 3) * 2;    // A: 2 contiguous 8-elem chunks
    int brow = tid >> 1, bc0 = (tid & 1) * 4;    // B: 4 contiguous 8-elem chunks
    int K = jb.K;
    int T = K >> 6;                              // all K multiples of 64

    f32x4 zero4 = {0.f, 0.f, 0.f, 0.f};
    f32x4 acc[2][4];
#pragma unroll
    for (int i = 0; i < 2; i++)
#pragma unroll
        for (int j = 0; j < 4; j++) acc[i][j] = zero4;

    bf16x8 pa[2], pb[4];

#define LOADT(k0)                                                                 \
    {                                                                             \
        _Pragma("unroll")                                                         \
        for (int q = 0; q < 2; q++) {                                             \
            bf16x8 va;                                                            \
            _Pragma("unroll") for (int z = 0; z < 8; z++) va[z] = 0;              \
            if (m0 + arow < jb.M)                                                 \
                va = *reinterpret_cast<const bf16x8*>(                            \
                    jb.A + (size_t)(m0 + arow) * K + (k0) + (ac0 + q) * 8);       \
            pa[q] = va;                                                           \
        }                                                                         \
        _Pragma("unroll")                                                         \
        for (int q = 0; q < 4; q++)                                               \
            pb[q] = *reinterpret_cast<const bf16x8*>(                             \
                jb.Wt + (size_t)(n0 + brow) * K + (k0) + (bc0 + q) * 8);          \
    }
#define STORET(buf)                                                               \
    {                                                                             \
        _Pragma("unroll")                                                         \
        for (int q = 0; q < 2; q++)                                               \
            *reinterpret_cast<bf16x8*>(&Als[buf][swz(arow, ac0 + q)]) = pa[q];    \
        _Pragma("unroll")                                                         \
        for (int q = 0; q < 4; q++)                                               \
            *reinterpret_cast<bf16x8*>(&Bls[buf][swz(brow, bc0 + q)]) = pb[q];    \
    }

    LOADT(0);
    STORET(0);
    __syncthreads();
    int cur = 0;
    for (int t = 0; t < T; t++) {
        if (t + 1 < T) LOADT((t + 1) << 6);     // issue next-tile loads early
#pragma unroll
        for (int sub = 0; sub < 2; sub++) {
            bf16x8 af[2], bg[4];
#pragma unroll
            for (int i = 0; i < 2; i++)
                af[i] = *reinterpret_cast<const bf16x8*>(
                    &Als[cur][swz(wm + i * 16 + lrow, sub * 4 + lhi)]);
#pragma unroll
            for (int j = 0; j < 4; j++)
                bg[j] = *reinterpret_cast<const bf16x8*>(
                    &Bls[cur][swz(wn + j * 16 + lrow, sub * 4 + lhi)]);
#pragma unroll
            for (int i = 0; i < 2; i++)
#pragma unroll
                for (int j = 0; j < 4; j++)
                    acc[i][j] = __builtin_amdgcn_mfma_f32_16x16x32_bf16(af[i], bg[j], acc[i][j], 0, 0, 0);
        }
        if (t + 1 < T) STORET(cur ^ 1);         // write to alternate buffer
        __syncthreads();                        // one barrier per iter (dbuf-safe)
        cur ^= 1;
    }
#undef LOADT
#undef STORET

#pragma unroll
    for (int i = 0; i < 2; i++) {
#pragma unroll
        for (int j = 0; j < 4; j++) {
            int n = n0 + wn + j * 16 + lrow;
            float bi = jb.bias[n];
#pragma unroll
            for (int q = 0; q < 4; q++) {
                int m = m0 + wm + i * 16 + lhi * 4 + q;
                if (m < jb.M) {
                    float val = acc[i][j][q] + bi;
                    // SELECT, not multiply: masked-out rows may have accumulated
                    // Inf/NaN from stale pad-buffer garbage (0 * Inf = NaN).
                    if (jb.rowmask) val = (jb.rowmask[m] != 0.f) ? val : 0.f;
                    if (jb.C)   jb.C[(size_t)m * jb.ldc + jb.coff + n] = val;
                    if (jb.Cbf) jb.Cbf[(size_t)m * jb.ldc + jb.coff + n] = f2bf(val);
                }
            }
        }
    }
}

// ---- 7. attention scores: block=(which,b,r), lane owns 12-elem h-slice in regs ----
__global__ __launch_bounds__(512) void k_score(const u16* __restrict__ tokpB,
        const float* __restrict__ relpf, const float* __restrict__ relpb,
        const float* __restrict__ hgpf, const float* __restrict__ hgpb,
        const float* __restrict__ V_w, const float* __restrict__ V_b,
        float* __restrict__ vraw)
{
    constexpr float C = 2.8853900817779268f;   // 2*log2(e)
    int idx = blockIdx.x;            // 512
    int which = idx >> 8, b = (idx >> 6) & 3, r = idx & 63;
    int wid = threadIdx.x >> 6, lane = threadIdx.x & 63;
    int h0 = lane * 12;
    const float* relp = (which ? relpb : relpf) + (size_t)r * kH + h0;
    const float* hgp  = (which ? hgpb : hgpf) + (size_t)b * kH + h0;
    const float* vw   = V_w + h0;

    float av2[12], w2[12], wsum = 0.f;
#pragma unroll
    for (int j = 0; j < 12; j++) {
        av2[j] = C * (relp[j] + hgp[j]);
        float wv = vw[j];
        w2[j] = -2.f * wv;
        wsum += wv;
    }
    float vb = V_b[0];
    const u16* base = tokpB + ((size_t)which * (kB * kL) + b * kL) * kH + h0;
    float* vout = vraw + ((size_t)(which * kB + b) * kR + r) * kL;

    int l0 = wid * 32;
    bf16x4 t0 = *reinterpret_cast<const bf16x4*>(base + (size_t)l0 * kH);
    bf16x4 t1 = *reinterpret_cast<const bf16x4*>(base + (size_t)l0 * kH + 4);
    bf16x4 t2 = *reinterpret_cast<const bf16x4*>(base + (size_t)l0 * kH + 8);
    for (int l = l0; l < l0 + 32; l++) {
        bf16x4 n0, n1, n2;
        if (l + 1 < l0 + 32) {
            const u16* nrow = base + (size_t)(l + 1) * kH;
            n0 = *reinterpret_cast<const bf16x4*>(nrow);
            n1 = *reinterpret_cast<const bf16x4*>(nrow + 4);
            n2 = *reinterpret_cast<const bf16x4*>(nrow + 8);
        }
        float acc = wsum;
#pragma unroll
        for (int j = 0; j < 4; j++) {
            float e0 = fast_exp2(fmaf(bf2f((u16)t0[j]), C, av2[j]));
            acc = fmaf(w2[j], fast_rcp(e0 + 1.f), acc);
            float e1 = fast_exp2(fmaf(bf2f((u16)t1[j]), C, av2[4 + j]));
            acc = fmaf(w2[4 + j], fast_rcp(e1 + 1.f), acc);
            float e2 = fast_exp2(fmaf(bf2f((u16)t2[j]), C, av2[8 + j]));
            acc = fmaf(w2[8 + j], fast_rcp(e2 + 1.f), acc);
        }
#pragma unroll
        for (int off = 32; off; off >>= 1) acc += __shfl_xor(acc, off, 64);
        if (lane == 0) vout[l] = acc + vb;
        t0 = n0; t1 = n1; t2 = n2;
    }
}

// ---- 8. softmax over l, bf16 A out ----
__global__ __launch_bounds__(256) void k_softmax(const float* __restrict__ vraw,
        u16* __restrict__ Abuf)
{
    int wid = threadIdx.x >> 6, lane = threadIdx.x & 63;
    int g = blockIdx.x * 4 + wid;      // 512 rows
    const float* row = vraw + (size_t)g * kL;
    float x[4];
#pragma unroll
    for (int q = 0; q < 4; q++) x[q] = row[lane + 64 * q];
    float m = fmaxf(fmaxf(x[0], x[1]), fmaxf(x[2], x[3]));
#pragma unroll
    for (int off = 32; off; off >>= 1) m = fmaxf(m, __shfl_xor(m, off, 64));
    float p[4], s = 0.f;
#pragma unroll
    for (int q = 0; q < 4; q++) { p[q] = __expf(x[q] - m); s += p[q]; }
#pragma unroll
    for (int off = 32; off; off >>= 1) s += __shfl_xor(s, off, 64);
    float inv = 1.f / s;
#pragma unroll
    for (int q = 0; q < 4; q++) Abuf[(size_t)g * kL + lane + 64 * q] = f2bf(p[q] * inv);
}

// ---- 9. c vectors from Cfb ----
__global__ __launch_bounds__(256) void k_c(const float* __restrict__ Cfb,
        const float* __restrict__ fc_w, float* __restrict__ c4, float* __restrict__ c5,
        float* __restrict__ c6, float* __restrict__ c7)
{
    int p = blockIdx.x;               // 512 = which*256 + b*64 + r
    int which = p >> 8, local = p & 255;
    const float* Cm = Cfb + (size_t)p * kH;
    const float* w0 = fc_w + (size_t)(which ? 6 : 4) * kH;
    const float* w1 = w0 + kH;
    float s0 = 0, s1 = 0;
    for (int h = threadIdx.x; h < kH; h += 256) {
        float x = Cm[h];
        s0 += x * w0[h];
        s1 += x * w1[h];
    }
#pragma unroll
    for (int off = 32; off; off >>= 1) {
        s0 += __shfl_down(s0, off, 64);
        s1 += __shfl_down(s1, off, 64);
    }
    __shared__ float red[2][4];
    int wid = threadIdx.x >> 6;
    if ((threadIdx.x & 63) == 0) { red[0][wid] = s0; red[1][wid] = s1; }
    __syncthreads();
    if (threadIdx.x == 0) {
        float a = red[0][0] + red[0][1] + red[0][2] + red[0][3];
        float c = red[1][0] + red[1][1] + red[1][2] + red[1][3];
        if (which) { c6[local] = a; c7[local] = c; }
        else       { c4[local] = a; c5[local] = c; }
    }
}

// ---- 10. t vectors ----
__global__ __launch_bounds__(256) void k_t(const float* __restrict__ embs,
        const float* __restrict__ fsw, const float* __restrict__ bow,
        const float* __restrict__ emb8, const float* __restrict__ emb9,
        const float* __restrict__ fc_w,
        float* __restrict__ t4, float* __restrict__ t5,
        float* __restrict__ t6, float* __restrict__ t7)
{
    int idx = blockIdx.x;
    int which = idx >> 10;
    int t = idx & 1023;
    const float* sw = which ? bow : fsw;
    const float* e8 = (which ? emb9 : emb8) + (size_t)t * kH;
    const float* w0 = fc_w + (size_t)(which ? 6 : 4) * kH;
    const float* w1 = w0 + kH;
    size_t base = (size_t)t * kH;
    float s0 = 0, s1 = 0;
    for (int h = threadIdx.x; h < kH; h += 256) {
        float x = sw[base + h] + e8[h] + embs[base + h];
        s0 += x * w0[h];
        s1 += x * w1[h];
    }
#pragma unroll
    for (int off = 32; off; off >>= 1) {
        s0 += __shfl_down(s0, off, 64);
        s1 += __shfl_down(s1, off, 64);
    }
    __shared__ float red[2][4];
    int wid = threadIdx.x >> 6;
    if ((threadIdx.x & 63) == 0) { red[0][wid] = s0; red[1][wid] = s1; }
    __syncthreads();
    if (threadIdx.x == 0) {
        float a = red[0][0] + red[0][1] + red[0][2] + red[0][3];
        float c = red[1][0] + red[1][1] + red[1][2] + red[1][3];
        if (which) { t6[t] = a; t7[t] = c; }
        else       { t4[t] = a; t5[t] = c; }
    }
}

// ---- 11. broadcast-add final pair logits ----
__global__ __launch_bounds__(64) void k_final(const float* __restrict__ t4,
        const float* __restrict__ t5, const float* __restrict__ t6,
        const float* __restrict__ t7, const float* __restrict__ c4,
        const float* __restrict__ c5, const float* __restrict__ c6,
        const float* __restrict__ c7, const float* __restrict__ fc_b,
        float* __restrict__ out)
{
    int which = blockIdx.x >> 10;
    int t = blockIdx.x & 1023;
    int b = t >> 8;
    int r = threadIdx.x;
    if (!which) {
        out[OFF_FOS + (size_t)t * kR + r] = t4[t] + c4[b * kR + r] + fc_b[4];
        out[OFF_FOE + (size_t)t * kR + r] = t5[t] + c5[b * kR + r] + fc_b[5];
    } else {
        out[OFF_BSS + (size_t)t * kR + r] = t6[t] + c6[b * kR + r] + fc_b[6];
        out[OFF_BSE + (size_t)t * kR + r] = t7[t] + c7[b * kR + r] + fc_b[7];
    }
}

extern "C" void kernel_launch(void* const* d_in, const int* in_sizes, int n_in,
                              void* d_out, int out_size, void* d_ws, size_t ws_size,
                              hipStream_t stream)
{
    const float* embs       = (const float*)d_in[0];
    const float* h_gs       = (const float*)d_in[1];
    const float* rel_embs   = (const float*)d_in[2];
    const float* rel_transe = (const float*)d_in[3];
    const float* fc_w       = (const float*)d_in[4];
    const float* fc_b       = (const float*)d_in[5];
    const float* Wm         = (const float*)d_in[6];
    const float* Wb         = (const float*)d_in[7];
    const float* V_w        = (const float*)d_in[8];
    const float* V_b        = (const float*)d_in[9];
    const float* rproj_w    = (const float*)d_in[10];
    const float* rproj_b    = (const float*)d_in[11];
    float* out = (float*)d_out;
    float* ws  = (float*)d_ws;

    u16* WtAll   = (u16*)(ws + WS_WTALL);
    u16* rprojT  = (u16*)(ws + WS_RPROJT);
    u16* embsB   = (u16*)(ws + WS_EMBSB);
    u16* relembB = (u16*)(ws + WS_RELEMBB);
    u16* hgsB    = (u16*)(ws + WS_HGSB);
    u16* rtransB = (u16*)(ws + WS_RTRANSB);
    u16* fpadB   = (u16*)(ws + WS_FPADB);
    u16* bpadB   = (u16*)(ws + WS_BPADB);
    u16* brelB   = (u16*)(ws + WS_BRELB);
    u16* embsT   = (u16*)(ws + WS_EMBST);
    u16* tokpB   = (u16*)(ws + WS_TOKPB);
    float* relpf = ws + WS_RELPF;
    float* relpb = ws + WS_RELPB;
    float* hgpf  = ws + WS_HGPF;
    float* hgpb  = ws + WS_HGPB;
    float* emb8  = ws + WS_EMB8;
    float* emb9  = ws + WS_EMB9;
    float* fsw   = ws + WS_FSW;
    float* bow   = ws + WS_BOW;
    float* zb    = ws + WS_ZB;
    float* fmask = ws + WS_FMASK;
    float* bmask = ws + WS_BMASK;
    float* vraw  = ws + WS_VRAW;
    u16*   Abuf  = (u16*)(ws + WS_ABUF);
    float* Cfb   = ws + WS_CFB;
    float* t4 = ws + WS_T4; float* t5 = ws + WS_T5;
    float* t6 = ws + WS_T6; float* t7 = ws + WS_T7;
    float* c4 = ws + WS_C4; float* c5 = ws + WS_C5;
    float* c6 = ws + WS_C6; float* c7 = ws + WS_C7;
    int* jbuf     = (int*)(ws + WS_AUX);
    int* rankbuf  = jbuf + 2 * kB * kL;
    int* validbuf = rankbuf + 2 * kB * kL;

    // prep
    k_logits<<<kB * kL, 256, 0, stream>>>(embs, fc_w, fc_b, out, embsB);
    k_prep_cast<<<133, 256, 0, stream>>>(rel_embs, h_gs, rel_transe, relembB, hgsB, rtransB, zb);
    k_prep_w<<<1464, 256, 0, stream>>>(Wm, rproj_w, WtAll, rprojT);
    k_embsT<<<192, 256, 0, stream>>>(embsB, embsT);
    k_extract_meta<<<2 * kB, 256, 0, stream>>>(out, jbuf, rankbuf, validbuf, fmask, bmask);
    k_span_mean<<<2 * kB * kL, 256, 0, stream>>>(embs, jbuf, rankbuf, validbuf, fpadB, bpadB);

    // gemmA: all independent GEMMs in one launch (10 jobs)
    {
        GemmBatch bt;
        bt.j[0] = { relembB, WtAll + 2 * HH, Wb + 2 * kH, relpf, nullptr, nullptr, kR, kH, kH, 0 };
        bt.j[1] = { hgsB,    WtAll + 3 * HH, Wb + 3 * kH, hgpf,  nullptr, nullptr, kB, kH, kH, 0 };
        bt.j[2] = { hgsB,    WtAll + 6 * HH, Wb + 6 * kH, hgpb,  nullptr, nullptr, kB, kH, kH, 0 };
        bt.j[3] = { rtransB, rprojT,         rproj_b,     nullptr, brelB, nullptr, kR, 128, kH, 0 };
        bt.j[4] = { embsB,   WtAll + 4 * HH, Wb + 4 * kH, nullptr, tokpB,            nullptr, kB * kL, kH, kH, 0 };
        bt.j[5] = { embsB,   WtAll + 7 * HH, Wb + 7 * kH, nullptr, tokpB + (size_t)kB * kL * kH, nullptr, kB * kL, kH, kH, 0 };
        bt.j[6] = { embsB,   WtAll + 8 * HH, Wb + 8 * kH, emb8, nullptr, nullptr, kB * kL, kH, kH, 0 };
        bt.j[7] = { embsB,   WtAll + 9 * HH, Wb + 9 * kH, emb9, nullptr, nullptr, kB * kL, kH, kH, 0 };
        bt.j[8] = { fpadB,   WtAll + 0 * HH, Wb + 0 * kH, fsw, nullptr, fmask, kB * kL, kH, kH, 0 };
        bt.j[9] = { bpadB,   WtAll + 1 * HH, Wb + 1 * kH, bow, nullptr, bmask, kB * kL, kH, kH, 0 };
        k_gemm_mfma<<<dim3(16, 6, 10), 256, 0, stream>>>(bt);
    }
    // gemmB: relpb = brel @ Wm5 (depends on brelB)
    {
        GemmBatch bt;
        bt.j[0] = { brelB, WtAll + 5 * HH, Wb + 5 * kH, relpb, nullptr, nullptr, kR, kH, kH, 0 };
        k_gemm_mfma<<<dim3(1, 6, 1), 256, 0, stream>>>(bt);
    }

    k_score<<<512, 512, 0, stream>>>(tokpB, relpf, relpb, hgpf, hgpb, V_w, V_b, vraw);
    k_softmax<<<128, 256, 0, stream>>>(vraw, Abuf);

    // gemmC: C[which,b] = A[which,b] @ embsT[b]^T  (8 jobs, M=64, K=256)
    {
        GemmBatch bt;
        for (int z = 0; z < 8; z++) {
            int which = z >> 2, b = z & 3;
            bt.j[z] = { Abuf + (size_t)z * kR * kL,
                        embsT + (size_t)b * kH * kL,
                        zb,
                        Cfb + (size_t)z * kR * kH, nullptr, nullptr,
                        kR, kL, kH, 0 };
        }
        k_gemm_mfma<<<dim3(1, 6, 8), 256, 0, stream>>>(bt);
    }

    k_c<<<512, 256, 0, stream>>>(Cfb, fc_w, c4, c5, c6, c7);
    k_t<<<2 * kB * kL, 256, 0, stream>>>(embs, fsw, bow, emb8, emb9, fc_w, t4, t5, t6, t7);
    k_final<<<2 * kB * kL, 64, 0, stream>>>(t4, t5, t6, t7, c4, c5, c6, c7, fc_b, out);
}

// Round 8
// 125.293 us; speedup vs baseline: 10.7647x; 1.0565x over previous
//
#include <hip/hip_runtime.h>
#include <cstddef>

using u16 = unsigned short;
typedef __attribute__((ext_vector_type(8))) short bf16x8;
typedef __attribute__((ext_vector_type(4))) short bf16x4;
typedef __attribute__((ext_vector_type(4))) float f32x4;

constexpr int kB = 4, kL = 256, kR = 64, kH = 768, kTE = 100;
constexpr size_t HH = (size_t)kH * kH;

// ---- output offsets (floats) in return order ----
constexpr size_t OFF_FSS = 0;
constexpr size_t OFF_FSE = OFF_FSS + kB * kL;
constexpr size_t OFF_FOS = OFF_FSE + kB * kL;
constexpr size_t OFF_FOE = OFF_FOS + (size_t)kB * kL * kR;
constexpr size_t OFF_BOS = OFF_FOE + (size_t)kB * kL * kR;
constexpr size_t OFF_BOE = OFF_BOS + kB * kL;
constexpr size_t OFF_BSS = OFF_BOE + kB * kL;
constexpr size_t OFF_BSE = OFF_BSS + (size_t)kB * kL * kR;

// ---- workspace layout (float units) ----
constexpr size_t WS_WTALL   = 0;                                   // 10xHH u16 (only 2..7 used now)
constexpr size_t WS_RPROJT  = WS_WTALL   + 10 * HH / 2;            // 768x128 u16
constexpr size_t WS_EMBSB   = WS_RPROJT  + (768 * 128) / 2;        // 1024x768 u16
constexpr size_t WS_RELEMBB = WS_EMBSB   + (1024 * 768) / 2;       // 64x768 u16
constexpr size_t WS_HGSB    = WS_RELEMBB + (64 * 768) / 2;         // 4x768 u16
constexpr size_t WS_RTRANSB = WS_HGSB    + (4 * 768) / 2;          // 64x128 u16
constexpr size_t WS_FPADB   = WS_RTRANSB + (64 * 128) / 2;         // 1024x768 u16 (live until k_t)
constexpr size_t WS_BPADB   = WS_FPADB   + (1024 * 768) / 2;       // 1024x768 u16 (live until k_t)
constexpr size_t WS_BRELB   = WS_BPADB   + (1024 * 768) / 2;       // 64x768 u16
constexpr size_t WS_EMBST   = WS_BRELB   + (64 * 768) / 2;         // 4x768x256 u16
constexpr size_t WS_TOKPB   = WS_EMBST   + (4 * 768 * 256) / 2;    // 2x1024x768 u16
constexpr size_t WS_RELPF   = WS_TOKPB   + (2 * 1024 * 768) / 2;   // 64x768 f32
constexpr size_t WS_RELPB   = WS_RELPF   + 64 * 768;
constexpr size_t WS_HGPF    = WS_RELPB   + 64 * 768;               // 4x768 f32
constexpr size_t WS_HGPB    = WS_HGPF    + 4 * 768;
constexpr size_t WS_EMB8    = WS_HGPB    + 4 * 768;                // dead GEMM region -> vraw/Abuf
constexpr size_t WS_EMB9    = WS_EMB8    + 1024 * 768;             // dead GEMM region -> Cfb
constexpr size_t WS_FSW     = WS_EMB9    + 1024 * 768;             // dead GEMM region -> uA/uB/cc
constexpr size_t WS_BOW     = WS_FSW     + 1024 * 768;             // dead
constexpr size_t WS_ZB      = WS_BOW     + 1024 * 768;             // 768 zeros
constexpr size_t WS_FMASK   = WS_ZB      + 768;
constexpr size_t WS_BMASK   = WS_FMASK   + 1024;
constexpr size_t WS_T4      = WS_BMASK   + 1024;
constexpr size_t WS_T5      = WS_T4 + 1024;
constexpr size_t WS_T6      = WS_T5 + 1024;
constexpr size_t WS_T7      = WS_T6 + 1024;
constexpr size_t WS_C4      = WS_T7 + 1024;
constexpr size_t WS_C5      = WS_C4 + 256;
constexpr size_t WS_C6      = WS_C5 + 256;
constexpr size_t WS_C7      = WS_C6 + 256;
constexpr size_t WS_AUX     = WS_C7 + 256;    // int region
// new aliases over truly-dead regions (nothing writes/reads emb8/emb9/fsw anymore)
constexpr size_t WS_VRAW    = WS_EMB8;                 // 512x256 f32
constexpr size_t WS_ABUF    = WS_EMB8 + 512 * 256;     // 512x256 u16
constexpr size_t WS_CFB     = WS_EMB9;                 // 512x768 f32
constexpr size_t WS_UA      = WS_FSW;                  // 4x768 f32 (pad-side GEMV vectors)
constexpr size_t WS_UB      = WS_FSW + 4 * 768;        // 4x768 f32 (embs-side, +w folded)
constexpr size_t WS_CC      = WS_FSW + 8 * 768;        // 8 f32 consts

__device__ inline float fast_rcp(float x) {
#if __has_builtin(__builtin_amdgcn_rcpf)
    return __builtin_amdgcn_rcpf(x);
#else
    return 1.f / x;
#endif
}
__device__ inline float fast_exp2(float x) {
#if __has_builtin(__builtin_amdgcn_exp2f)
    return __builtin_amdgcn_exp2f(x);
#else
    return __exp2f(x);
#endif
}
__device__ inline u16 f2bf(float x) {   // RNE
    union { float f; unsigned u; } v; v.f = x;
    unsigned r = v.u + 0x7FFFu + ((v.u >> 16) & 1u);
    return (u16)(r >> 16);
}
__device__ inline float bf2f(u16 x) {
    union { unsigned u; float f; } v; v.u = ((unsigned)x) << 16;
    return v.f;
}

// ---- 1. per-token fc logits (fp32 exact: threshold source) + embs bf16 cast ----
__global__ __launch_bounds__(256) void k_logits(const float* __restrict__ embs,
        const float* __restrict__ fc_w, const float* __restrict__ fc_b,
        float* __restrict__ out, u16* __restrict__ embsB)
{
    int t = blockIdx.x;
    const float* e = embs + (size_t)t * kH;
    float s0 = 0, s1 = 0, s2 = 0, s3 = 0;
    for (int h = threadIdx.x; h < kH; h += 256) {
        float x = e[h];
        embsB[(size_t)t * kH + h] = f2bf(x);
        s0 += x * fc_w[0 * kH + h];
        s1 += x * fc_w[1 * kH + h];
        s2 += x * fc_w[2 * kH + h];
        s3 += x * fc_w[3 * kH + h];
    }
#pragma unroll
    for (int off = 32; off; off >>= 1) {
        s0 += __shfl_down(s0, off, 64);
        s1 += __shfl_down(s1, off, 64);
        s2 += __shfl_down(s2, off, 64);
        s3 += __shfl_down(s3, off, 64);
    }
    __shared__ float red[4][4];
    int wid = threadIdx.x >> 6;
    if ((threadIdx.x & 63) == 0) {
        red[0][wid] = s0; red[1][wid] = s1; red[2][wid] = s2; red[3][wid] = s3;
    }
    __syncthreads();
    if (threadIdx.x == 0) {
        out[OFF_FSS + t] = red[0][0] + red[0][1] + red[0][2] + red[0][3] + fc_b[0];
        out[OFF_FSE + t] = red[1][0] + red[1][1] + red[1][2] + red[1][3] + fc_b[1];
        out[OFF_BOS + t] = red[2][0] + red[2][1] + red[2][2] + red[2][3] + fc_b[2];
        out[OFF_BOE + t] = red[3][0] + red[3][1] + red[3][2] + red[3][3] + fc_b[3];
    }
}

// ---- 2. misc bf16 casts + zero-bias init + cc scalar consts ----
__global__ __launch_bounds__(256) void k_prep_cast(const float* __restrict__ rel_embs,
        const float* __restrict__ h_gs, const float* __restrict__ rel_transe,
        const float* __restrict__ Wb, const float* __restrict__ fc_w,
        u16* __restrict__ relembB, u16* __restrict__ hgsB, u16* __restrict__ rtransB,
        float* __restrict__ zb, float* __restrict__ cc)
{
    int bx = blockIdx.x, t = threadIdx.x;
    if (bx < 64) {
        for (int h = t; h < kH; h += 256) relembB[bx * kH + h] = f2bf(rel_embs[bx * kH + h]);
    } else if (bx < 68) {
        int r = bx - 64;
        for (int h = t; h < kH; h += 256) hgsB[r * kH + h] = f2bf(h_gs[r * kH + h]);
    } else if (bx < 132) {
        int r = bx - 68;
        if (t < 128) rtransB[r * 128 + t] = (t < kTE) ? f2bf(rel_transe[r * kTE + t]) : (u16)0;
    } else if (bx == 132) {
        for (int h = t; h < kH; h += 256) zb[h] = 0.f;
    } else {
        // cc[j] = Wb[{0,0,1,1,8,8,9,9}[j]] . fc_w[{4,5,6,7,4,5,6,7}[j]]
        int j = bx - 133;          // 0..7
        const int wbI[8] = {0, 0, 1, 1, 8, 8, 9, 9};
        const int fcI[8] = {4, 5, 6, 7, 4, 5, 6, 7};
        const float* wb = Wb + (size_t)wbI[j] * kH;
        const float* w  = fc_w + (size_t)fcI[j] * kH;
        float s = 0.f;
        for (int h = t; h < kH; h += 256) s += wb[h] * w[h];
#pragma unroll
        for (int off = 32; off; off >>= 1) s += __shfl_down(s, off, 64);
        __shared__ float red[4];
        int wid = t >> 6;
        if ((t & 63) == 0) red[wid] = s;
        __syncthreads();
        if (t == 0) cc[j] = red[0] + red[1] + red[2] + red[3];
    }
}

// ---- 2b. GEMVs: uA[j] = Wm{0,0,1,1}@w{4,5,6,7}; uB[j] = Wm{8,8,9,9}@w{...} + w ----
__global__ __launch_bounds__(256) void k_gemv(const float* __restrict__ Wm,
        const float* __restrict__ fc_w, float* __restrict__ uA, float* __restrict__ uB)
{
    int j = blockIdx.x / 192;                    // 0..7
    int wid = threadIdx.x >> 6, lane = threadIdx.x & 63;
    int row = (blockIdx.x % 192) * 4 + wid;      // h_in
    const int wmI[8] = {0, 0, 1, 1, 8, 8, 9, 9};
    const int fcI[8] = {4, 5, 6, 7, 4, 5, 6, 7};
    const float* W = Wm + (size_t)wmI[j] * HH + (size_t)row * kH;
    const float* w = fc_w + (size_t)fcI[j] * kH;
    float s = 0.f;
    for (int c = lane; c < kH; c += 64) s += W[c] * w[c];
#pragma unroll
    for (int off = 32; off; off >>= 1) s += __shfl_xor(s, off, 64);
    if (lane == 0) {
        if (j < 4) uA[j * kH + row] = s;
        else       uB[(j - 4) * kH + row] = s + w[row];
    }
}

// ---- 3. weight transposes: Wt[n][k] = W[k][n], bf16 out (only Wm2..7 + rproj) ----
__global__ __launch_bounds__(256) void k_prep_w(const float* __restrict__ Wm,
        const float* __restrict__ rproj_w, u16* __restrict__ WtAll, u16* __restrict__ rprojT)
{
    __shared__ float tl[64][65];
    int bx = blockIdx.x, t = threadIdx.x;
    const float* src; u16* dst; int kt, nt, dstStride, srcRows;
    if (bx < 864) {
        int mi = 2 + bx / 144, tile = bx % 144;
        kt = (tile / 12) * 64; nt = (tile % 12) * 64;
        src = Wm + (size_t)mi * HH; dst = WtAll + (size_t)mi * HH;
        dstStride = kH; srcRows = kH;
    } else {
        int tt = bx - 864;
        kt = (tt / 12) * 64; nt = (tt % 12) * 64;
        src = rproj_w; dst = rprojT; dstStride = 128; srcRows = kTE;
    }
    int r = t >> 2, cq = (t & 3) * 16;
    int row = kt + r;
#pragma unroll
    for (int q = 0; q < 4; q++) {
        float4 v = make_float4(0.f, 0.f, 0.f, 0.f);
        if (row < srcRows) v = *(const float4*)(src + (size_t)row * kH + nt + cq + q * 4);
        tl[r][cq + q * 4 + 0] = v.x;
        tl[r][cq + q * 4 + 1] = v.y;
        tl[r][cq + q * 4 + 2] = v.z;
        tl[r][cq + q * 4 + 3] = v.w;
    }
    __syncthreads();
    u16* drow = dst + (size_t)(nt + r) * dstStride + kt + cq;
#pragma unroll
    for (int j = 0; j < 16; j++) drow[j] = f2bf(tl[cq + j][r]);
}

// ---- 3b. embs transpose to embsT[b][h][l] bf16 ----
__global__ __launch_bounds__(256) void k_embsT(const u16* __restrict__ embsB,
        u16* __restrict__ embsT)
{
    __shared__ u16 tl[64][66];
    int b = blockIdx.x / 48, rem = blockIdx.x % 48;
    int h0 = (rem / 4) * 64, l0 = (rem % 4) * 64;
    int r = threadIdx.x >> 2, cq = (threadIdx.x & 3) * 16;
    const u16* src = embsB + (size_t)(b * kL + l0 + r) * kH + h0 + cq;
#pragma unroll
    for (int j = 0; j < 16; j++) tl[r][cq + j] = src[j];
    __syncthreads();
    u16* dst = embsT + (size_t)b * kH * kL + (size_t)(h0 + r) * kL + l0 + cq;
#pragma unroll
    for (int j = 0; j < 16; j++) dst[j] = tl[cq + j][r];
}

// ---- 4. span extraction metadata ----
__global__ __launch_bounds__(256) void k_extract_meta(const float* __restrict__ out,
        int* __restrict__ jbuf, int* __restrict__ rankbuf, int* __restrict__ validbuf,
        float* __restrict__ fmask, float* __restrict__ bmask)
{
    int which = blockIdx.x >> 2;
    int b = blockIdx.x & 3;
    int i = threadIdx.x;
    const float* slog = out + (which ? OFF_BOS : OFF_FSS) + (size_t)b * kL;
    const float* elog = out + (which ? OFF_BOE : OFF_FSE) + (size_t)b * kL;
    float sv = slog[i], ev = elog[i];
    bool st = (1.f / (1.f + __expf(-sv)) > 0.5f);
    bool en = (1.f / (1.f + __expf(-ev)) > 0.5f);

    __shared__ int sm[kL];
    __shared__ int ps[kL];
    sm[i] = en ? i : kL;
    __syncthreads();
    for (int step = 1; step < kL; step <<= 1) {
        int v = (i + step < kL) ? sm[i + step] : kL;
        __syncthreads();
        sm[i] = min(sm[i], v);
        __syncthreads();
    }
    int next_end = sm[i];
    int validi = (st && next_end < kL) ? 1 : 0;
    ps[i] = validi;
    __syncthreads();
    for (int step = 1; step < kL; step <<= 1) {
        int v = (i >= step) ? ps[i - step] : 0;
        __syncthreads();
        ps[i] += v;
        __syncthreads();
    }
    int rank = ps[i] - 1;
    int num = ps[kL - 1];
    int gbase = (which * kB + b) * kL + i;
    jbuf[gbase] = min(next_end, kL - 1);
    rankbuf[gbase] = rank;
    validbuf[gbase] = validi;
    (which ? bmask : fmask)[b * kL + i] = (i < num) ? 1.f : 0.f;
}

// ---- 5. span means packed by rank (bf16 out) ----
__global__ __launch_bounds__(256) void k_span_mean(const float* __restrict__ embs,
        const int* __restrict__ jbuf, const int* __restrict__ rankbuf,
        const int* __restrict__ validbuf, u16* __restrict__ fpadB, u16* __restrict__ bpadB)
{
    int idx = blockIdx.x;
    int which = idx >> 10;
    int b = (idx >> 8) & 3;
    int i = idx & 255;
    int gbase = (which * kB + b) * kL + i;
    if (!validbuf[gbase]) return;
    int j = jbuf[gbase];
    int rk = rankbuf[gbase];
    int len = j - i + 1;
    float inv = 1.f / (float)len;
    u16* pad = (which ? bpadB : fpadB) + ((size_t)(b * kL + rk)) * kH;
    const float* e = embs + ((size_t)(b * kL + i)) * kH;
    for (int h = threadIdx.x; h < kH; h += 256) {
        float s = 0.f;
        for (int row = 0; row < len; row++) s += e[(size_t)row * kH + h];
        pad[h] = f2bf(s * inv);
    }
}

// ---- 6. batched MFMA GEMM, 64x128 tile, BK=64, dbuf + reg-prefetch ----
struct GemmJob {
    const u16* A; const u16* Wt; const float* bias;
    float* C; u16* Cbf; const float* rowmask;
    int M; int K; int ldc; int coff;
};
struct GemmBatch { GemmJob j[10]; };

__device__ inline int swz(int row, int slot) {   // short-index into [row][64] layout
    return row * 64 + ((slot ^ (row & 7)) << 3);
}

__global__ __launch_bounds__(256) void k_gemm_mfma(GemmBatch batch)
{
    GemmJob jb = batch.j[blockIdx.z];
    if (blockIdx.x * 64 >= jb.M) return;
    __shared__ short Als[2][64 * 64];      // 16 KB
    __shared__ short Bls[2][128 * 64];     // 32 KB
    int tid = threadIdx.x;
    int m0 = blockIdx.x * 64;
    int n0 = blockIdx.y * 128;
    int w = tid >> 6, lane = tid & 63;
    int wm = (w >> 1) * 32, wn = (w & 1) * 64;   // 2M x 2N waves, each 32x64
    int lrow = lane & 15, lhi = lane >> 4;
    int arow = tid >> 2, ac0 = (tid & 3) * 2;
    int brow = tid >> 1, bc0 = (tid & 1) * 4;
    int K = jb.K;
    int T = K >> 6;

    f32x4 zero4 = {0.f, 0.f, 0.f, 0.f};
    f32x4 acc[2][4];
#pragma unroll
    for (int i = 0; i < 2; i++)
#pragma unroll
        for (int j = 0; j < 4; j++) acc[i][j] = zero4;

    bf16x8 pa[2], pb[4];

#define LOADT(k0)                                                                 \
    {                                                                             \
        _Pragma("unroll")                                                         \
        for (int q = 0; q < 2; q++) {                                             \
            bf16x8 va;                                                            \
            _Pragma("unroll") for (int z = 0; z < 8; z++) va[z] = 0;              \
            if (m0 + arow < jb.M)                                                 \
                va = *reinterpret_cast<const bf16x8*>(                            \
                    jb.A + (size_t)(m0 + arow) * K + (k0) + (ac0 + q) * 8);       \
            pa[q] = va;                                                           \
        }                                                                         \
        _Pragma("unroll")                                                         \
        for (int q = 0; q < 4; q++)                                               \
            pb[q] = *reinterpret_cast<const bf16x8*>(                             \
                jb.Wt + (size_t)(n0 + brow) * K + (k0) + (bc0 + q) * 8);          \
    }
#define STORET(buf)                                                               \
    {                                                                             \
        _Pragma("unroll")                                                         \
        for (int q = 0; q < 2; q++)                                               \
            *reinterpret_cast<bf16x8*>(&Als[buf][swz(arow, ac0 + q)]) = pa[q];    \
        _Pragma("unroll")                                                         \
        for (int q = 0; q < 4; q++)                                               \
            *reinterpret_cast<bf16x8*>(&Bls[buf][swz(brow, bc0 + q)]) = pb[q];    \
    }

    LOADT(0);
    STORET(0);
    __syncthreads();
    int cur = 0;
    for (int t = 0; t < T; t++) {
        if (t + 1 < T) LOADT((t + 1) << 6);     // issue next-tile loads early
#pragma unroll
        for (int sub = 0; sub < 2; sub++) {
            bf16x8 af[2], bg[4];
#pragma unroll
            for (int i = 0; i < 2; i++)
                af[i] = *reinterpret_cast<const bf16x8*>(
                    &Als[cur][swz(wm + i * 16 + lrow, sub * 4 + lhi)]);
#pragma unroll
            for (int j = 0; j < 4; j++)
                bg[j] = *reinterpret_cast<const bf16x8*>(
                    &Bls[cur][swz(wn + j * 16 + lrow, sub * 4 + lhi)]);
#pragma unroll
            for (int i = 0; i < 2; i++)
#pragma unroll
                for (int j = 0; j < 4; j++)
                    acc[i][j] = __builtin_amdgcn_mfma_f32_16x16x32_bf16(af[i], bg[j], acc[i][j], 0, 0, 0);
        }
        if (t + 1 < T) STORET(cur ^ 1);         // write to alternate buffer
        __syncthreads();
        cur ^= 1;
    }
#undef LOADT
#undef STORET

#pragma unroll
    for (int i = 0; i < 2; i++) {
#pragma unroll
        for (int j = 0; j < 4; j++) {
            int n = n0 + wn + j * 16 + lrow;
            float bi = jb.bias[n];
#pragma unroll
            for (int q = 0; q < 4; q++) {
                int m = m0 + wm + i * 16 + lhi * 4 + q;
                if (m < jb.M) {
                    float val = acc[i][j][q] + bi;
                    if (jb.rowmask) val = (jb.rowmask[m] != 0.f) ? val : 0.f;
                    if (jb.C)   jb.C[(size_t)m * jb.ldc + jb.coff + n] = val;
                    if (jb.Cbf) jb.Cbf[(size_t)m * jb.ldc + jb.coff + n] = f2bf(val);
                }
            }
        }
    }
}

// ---- 7. attention scores: block=(which,b,r), lane owns 12-elem h-slice in regs ----
__global__ __launch_bounds__(512) void k_score(const u16* __restrict__ tokpB,
        const float* __restrict__ relpf, const float* __restrict__ relpb,
        const float* __restrict__ hgpf, const float* __restrict__ hgpb,
        const float* __restrict__ V_w, const float* __restrict__ V_b,
        float* __restrict__ vraw)
{
    constexpr float C = 2.8853900817779268f;   // 2*log2(e)
    int idx = blockIdx.x;            // 512
    int which = idx >> 8, b = (idx >> 6) & 3, r = idx & 63;
    int wid = threadIdx.x >> 6, lane = threadIdx.x & 63;
    int h0 = lane * 12;
    const float* relp = (which ? relpb : relpf) + (size_t)r * kH + h0;
    const float* hgp  = (which ? hgpb : hgpf) + (size_t)b * kH + h0;
    const float* vw   = V_w + h0;

    float av2[12], w2[12], wsum = 0.f;
#pragma unroll
    for (int j = 0; j < 12; j++) {
        av2[j] = C * (relp[j] + hgp[j]);
        float wv = vw[j];
        w2[j] = -2.f * wv;
        wsum += wv;
    }
    float vb = V_b[0];
    const u16* base = tokpB + ((size_t)which * (kB * kL) + b * kL) * kH + h0;
    float* vout = vraw + ((size_t)(which * kB + b) * kR + r) * kL;

    int l0 = wid * 32;
    bf16x4 t0 = *reinterpret_cast<const bf16x4*>(base + (size_t)l0 * kH);
    bf16x4 t1 = *reinterpret_cast<const bf16x4*>(base + (size_t)l0 * kH + 4);
    bf16x4 t2 = *reinterpret_cast<const bf16x4*>(base + (size_t)l0 * kH + 8);
    for (int l = l0; l < l0 + 32; l++) {
        bf16x4 n0, n1, n2;
        if (l + 1 < l0 + 32) {
            const u16* nrow = base + (size_t)(l + 1) * kH;
            n0 = *reinterpret_cast<const bf16x4*>(nrow);
            n1 = *reinterpret_cast<const bf16x4*>(nrow + 4);
            n2 = *reinterpret_cast<const bf16x4*>(nrow + 8);
        }
        float acc = wsum;
#pragma unroll
        for (int j = 0; j < 4; j++) {
            float e0 = fast_exp2(fmaf(bf2f((u16)t0[j]), C, av2[j]));
            acc = fmaf(w2[j], fast_rcp(e0 + 1.f), acc);
            float e1 = fast_exp2(fmaf(bf2f((u16)t1[j]), C, av2[4 + j]));
            acc = fmaf(w2[4 + j], fast_rcp(e1 + 1.f), acc);
            float e2 = fast_exp2(fmaf(bf2f((u16)t2[j]), C, av2[8 + j]));
            acc = fmaf(w2[8 + j], fast_rcp(e2 + 1.f), acc);
        }
#pragma unroll
        for (int off = 32; off; off >>= 1) acc += __shfl_xor(acc, off, 64);
        if (lane == 0) vout[l] = acc + vb;
        t0 = n0; t1 = n1; t2 = n2;
    }
}

// ---- 8. softmax over l, bf16 A out ----
__global__ __launch_bounds__(256) void k_softmax(const float* __restrict__ vraw,
        u16* __restrict__ Abuf)
{
    int wid = threadIdx.x >> 6, lane = threadIdx.x & 63;
    int g = blockIdx.x * 4 + wid;      // 512 rows
    const float* row = vraw + (size_t)g * kL;
    float x[4];
#pragma unroll
    for (int q = 0; q < 4; q++) x[q] = row[lane + 64 * q];
    float m = fmaxf(fmaxf(x[0], x[1]), fmaxf(x[2], x[3]));
#pragma unroll
    for (int off = 32; off; off >>= 1) m = fmaxf(m, __shfl_xor(m, off, 64));
    float p[4], s = 0.f;
#pragma unroll
    for (int q = 0; q < 4; q++) { p[q] = __expf(x[q] - m); s += p[q]; }
#pragma unroll
    for (int off = 32; off; off >>= 1) s += __shfl_xor(s, off, 64);
    float inv = 1.f / s;
#pragma unroll
    for (int q = 0; q < 4; q++) Abuf[(size_t)g * kL + lane + 64 * q] = f2bf(p[q] * inv);
}

// ---- 9. c vectors from Cfb ----
__global__ __launch_bounds__(256) void k_c(const float* __restrict__ Cfb,
        const float* __restrict__ fc_w, float* __restrict__ c4, float* __restrict__ c5,
        float* __restrict__ c6, float* __restrict__ c7)
{
    int p = blockIdx.x;               // 512 = which*256 + b*64 + r
    int which = p >> 8, local = p & 255;
    const float* Cm = Cfb + (size_t)p * kH;
    const float* w0 = fc_w + (size_t)(which ? 6 : 4) * kH;
    const float* w1 = w0 + kH;
    float s0 = 0, s1 = 0;
    for (int h = threadIdx.x; h < kH; h += 256) {
        float x = Cm[h];
        s0 += x * w0[h];
        s1 += x * w1[h];
    }
#pragma unroll
    for (int off = 32; off; off >>= 1) {
        s0 += __shfl_down(s0, off, 64);
        s1 += __shfl_down(s1, off, 64);
    }
    __shared__ float red[2][4];
    int wid = threadIdx.x >> 6;
    if ((threadIdx.x & 63) == 0) { red[0][wid] = s0; red[1][wid] = s1; }
    __syncthreads();
    if (threadIdx.x == 0) {
        float a = red[0][0] + red[0][1] + red[0][2] + red[0][3];
        float c = red[1][0] + red[1][1] + red[1][2] + red[1][3];
        if (which) { c6[local] = a; c7[local] = c; }
        else       { c4[local] = a; c5[local] = c; }
    }
}

// ---- 10. t vectors via GEMV decomposition:
// t4 = sel(fmask){fpad.uA0 + cc0} + embs.uB0 + cc4   (uB has +w folded) etc.
__global__ __launch_bounds__(256) void k_t(const float* __restrict__ embs,
        const u16* __restrict__ fpadB, const u16* __restrict__ bpadB,
        const float* __restrict__ uA, const float* __restrict__ uB,
        const float* __restrict__ cc,
        const float* __restrict__ fmask, const float* __restrict__ bmask,
        float* __restrict__ t4, float* __restrict__ t5,
        float* __restrict__ t6, float* __restrict__ t7)
{
    int t = blockIdx.x;               // 1024
    size_t base = (size_t)t * kH;
    float a4 = 0, a5 = 0, a6 = 0, a7 = 0, f4 = 0, f5 = 0, b6 = 0, b7 = 0;
    for (int h = threadIdx.x; h < kH; h += 256) {
        float e = embs[base + h];
        a4 += e * uB[h];
        a5 += e * uB[kH + h];
        a6 += e * uB[2 * kH + h];
        a7 += e * uB[3 * kH + h];
        float fp = bf2f(fpadB[base + h]);
        f4 += fp * uA[h];
        f5 += fp * uA[kH + h];
        float bp = bf2f(bpadB[base + h]);
        b6 += bp * uA[2 * kH + h];
        b7 += bp * uA[3 * kH + h];
    }
#pragma unroll
    for (int off = 32; off; off >>= 1) {
        a4 += __shfl_down(a4, off, 64);
        a5 += __shfl_down(a5, off, 64);
        a6 += __shfl_down(a6, off, 64);
        a7 += __shfl_down(a7, off, 64);
        f4 += __shfl_down(f4, off, 64);
        f5 += __shfl_down(f5, off, 64);
        b6 += __shfl_down(b6, off, 64);
        b7 += __shfl_down(b7, off, 64);
    }
    __shared__ float red[8][4];
    int wid = threadIdx.x >> 6;
    if ((threadIdx.x & 63) == 0) {
        red[0][wid] = a4; red[1][wid] = a5; red[2][wid] = a6; red[3][wid] = a7;
        red[4][wid] = f4; red[5][wid] = f5; red[6][wid] = b6; red[7][wid] = b7;
    }
    __syncthreads();
    if (threadIdx.x == 0) {
        float ra4 = red[0][0] + red[0][1] + red[0][2] + red[0][3];
        float ra5 = red[1][0] + red[1][1] + red[1][2] + red[1][3];
        float ra6 = red[2][0] + red[2][1] + red[2][2] + red[2][3];
        float ra7 = red[3][0] + red[3][1] + red[3][2] + red[3][3];
        float rf4 = red[4][0] + red[4][1] + red[4][2] + red[4][3];
        float rf5 = red[5][0] + red[5][1] + red[5][2] + red[5][3];
        float rb6 = red[6][0] + red[6][1] + red[6][2] + red[6][3];
        float rb7 = red[7][0] + red[7][1] + red[7][2] + red[7][3];
        bool mf = fmask[t] != 0.f, mb = bmask[t] != 0.f;
        // SELECT: garbage pad rows (mask=0) may be bf16 Inf/NaN -> never multiply
        t4[t] = (mf ? (rf4 + cc[0]) : 0.f) + ra4 + cc[4];
        t5[t] = (mf ? (rf5 + cc[1]) : 0.f) + ra5 + cc[5];
        t6[t] = (mb ? (rb6 + cc[2]) : 0.f) + ra6 + cc[6];
        t7[t] = (mb ? (rb7 + cc[3]) : 0.f) + ra7 + cc[7];
    }
}

// ---- 11. broadcast-add final pair logits ----
__global__ __launch_bounds__(64) void k_final(const float* __restrict__ t4,
        const float* __restrict__ t5, const float* __restrict__ t6,
        const float* __restrict__ t7, const float* __restrict__ c4,
        const float* __restrict__ c5, const float* __restrict__ c6,
        const float* __restrict__ c7, const float* __restrict__ fc_b,
        float* __restrict__ out)
{
    int which = blockIdx.x >> 10;
    int t = blockIdx.x & 1023;
    int b = t >> 8;
    int r = threadIdx.x;
    if (!which) {
        out[OFF_FOS + (size_t)t * kR + r] = t4[t] + c4[b * kR + r] + fc_b[4];
        out[OFF_FOE + (size_t)t * kR + r] = t5[t] + c5[b * kR + r] + fc_b[5];
    } else {
        out[OFF_BSS + (size_t)t * kR + r] = t6[t] + c6[b * kR + r] + fc_b[6];
        out[OFF_BSE + (size_t)t * kR + r] = t7[t] + c7[b * kR + r] + fc_b[7];
    }
}

extern "C" void kernel_launch(void* const* d_in, const int* in_sizes, int n_in,
                              void* d_out, int out_size, void* d_ws, size_t ws_size,
                              hipStream_t stream)
{
    const float* embs       = (const float*)d_in[0];
    const float* h_gs       = (const float*)d_in[1];
    const float* rel_embs   = (const float*)d_in[2];
    const float* rel_transe = (const float*)d_in[3];
    const float* fc_w       = (const float*)d_in[4];
    const float* fc_b       = (const float*)d_in[5];
    const float* Wm         = (const float*)d_in[6];
    const float* Wb         = (const float*)d_in[7];
    const float* V_w        = (const float*)d_in[8];
    const float* V_b        = (const float*)d_in[9];
    const float* rproj_w    = (const float*)d_in[10];
    const float* rproj_b    = (const float*)d_in[11];
    float* out = (float*)d_out;
    float* ws  = (float*)d_ws;

    u16* WtAll   = (u16*)(ws + WS_WTALL);
    u16* rprojT  = (u16*)(ws + WS_RPROJT);
    u16* embsB   = (u16*)(ws + WS_EMBSB);
    u16* relembB = (u16*)(ws + WS_RELEMBB);
    u16* hgsB    = (u16*)(ws + WS_HGSB);
    u16* rtransB = (u16*)(ws + WS_RTRANSB);
    u16* fpadB   = (u16*)(ws + WS_FPADB);
    u16* bpadB   = (u16*)(ws + WS_BPADB);
    u16* brelB   = (u16*)(ws + WS_BRELB);
    u16* embsT   = (u16*)(ws + WS_EMBST);
    u16* tokpB   = (u16*)(ws + WS_TOKPB);
    float* relpf = ws + WS_RELPF;
    float* relpb = ws + WS_RELPB;
    float* hgpf  = ws + WS_HGPF;
    float* hgpb  = ws + WS_HGPB;
    float* zb    = ws + WS_ZB;
    float* fmask = ws + WS_FMASK;
    float* bmask = ws + WS_BMASK;
    float* vraw  = ws + WS_VRAW;
    u16*   Abuf  = (u16*)(ws + WS_ABUF);
    float* Cfb   = ws + WS_CFB;
    float* uA    = ws + WS_UA;
    float* uB    = ws + WS_UB;
    float* cc    = ws + WS_CC;
    float* t4 = ws + WS_T4; float* t5 = ws + WS_T5;
    float* t6 = ws + WS_T6; float* t7 = ws + WS_T7;
    float* c4 = ws + WS_C4; float* c5 = ws + WS_C5;
    float* c6 = ws + WS_C6; float* c7 = ws + WS_C7;
    int* jbuf     = (int*)(ws + WS_AUX);
    int* rankbuf  = jbuf + 2 * kB * kL;
    int* validbuf = rankbuf + 2 * kB * kL;

    // prep
    k_logits<<<kB * kL, 256, 0, stream>>>(embs, fc_w, fc_b, out, embsB);
    k_prep_cast<<<141, 256, 0, stream>>>(rel_embs, h_gs, rel_transe, Wb, fc_w,
                                         relembB, hgsB, rtransB, zb, cc);
    k_prep_w<<<888, 256, 0, stream>>>(Wm, rproj_w, WtAll, rprojT);
    k_gemv<<<1536, 256, 0, stream>>>(Wm, fc_w, uA, uB);
    k_embsT<<<192, 256, 0, stream>>>(embsB, embsT);
    k_extract_meta<<<2 * kB, 256, 0, stream>>>(out, jbuf, rankbuf, validbuf, fmask, bmask);
    k_span_mean<<<2 * kB * kL, 256, 0, stream>>>(embs, jbuf, rankbuf, validbuf, fpadB, bpadB);

    // gemmA: 6 jobs (emb8/emb9/fsw/bow GEMMs eliminated algebraically)
    {
        GemmBatch bt;
        bt.j[0] = { relembB, WtAll + 2 * HH, Wb + 2 * kH, relpf, nullptr, nullptr, kR, kH, kH, 0 };
        bt.j[1] = { hgsB,    WtAll + 3 * HH, Wb + 3 * kH, hgpf,  nullptr, nullptr, kB, kH, kH, 0 };
        bt.j[2] = { hgsB,    WtAll + 6 * HH, Wb + 6 * kH, hgpb,  nullptr, nullptr, kB, kH, kH, 0 };
        bt.j[3] = { rtransB, rprojT,         rproj_b,     nullptr, brelB, nullptr, kR, 128, kH, 0 };
        bt.j[4] = { embsB,   WtAll + 4 * HH, Wb + 4 * kH, nullptr, tokpB,            nullptr, kB * kL, kH, kH, 0 };
        bt.j[5] = { embsB,   WtAll + 7 * HH, Wb + 7 * kH, nullptr, tokpB + (size_t)kB * kL * kH, nullptr, kB * kL, kH, kH, 0 };
        k_gemm_mfma<<<dim3(16, 6, 6), 256, 0, stream>>>(bt);
    }
    // gemmB: relpb = brel @ Wm5 (depends on brelB)
    {
        GemmBatch bt;
        bt.j[0] = { brelB, WtAll + 5 * HH, Wb + 5 * kH, relpb, nullptr, nullptr, kR, kH, kH, 0 };
        k_gemm_mfma<<<dim3(1, 6, 1), 256, 0, stream>>>(bt);
    }

    k_score<<<512, 512, 0, stream>>>(tokpB, relpf, relpb, hgpf, hgpb, V_w, V_b, vraw);
    k_softmax<<<128, 256, 0, stream>>>(vraw, Abuf);

    // gemmC: C[which,b] = A[which,b] @ embsT[b]^T  (8 jobs, M=64, K=256)
    {
        GemmBatch bt;
        for (int z = 0; z < 8; z++) {
            int which = z >> 2, b = z & 3;
            bt.j[z] = { Abuf + (size_t)z * kR * kL,
                        embsT + (size_t)b * kH * kL,
                        zb,
                        Cfb + (size_t)z * kR * kH, nullptr, nullptr,
                        kR, kL, kH, 0 };
        }
        k_gemm_mfma<<<dim3(1, 6, 8), 256, 0, stream>>>(bt);
    }

    k_c<<<512, 256, 0, stream>>>(Cfb, fc_w, c4, c5, c6, c7);
    k_t<<<kB * kL, 256, 0, stream>>>(embs, fpadB, bpadB, uA, uB, cc, fmask, bmask, t4, t5, t6, t7);
    k_final<<<2 * kB * kL, 64, 0, stream>>>(t4, t5, t6, t7, c4, c5, c6, c7, fc_b, out);
}